// Round 7
// baseline (477.011 us; speedup 1.0000x reference)
//
#include <hip/hip_runtime.h>

typedef unsigned short u16;

// ---------------- problem constants ----------------
constexpr int NN = 20000;   // nodes
constexpr int EE = 320000;  // edges
constexpr int FD = 128;     // input features
constexpr int C0 = 256;     // hidden (mlp)
constexpr int C1 = 512;     // H*C for GAT
constexpr int NG = 128;     // graphs
constexpr int NC = 10;      // classes
constexpr int NBLK = (NN + 255) / 256;  // 79
constexpr int HB  = 320;                // hist/fill blocks
constexpr int EST = HB * 256;           // edge stride (81920); 4 chunks cover EE
constexpr int LGB = 640;                // logits blocks (persistent)
constexpr int NCH = 8;                  // feature chunks (64 feats each) -> XCD slicing
constexpr int MAXPE = 620032;           // max padded edges: EE + 15*NN = 620000, rounded

// ---------------- workspace layout (bytes) ----------------
constexpr size_t OFF_XB   = 0;                                   // NN*FD bf16 (dead after gemm1 -> reused for PE0)
constexpr size_t OFF_H1   = OFF_XB  + (size_t)NN * FD * 2;       // NN*C0 bf16 (dead after gemm2 -> reused for PE1)
constexpr size_t OFF_H2   = OFF_H1  + (size_t)NN * C0 * 2;       // NN*C0 bf16
constexpr size_t OFF_XW   = OFF_H2  + (size_t)NN * C0 * 2;       // NN*C1 bf16 (chunk-major xwt)
constexpr size_t OFF_H34  = OFF_XW  + (size_t)NN * C1 * 2;       // NN*C1 bf16 (h3 then h4, row-major)
constexpr size_t OFF_LS   = OFF_H34 + (size_t)NN * C1 * 2;       // NN*2 f32
constexpr size_t OFF_LD   = OFF_LS  + (size_t)NN * 2 * 4;        // NN*2 f32
constexpr size_t OFF_DEG  = OFF_LD  + (size_t)NN * 2 * 4;        // NN i32
constexpr size_t OFF_OFFS = OFF_DEG + (size_t)NN * 4;            // NN+1 i32 PADDED offsets (pad 80016)
constexpr size_t OFF_CUR  = OFF_OFFS + 80016;                    // NN i32
constexpr size_t OFF_CSRC = OFF_CUR + (size_t)NN * 4;            // (legacy region, unused)
constexpr size_t OFF_GCNT = OFF_CSRC + (size_t)EE * 4;           // NG i32
constexpr size_t OFF_GOFF = OFF_GCNT + 512;                      // NG+1 i32 (pad 768)
constexpr size_t OFF_PART = OFF_GOFF + 768;                      // NBLK i32 (pad 512)
constexpr size_t OFF_PTOT = OFF_PART + 512;                      // 1 i32 (pad 256)
constexpr size_t OFF_Z1   = OFF_PTOT + 256;                      // NG*C1 bf16
constexpr size_t OFF_Z2   = OFF_Z1  + (size_t)NG * C1 * 2;
constexpr size_t OFF_ST   = OFF_Z2  + (size_t)NG * C1 * 2;       // S1,T1,S2,T2 (256 f32), S3,T3 (512 f32)
constexpr size_t OFF_W1T  = OFF_ST  + 8192;
constexpr size_t OFF_W2T  = OFF_W1T + (size_t)FD * C0 * 2;
constexpr size_t OFF_G0T  = OFF_W2T + (size_t)C0 * C0 * 2;
constexpr size_t OFF_G1T  = OFF_G0T + (size_t)C0 * C1 * 2;
constexpr size_t OFF_AUX  = OFF_G1T + (size_t)C1 * C1 * 2;
constexpr size_t OFF_FLAG = OFF_AUX  + 0;      // u32
constexpr size_t OFF_A0S  = OFF_AUX  + 256;    // 512 u16
constexpr size_t OFF_A0D  = OFF_AUX  + 1280;
constexpr size_t OFF_A1S  = OFF_AUX  + 2304;
constexpr size_t OFF_A1D  = OFF_AUX  + 3328;
constexpr size_t OFF_GB0  = OFF_AUX  + 4352;   // 512 f32
constexpr size_t OFF_GB1  = OFF_AUX  + 6400;
constexpr size_t OFF_FB1  = OFF_AUX  + 8448;   // 512 f32
constexpr size_t OFF_FB2  = OFF_AUX  + 10496;  // 10 f32 (pad 256)
constexpr size_t OFF_GMX  = OFF_AUX  + 10752;  // 4 u32 (pad 256)
constexpr size_t OFF_CSP  = OFF_AUX  + 11008;               // u32[MAXPE] padded edge srcs (+2.48MB)
constexpr size_t OFF_DENA = OFF_CSP + (size_t)MAXPE * 4;    // f32[NN*2] softmax denominators
// packed per-edge records {src,p} per head -- reuse dead XB / H1 regions (written by gat_prep)
constexpr size_t OFF_PE0  = OFF_XB;            // uint2[MAXPE] = 4.96MB <= 5.12MB XB
constexpr size_t OFF_PE1  = OFF_H1;            // uint2[MAXPE] <= 10.24MB H1
// end ~= 73 MB

// ---------------- helpers ----------------
__device__ inline float bf2f(u16 u) { return __uint_as_float(((unsigned)u) << 16); }
__device__ inline u16 f2bf(float f) {
    unsigned u = __float_as_uint(f);
    unsigned r = u + 0x7fffu + ((u >> 16) & 1u);   // RNE
    return (u16)(r >> 16);
}
// flag-driven load of an external float input (flag=1 -> f32, 0 -> bf16)
__device__ inline float ldf(const void* p, long i, unsigned f) {
    return f ? ((const float*)p)[i] : bf2f(((const u16*)p)[i]);
}
__device__ inline unsigned encf(float f) {  // monotonic float->uint for atomicMax
    unsigned u = __float_as_uint(f);
    return (u & 0x80000000u) ? ~u : (u | 0x80000000u);
}
__device__ inline float decf(unsigned e) {
    return (e & 0x80000000u) ? __uint_as_float(e ^ 0x80000000u) : __uint_as_float(~e);
}
// 2 VALU ops per 32-bit word (low: shl drops high; high: mask)
__device__ inline void unpack8(uint4 r, float* v) {
    v[0] = __uint_as_float(r.x << 16); v[1] = __uint_as_float(r.x & 0xffff0000u);
    v[2] = __uint_as_float(r.y << 16); v[3] = __uint_as_float(r.y & 0xffff0000u);
    v[4] = __uint_as_float(r.z << 16); v[5] = __uint_as_float(r.z & 0xffff0000u);
    v[6] = __uint_as_float(r.w << 16); v[7] = __uint_as_float(r.w & 0xffff0000u);
}

typedef __bf16 bf16x8_t __attribute__((ext_vector_type(8)));
typedef float  f32x4_t  __attribute__((ext_vector_type(4)));

// async 16B global -> LDS (wave-uniform LDS base + lane*16 layout)
__device__ __forceinline__ void gl_lds16(const u16* g, u16* l) {
    __builtin_amdgcn_global_load_lds((const __attribute__((address_space(1))) void*)g,
                                     (__attribute__((address_space(3))) void*)l, 16, 0, 0);
}

// ---------------- dtype detector ----------------
__global__ void detect_dtype(const u16* __restrict__ x, const u16* __restrict__ w,
                             const u16* __restrict__ fw, unsigned* flag) {
    __shared__ int cnt;
    if (threadIdx.x == 0) cnt = 0;
    __syncthreads();
    int c = 0;
    for (int i = threadIdx.x; i < 4096; i += 256) {
        c += (((x[i]  >> 7) & 0xFF) == 0xFF);
        c += (((w[i]  >> 7) & 0xFF) == 0xFF);
        c += (((fw[i] >> 7) & 0xFF) == 0xFF);
    }
    atomicAdd(&cnt, c);
    __syncthreads();
    if (threadIdx.x == 0) *flag = (cnt >= 2) ? 1u : 0u;  // 1 = f32 inputs
}

// ---------------- x -> internal bf16 copy (+ zero deg/gcnt, init gmx) ----------------
__global__ void cvt_x(const unsigned* __restrict__ flag, const void* __restrict__ xin,
                      u16* __restrict__ XB, int* __restrict__ deg, int* __restrict__ gcnt,
                      unsigned* __restrict__ gmxu) {
    int i = blockIdx.x * 256 + threadIdx.x;  // grid covers NN*FD/4 (2500 blocks)
    if (i < NN) deg[i] = 0;
    if (i < NG) gcnt[i] = 0;
    if (i < 4)  gmxu[i] = encf(-1e30f);
    if (*flag) {
        float4 v = ((const float4*)xin)[i];
        ushort4 r;
        r.x = f2bf(v.x); r.y = f2bf(v.y); r.z = f2bf(v.z); r.w = f2bf(v.w);
        ((ushort4*)XB)[i] = r;
    } else {
        ((ushort4*)XB)[i] = ((const ushort4*)xin)[i];
    }
}

// ---------------- params prep ----------------
__global__ void prep_params(const unsigned* __restrict__ flag,
                            const void* g1, const void* b1, const void* m1, const void* v1, const void* lb1,
                            const void* g2, const void* b2, const void* m2, const void* v2, const void* lb2,
                            const void* g3, const void* b3, const void* m3, const void* v3,
                            const void* a0s, const void* a0d, const void* gb0in,
                            const void* a1s, const void* a1d, const void* gb1in,
                            const void* fb1in, const void* fb2in,
                            float* S1, float* T1, float* S2, float* T2, float* S3, float* T3,
                            u16* A0S, u16* A0D, u16* A1S, u16* A1D,
                            float* GB0, float* GB1, float* FB1, float* FB2) {
    unsigned f = *flag;
    int c = threadIdx.x;  // block 512
    if (c < 256) {
        float s = ldf(g1, c, f) / sqrtf(ldf(v1, c, f) + 1e-5f);
        S1[c] = s; T1[c] = s * (ldf(lb1, c, f) - ldf(m1, c, f)) + ldf(b1, c, f);
        float s2 = ldf(g2, c, f) / sqrtf(ldf(v2, c, f) + 1e-5f);
        S2[c] = s2; T2[c] = s2 * (ldf(lb2, c, f) - ldf(m2, c, f)) + ldf(b2, c, f);
    }
    float s3 = ldf(g3, c, f) / sqrtf(ldf(v3, c, f) + 1e-5f);
    S3[c] = s3; T3[c] = ldf(b3, c, f) - ldf(m3, c, f) * s3;
    A0S[c] = f2bf(ldf(a0s, c, f));
    A0D[c] = f2bf(ldf(a0d, c, f));
    A1S[c] = f2bf(ldf(a1s, c, f));
    A1D[c] = f2bf(ldf(a1d, c, f));
    GB0[c] = ldf(gb0in, c, f);
    GB1[c] = ldf(gb1in, c, f);
    FB1[c] = ldf(fb1in, c, f);
    if (c < NC) FB2[c] = ldf(fb2in, c, f);
}

// ---------------- all 4 weight transposes fused (B[K,N] -> BT[N,K] bf16) ----------------
__global__ void transpose_all(const unsigned* __restrict__ flag,
                              const void* __restrict__ w1, const void* __restrict__ w2,
                              const void* __restrict__ g0, const void* __restrict__ g1,
                              u16* __restrict__ w1T, u16* __restrict__ w2T,
                              u16* __restrict__ g0T, u16* __restrict__ g1T) {
    int b = blockIdx.x;
    const void* B; u16* BT; int K, logN, base;
    if (b < 128)      { B = w1; BT = w1T; K = FD; logN = 8; base = 0; }
    else if (b < 384) { B = w2; BT = w2T; K = C0; logN = 8; base = 128; }
    else if (b < 896) { B = g0; BT = g0T; K = C0; logN = 9; base = 384; }
    else              { B = g1; BT = g1T; K = C1; logN = 9; base = 896; }
    int idx = (b - base) * 256 + threadIdx.x;
    int N = 1 << logN;
    int k = idx >> logN, n = idx & (N - 1);
    u16 v = (*flag) ? f2bf(((const float*)B)[idx]) : ((const u16*)B)[idx];
    BT[(size_t)n * K + k] = v;
}

// ---------------- CSR build: histograms (pipelined atomics + wave-run gcnt) ----------------
__global__ __launch_bounds__(256) void hist_k(const int* __restrict__ dst, const int* __restrict__ ew,
                                              const int* __restrict__ batch,
                                              int* __restrict__ deg, int* __restrict__ gcnt) {
    int tid = blockIdx.x * 256 + threadIdx.x;
    int lane = threadIdx.x & 63;
    // edges: 4 independent atomic chains per thread (outstanding-transaction pipelining)
#pragma unroll
    for (int j = 0; j < 4; j++) {
        int e = tid + j * EST;
        if (e < EE && ew[e] == 1) atomicAdd(&deg[dst[e]], 1);
    }
    // nodes: batch is sorted -> one atomic per run per wave (kills same-address serialization)
    int n = tid;
    if (n < NN) {
        int g = batch[n];
        int pg = __shfl_up(g, 1);
        bool head = (lane == 0) || (pg != g);
        unsigned long long act = __ballot(1);
        unsigned long long hm  = __ballot(head);
        if (head) {
            unsigned long long above = (lane < 63) ? ((hm >> (lane + 1)) << (lane + 1)) : 0ull;
            int limit = 64 - __builtin_clzll(act);           // highest active lane + 1
            int nxt = above ? __builtin_ctzll(above) : limit;
            atomicAdd(&gcnt[g], nxt - lane);
        }
    }
}
// hierarchical scan over PADDED degrees: (1) per-block local exclusive scan + block totals.
// pdeg = ceil(deg/16)*16 -> every CSR segment is a multiple of 16 (tail-free aggregation).
__global__ __launch_bounds__(256) void scan_blk(const int* __restrict__ deg, int* __restrict__ offP,
                                                int* __restrict__ part) {
    __shared__ int tmp[256];
    int tid = threadIdx.x, i = blockIdx.x * 256 + tid;
    int v = (i < NN) ? ((deg[i] + 15) & ~15) : 0;
    tmp[tid] = v;
    __syncthreads();
#pragma unroll
    for (int s = 1; s < 256; s <<= 1) {
        int a = (tid >= s) ? tmp[tid - s] : 0;
        __syncthreads();
        if (tid >= s) tmp[tid] += a;
        __syncthreads();
    }
    if (i < NN) offP[i] = tmp[tid] - v;   // block-local exclusive (padded)
    if (tid == 255) part[blockIdx.x] = tmp[255];
}
// (2) scan the NBLK partials + scan gcnt -> goff (one small block does both)
__global__ __launch_bounds__(128) void scan_small(int* __restrict__ part, int* __restrict__ ptot,
                                                  const int* __restrict__ gcnt, int* __restrict__ goff) {
    __shared__ int tmp[128];
    int tid = threadIdx.x;
    int v = (tid < NBLK) ? part[tid] : 0;
    tmp[tid] = v;
    __syncthreads();
#pragma unroll
    for (int s = 1; s < 128; s <<= 1) {
        int a = (tid >= s) ? tmp[tid - s] : 0;
        __syncthreads();
        if (tid >= s) tmp[tid] += a;
        __syncthreads();
    }
    if (tid < NBLK) part[tid] = tmp[tid] - v;  // exclusive
    if (tid == 127) *ptot = tmp[127];
    __syncthreads();
    int g = gcnt[tid];
    tmp[tid] = g;
    __syncthreads();
#pragma unroll
    for (int s = 1; s < 128; s <<= 1) {
        int a = (tid >= s) ? tmp[tid - s] : 0;
        __syncthreads();
        if (tid >= s) tmp[tid] += a;
        __syncthreads();
    }
    goff[tid] = tmp[tid] - g;
    if (tid == 127) goff[128] = tmp[127];
}
// (3) add block prefix, emit cursor copy and total
__global__ __launch_bounds__(256) void scan_add(int* __restrict__ offP, const int* __restrict__ part,
                                                const int* __restrict__ ptot, int* __restrict__ cursor) {
    int tid = threadIdx.x, i = blockIdx.x * 256 + tid;
    if (i < NN) {
        int o = offP[i] + part[blockIdx.x];
        offP[i] = o;
        cursor[i] = o;
    }
    if (i == 0) offP[NN] = *ptot;
}
// fill: 4 independent atomic-return chains per thread; real edges fill the FRONT of each
// padded segment (cursor starts at offP[n]); pad slots left uninitialized (gat_prep masks).
__global__ __launch_bounds__(256) void csr_fill(const int* __restrict__ src, const int* __restrict__ dst,
                                                const int* __restrict__ ew,
                                                int* __restrict__ cursor, unsigned* __restrict__ csrcP) {
    int tid = blockIdx.x * 256 + threadIdx.x;
    bool ok[4]; int sv[4]; int p[4];
#pragma unroll
    for (int j = 0; j < 4; j++) {
        int e = tid + j * EST;
        ok[j] = false; sv[j] = 0; p[j] = 0;
        if (e < EE && ew[e] == 1) {
            ok[j] = true;
            sv[j] = src[e];
            p[j] = atomicAdd(&cursor[dst[e]], 1);
        }
    }
#pragma unroll
    for (int j = 0; j < 4; j++) if (ok[j]) csrcP[p[j]] = (unsigned)sv[j];
}

// ---------------- MFMA GEMM (m97-style LDS-staged): C[M,N] = A[M,K] @ B[K,N] ----------------
// 128x128 block, 4 waves 2x2 (64x64 per wave), BK=32, async global->LDS staging.
// EPI: 0 = store raw bf16 row-major; 1 = relu(acc*S[col]+T[col]) row-major;
//      2 = store raw bf16 CHUNK-MAJOR xwt[(col/64)*NN + row][col%64] (requires M==NN)
template <int EPI>
__global__ __launch_bounds__(256) void gemm_tile(const u16* __restrict__ A, const u16* __restrict__ BT,
                                                 u16* __restrict__ Cm,
                                                 const float* __restrict__ S, const float* __restrict__ T,
                                                 int M, int N, int K) {
    __shared__ u16 As[128 * 32];   // [row][k] row-major, unpadded (global_load_lds layout)
    __shared__ u16 Bs[128 * 32];   // [col][k]
    const int tid  = threadIdx.x;
    const int wave = tid >> 6;
    const int lane = tid & 63;
    const int quad = lane >> 4;
    const int l16  = lane & 15;
    const int wr0  = (wave >> 1) * 64;
    const int wc0  = (wave & 1) * 64;
    const int row0 = blockIdx.x * 128;
    const int col0 = blockIdx.y * 128;

    const int lr = lane >> 2;          // 0..15 row within 16-row segment
    const int lk = (lane & 3) * 8;     // 0,8,16,24 element offset in k
    int r0l = wave * 32 + lr;
    int r1l = r0l + 16;
    int gr0 = row0 + r0l; if (gr0 >= M) gr0 = M - 1;   // clamp: loads valid, stores guarded
    int gr1 = row0 + r1l; if (gr1 >= M) gr1 = M - 1;
    const u16* ga0 = A  + (size_t)gr0 * K + lk;
    const u16* ga1 = A  + (size_t)gr1 * K + lk;
    const u16* gb0 = BT + (size_t)(col0 + r0l) * K + lk;
    const u16* gb1 = BT + (size_t)(col0 + r1l) * K + lk;
    u16* la0 = As + (size_t)(wave * 32)      * 32 + lane * 8;
    u16* la1 = As + (size_t)(wave * 32 + 16) * 32 + lane * 8;
    u16* lb0 = Bs + (size_t)(wave * 32)      * 32 + lane * 8;
    u16* lb1 = Bs + (size_t)(wave * 32 + 16) * 32 + lane * 8;

    f32x4_t acc[4][4];
#pragma unroll
    for (int r = 0; r < 4; r++)
#pragma unroll
        for (int c = 0; c < 4; c++)
#pragma unroll
            for (int i = 0; i < 4; i++) acc[r][c][i] = 0.f;

    for (int k0 = 0; k0 < K; k0 += 32) {
        gl_lds16(ga0 + k0, la0);
        gl_lds16(ga1 + k0, la1);
        gl_lds16(gb0 + k0, lb0);
        gl_lds16(gb1 + k0, lb1);
        __syncthreads();   // drains vmcnt (async LDS writes) + all waves

        bf16x8_t a[4], b[4];
#pragma unroll
        for (int r = 0; r < 4; r++)
            a[r] = *(const bf16x8_t*)(As + (size_t)(wr0 + r * 16 + l16) * 32 + quad * 8);
#pragma unroll
        for (int c = 0; c < 4; c++)
            b[c] = *(const bf16x8_t*)(Bs + (size_t)(wc0 + c * 16 + l16) * 32 + quad * 8);
#pragma unroll
        for (int r = 0; r < 4; r++)
#pragma unroll
            for (int c = 0; c < 4; c++)
                acc[r][c] = __builtin_amdgcn_mfma_f32_16x16x32_bf16(a[r], b[c], acc[r][c], 0, 0, 0);
        __syncthreads();   // LDS reads done before next staging overwrites
    }

#pragma unroll
    for (int r = 0; r < 4; r++) {
        int rb = row0 + wr0 + r * 16 + quad * 4;
#pragma unroll
        for (int c = 0; c < 4; c++) {
            int col = col0 + wc0 + c * 16 + l16;
            float sc = (EPI == 1) ? S[col] : 0.f;
            float sh = (EPI == 1) ? T[col] : 0.f;
#pragma unroll
            for (int i = 0; i < 4; i++) {
                int row = rb + i;
                if (row < M) {
                    float v = acc[r][c][i];
                    if (EPI == 1) v = fmaxf(v * sc + sh, 0.f);
                    if (EPI == 2)
                        Cm[((size_t)(col >> 6) * NN + row) * 64 + (col & 63)] = f2bf(v);
                    else
                        Cm[(size_t)row * N + col] = f2bf(v);
                }
            }
        }
    }
}

// ---------------- GAT: per-node attention logits (persistent, fused global max) ----------------
// reads chunk-major xwt; 640 blocks x 4 waves, 1-deep prefetch; block max -> atomicMax.
__global__ __launch_bounds__(256) void gat_logits(const u16* __restrict__ xwt, const u16* __restrict__ asrc,
                                                  const u16* __restrict__ adst, float* __restrict__ ls,
                                                  float* __restrict__ ld, unsigned* __restrict__ gmx) {
    __shared__ float smax[8];
    int lane = threadIdx.x & 63;
    int wv   = threadIdx.x >> 6;
    int h    = lane >> 5;
    // lane covers feats [lane*8, lane*8+8): chunk = lane>>3, offset = (lane&7)*8
    const u16* xb = xwt + (size_t)(lane >> 3) * NN * 64 + (lane & 7) * 8;
    uint4 av = ((const uint4*)asrc)[lane];
    uint4 dv = ((const uint4*)adst)[lane];
    float a[8], d[8];
    unpack8(av, a); unpack8(dv, d);
    float mm = -1e30f;
    int n = blockIdx.x * 4 + wv;
    uint4 xv;
    if (n < NN) xv = *(const uint4*)(xb + (size_t)n * 64);
    while (n < NN) {
        int n2 = n + LGB * 4;
        uint4 nx;
        if (n2 < NN) nx = *(const uint4*)(xb + (size_t)n2 * 64);
        float x[8];
        unpack8(xv, x);
        float ps = 0.f, pd = 0.f;
#pragma unroll
        for (int j = 0; j < 8; j++) { ps += x[j] * a[j]; pd += x[j] * d[j]; }
#pragma unroll
        for (int m = 16; m >= 1; m >>= 1) { ps += __shfl_xor(ps, m); pd += __shfl_xor(pd, m); }
        if ((lane & 31) == 0) {
            ls[n * 2 + h] = ps;
            ld[n * 2 + h] = pd;
        }
        mm = fmaxf(mm, ps);   // all lanes in a 32-group hold the reduced ps
        xv = nx; n = n2;
    }
    if ((lane & 31) == 0) smax[wv * 2 + h] = mm;
    __syncthreads();
    if (threadIdx.x < 2) {
        float m = fmaxf(fmaxf(smax[threadIdx.x], smax[2 + threadIdx.x]),
                        fmaxf(smax[4 + threadIdx.x], smax[6 + threadIdx.x]));
        atomicMax(&gmx[threadIdx.x], encf(m));
    }
}

// ---------------- per-edge packed records PE = {src, p} + denominator per (node,head) ----------
// wave per node; lanes 0..31 -> head 0 over 32-slot windows of the PADDED segment,
// lanes 32..63 -> head 1. Pad slots get {0, 0.0} (src 0 is a valid row; p=0 kills it).
// den = masked butterfly sum, same values/order as before -> identical den.
// Normalization moved to the aggregate epilogue: out = (sum p*x) * inv(den).
__global__ __launch_bounds__(256) void gat_prep(const int* __restrict__ offP, const int* __restrict__ deg,
                                                const unsigned* __restrict__ csrcP,
                                                const float* __restrict__ ls, const float* __restrict__ ld,
                                                const unsigned* __restrict__ gmx,
                                                uint2* __restrict__ PE0, uint2* __restrict__ PE1,
                                                float* __restrict__ denA) {
    int n = blockIdx.x * 4 + (threadIdx.x >> 6);
    if (n >= NN) return;
    int lane = threadIdx.x & 63;
    int h = lane >> 5;
    int el = lane & 31;
    int begP = offP[n], endP = offP[n + 1];
    int d = deg[n];
    float2 ldv = ((const float2*)ld)[n];
    float ldh = h ? ldv.y : ldv.x;
    float gm = decf(gmx[h]) + ldh;
    float mhat = gm > 0.f ? gm : 0.2f * gm;   // leaky is monotone -> valid upper bound
    uint2* __restrict__ PEh = h ? PE1 : PE0;
    float den = 0.f;
    for (int base = begP; base < endP; base += 32) {
        int s = base + el;
        int sc = s < endP ? s : endP - 1;     // half-window when pdeg%32==16
        int j = s - begP;
        bool real = j < d;
        unsigned sv = real ? csrcP[sc] : 0u;  // pad slots -> row 0 (valid), weight 0
        float vv = ls[sv * 2 + h] + ldh;
        vv = vv > 0.f ? vv : 0.2f * vv;
        float p = real ? __expf(vv - mhat) : 0.f;
        float pm = p;
#pragma unroll
        for (int m = 16; m >= 1; m >>= 1) pm += __shfl_xor(pm, m);  // masks <32: stays in half
        den += pm;
        if (s < endP) PEh[s] = make_uint2(sv, __float_as_uint(p));
    }
    if (el == 0) denA[n * 2 + h] = den;       // lanes 0 (h=0) and 32 (h=1)
}

// ---------------- feature-sliced GAT aggregation (R7: padded, packed, tail-free) -------------
// grid (NCH=8, NN/8): blockIdx.x = feature chunk -> round-robins XCDs; each XCD's random
// row gathers hit a 2.56 MB xwt slice that fits its 4 MB L2 (R3: FETCH 188->18 MB).
// R7 vs R6 (VALU-overhead-bound at 59% busy): padded segments (all windows full -> zero
// clamps/selects), packed {src,p} records (4 loads/window instead of 8 + half the addr
// chains), normalization at epilogue. Same mod-4 edge->group classes, same xor-16/32
// butterfly; only the final *inv placement is reassociated (ulp-level, R4 precedent).
__device__ __forceinline__ void agg_win(const uint2* __restrict__ PEh, const u16* __restrict__ xc,
                                        int base, int g,
                                        float& a0, float& a1, float& a2, float& a3) {
    uint2 p0 = PEh[base + g];
    uint2 p1 = PEh[base + 4 + g];
    uint2 p2 = PEh[base + 8 + g];
    uint2 p3 = PEh[base + 12 + g];
    uint2 r0 = *(const uint2*)(xc + (size_t)p0.x * 64);
    uint2 r1 = *(const uint2*)(xc + (size_t)p1.x * 64);
    uint2 r2 = *(const uint2*)(xc + (size_t)p2.x * 64);
    uint2 r3 = *(const uint2*)(xc + (size_t)p3.x * 64);
    float w0 = __uint_as_float(p0.y), w1 = __uint_as_float(p1.y);
    float w2 = __uint_as_float(p2.y), w3 = __uint_as_float(p3.y);
    a0 = fmaf(w0, __uint_as_float(r0.x << 16),         a0);
    a1 = fmaf(w0, __uint_as_float(r0.x & 0xffff0000u), a1);
    a2 = fmaf(w0, __uint_as_float(r0.y << 16),         a2);
    a3 = fmaf(w0, __uint_as_float(r0.y & 0xffff0000u), a3);
    a0 = fmaf(w1, __uint_as_float(r1.x << 16),         a0);
    a1 = fmaf(w1, __uint_as_float(r1.x & 0xffff0000u), a1);
    a2 = fmaf(w1, __uint_as_float(r1.y << 16),         a2);
    a3 = fmaf(w1, __uint_as_float(r1.y & 0xffff0000u), a3);
    a0 = fmaf(w2, __uint_as_float(r2.x << 16),         a0);
    a1 = fmaf(w2, __uint_as_float(r2.x & 0xffff0000u), a1);
    a2 = fmaf(w2, __uint_as_float(r2.y << 16),         a2);
    a3 = fmaf(w2, __uint_as_float(r2.y & 0xffff0000u), a3);
    a0 = fmaf(w3, __uint_as_float(r3.x << 16),         a0);
    a1 = fmaf(w3, __uint_as_float(r3.x & 0xffff0000u), a1);
    a2 = fmaf(w3, __uint_as_float(r3.y << 16),         a2);
    a3 = fmaf(w3, __uint_as_float(r3.y & 0xffff0000u), a3);
}

__global__ __launch_bounds__(256, 6) void gat_aggregate(const int* __restrict__ offP,
                                                        const uint2* __restrict__ PE0,
                                                        const uint2* __restrict__ PE1,
                                                        const float* __restrict__ denA,
                                                        const u16* __restrict__ xwt,
                                                        const float* __restrict__ bias,
                                                        u16* __restrict__ outh) {
    const int c    = blockIdx.x;                       // feature chunk 0..7
    const int nA   = blockIdx.y * 8 + (threadIdx.x >> 6) * 2;   // wave owns nodes nA, nA+1
    const int lane = threadIdx.x & 63;
    const int g    = lane >> 4;                        // edge group 0..3
    const int i    = lane & 15;                        // feat quad: feats i*4..i*4+3
    const int hc   = c >> 2;                           // chunks 0..3 head0, 4..7 head1
    const uint2* __restrict__ PEh = hc ? PE1 : PE0;
    const u16* __restrict__ xc = xwt + (size_t)c * NN * 64 + i * 4;

    int begA = offP[nA], endA = offP[nA + 1], endB = offP[nA + 2];

    float aA0 = 0.f, aA1 = 0.f, aA2 = 0.f, aA3 = 0.f;
    float aB0 = 0.f, aB1 = 0.f, aB2 = 0.f, aB3 = 0.f;

    int bA = begA, bB = endA;
    while (bA < endA && bB < endB) {                   // interleaved: independent chains (MLP x2)
        agg_win(PEh, xc, bA, g, aA0, aA1, aA2, aA3);
        agg_win(PEh, xc, bB, g, aB0, aB1, aB2, aB3);
        bA += 16; bB += 16;
    }
    for (; bA < endA; bA += 16) agg_win(PEh, xc, bA, g, aA0, aA1, aA2, aA3);
    for (; bB < endB; bB += 16) agg_win(PEh, xc, bB, g, aB0, aB1, aB2, aB3);

    float invA = 1.f / fmaxf(denA[nA * 2 + hc], 1e-30f);
    float invB = 1.f / fmaxf(denA[(nA + 1) * 2 + hc], 1e-30f);

    // reduce the 4 edge-group partials (lanes xor 16, 32) for both nodes
#pragma unroll
    for (int m = 16; m <= 32; m <<= 1) {
        aA0 += __shfl_xor(aA0, m); aA1 += __shfl_xor(aA1, m);
        aA2 += __shfl_xor(aA2, m); aA3 += __shfl_xor(aA3, m);
        aB0 += __shfl_xor(aB0, m); aB1 += __shfl_xor(aB1, m);
        aB2 += __shfl_xor(aB2, m); aB3 += __shfl_xor(aB3, m);
    }
    if (g == 0) {
        int f = c * 64 + i * 4;
        const float4 b = *(const float4*)(bias + f);
        uint2 stA, stB;
        stA.x = (unsigned)f2bf(fmaf(aA0, invA, b.x)) | ((unsigned)f2bf(fmaf(aA1, invA, b.y)) << 16);
        stA.y = (unsigned)f2bf(fmaf(aA2, invA, b.z)) | ((unsigned)f2bf(fmaf(aA3, invA, b.w)) << 16);
        stB.x = (unsigned)f2bf(fmaf(aB0, invB, b.x)) | ((unsigned)f2bf(fmaf(aB1, invB, b.y)) << 16);
        stB.y = (unsigned)f2bf(fmaf(aB2, invB, b.z)) | ((unsigned)f2bf(fmaf(aB3, invB, b.w)) << 16);
        *(uint2*)(outh + (size_t)nA * C1 + f) = stA;       // 16 lanes x 8B = 128B
        *(uint2*)(outh + (size_t)(nA + 1) * C1 + f) = stB;
    }
}

// ---------------- fused pool + BN3 + ReLU (block per graph; batch is sorted) ----------------
__global__ __launch_bounds__(512) void pool_bn(const u16* __restrict__ h4, const int* __restrict__ goff,
                                               const float* __restrict__ S3, const float* __restrict__ T3,
                                               u16* __restrict__ z1) {
    int g = blockIdx.x, t = threadIdx.x;
    int b = goff[g], e = goff[g + 1];
    float s = 0.f;
    for (int n = b; n < e; n++) s += bf2f(h4[(size_t)n * C1 + t]);
    float mean = s / fmaxf((float)(e - b), 1.f);
    float v = mean * S3[t] + T3[t];
    z1[(size_t)g * C1 + t] = f2bf(fmaxf(v, 0.f));
}

// ---------------- head ----------------
__global__ __launch_bounds__(512) void head_fc1(const unsigned* __restrict__ flag, const u16* __restrict__ z1,
                                                const void* __restrict__ w1, const float* __restrict__ FB1,
                                                u16* __restrict__ z2) {
    __shared__ float zrow[512];
    int g = blockIdx.x, t = threadIdx.x;
    zrow[t] = bf2f(z1[(size_t)g * 512 + t]);
    __syncthreads();
    float acc = 0.f;
    if (*flag) {
        const float* w = (const float*)w1;
        for (int k = 0; k < 512; k++) acc = fmaf(zrow[k], w[(size_t)k * 512 + t], acc);
    } else {
        const u16* w = (const u16*)w1;
        for (int k = 0; k < 512; k++) acc = fmaf(zrow[k], bf2f(w[(size_t)k * 512 + t]), acc);
    }
    acc += FB1[t];
    z2[(size_t)g * 512 + t] = f2bf(fmaxf(acc, 0.f));
}
__global__ __launch_bounds__(64) void head_fc2(const unsigned* __restrict__ flag, const u16* __restrict__ z2,
                                               const void* __restrict__ w2, const float* __restrict__ FB2,
                                               void* __restrict__ out) {
    int g = blockIdx.x, o = blockIdx.y, lane = threadIdx.x;
    unsigned f = *flag;
    float acc = 0.f;
    if (f) {
        const float* w = (const float*)w2;
        for (int k = lane; k < 512; k += 64) acc += bf2f(z2[(size_t)g * 512 + k]) * w[(size_t)k * NC + o];
    } else {
        const u16* w = (const u16*)w2;
        for (int k = lane; k < 512; k += 64) acc += bf2f(z2[(size_t)g * 512 + k]) * bf2f(w[(size_t)k * NC + o]);
    }
#pragma unroll
    for (int m = 32; m >= 1; m >>= 1) acc += __shfl_xor(acc, m);
    if (lane == 0) {
        float v = acc + FB2[o];
        if (f) ((float*)out)[g * NC + o] = v;
        else   ((u16*)out)[g * NC + o] = f2bf(v);
    }
}

// ---------------- launch ----------------
extern "C" void kernel_launch(void* const* d_in, const int* in_sizes, int n_in,
                              void* d_out, int out_size, void* d_ws, size_t ws_size,
                              hipStream_t stream) {
    (void)in_sizes; (void)n_in; (void)out_size; (void)ws_size;

    const void* x      = d_in[0];
    const int* ei      = (const int*)d_in[1];
    const int* src     = ei;
    const int* dst     = ei + EE;
    const int* ew      = (const int*)d_in[2];
    const int* batch   = (const int*)d_in[3];
    const void* mlp_w1 = d_in[4];
    const void* mlp_b1 = d_in[5];
    const void *bn1g = d_in[6], *bn1b = d_in[7], *bn1m = d_in[8], *bn1v = d_in[9];
    const void* mlp_w2 = d_in[10];
    const void* mlp_b2 = d_in[11];
    const void *bn2g = d_in[12], *bn2b = d_in[13], *bn2m = d_in[14], *bn2v = d_in[15];
    const void* g0w    = d_in[16];
    const void* g0as   = d_in[17];
    const void* g0ad   = d_in[18];
    const void* g0bias = d_in[19];
    const void* g1w    = d_in[20];
    const void* g1as   = d_in[21];
    const void* g1ad   = d_in[22];
    const void* g1bias = d_in[23];
    const void *bn3g = d_in[24], *bn3b = d_in[25], *bn3m = d_in[26], *bn3v = d_in[27];
    const void* fin_w1 = d_in[28];
    const void* fin_b1 = d_in[29];
    const void* fin_w2 = d_in[30];
    const void* fin_b2 = d_in[31];

    char* ws = (char*)d_ws;
    u16*  XB   = (u16*)(ws + OFF_XB);
    u16*  h1   = (u16*)(ws + OFF_H1);
    u16*  h2   = (u16*)(ws + OFF_H2);
    u16*  xwt  = (u16*)(ws + OFF_XW);    // chunk-major [8][NN][64]
    u16*  h34  = (u16*)(ws + OFF_H34);   // row-major [NN][512]
    float* ls  = (float*)(ws + OFF_LS);
    float* ld  = (float*)(ws + OFF_LD);
    int*  deg  = (int*)(ws + OFF_DEG);
    int*  offP = (int*)(ws + OFF_OFFS);  // PADDED offsets (NN+1)
    int*  cur  = (int*)(ws + OFF_CUR);
    unsigned* csrcP = (unsigned*)(ws + OFF_CSP);   // padded edge srcs (real slots only)
    int*  gcnt = (int*)(ws + OFF_GCNT);
    int*  goff = (int*)(ws + OFF_GOFF);
    int*  part = (int*)(ws + OFF_PART);
    int*  ptot = (int*)(ws + OFF_PTOT);
    u16*  z1   = (u16*)(ws + OFF_Z1);
    u16*  z2   = (u16*)(ws + OFF_Z2);
    float* S1 = (float*)(ws + OFF_ST);
    float* T1 = S1 + 256;
    float* S2 = T1 + 256;
    float* T2 = S2 + 256;
    float* S3 = T2 + 256;
    float* T3 = S3 + 512;
    u16* w1T = (u16*)(ws + OFF_W1T);
    u16* w2T = (u16*)(ws + OFF_W2T);
    u16* g0T = (u16*)(ws + OFF_G0T);
    u16* g1T = (u16*)(ws + OFF_G1T);
    unsigned* flag = (unsigned*)(ws + OFF_FLAG);
    u16* A0S = (u16*)(ws + OFF_A0S);
    u16* A0D = (u16*)(ws + OFF_A0D);
    u16* A1S = (u16*)(ws + OFF_A1S);
    u16* A1D = (u16*)(ws + OFF_A1D);
    float* GB0 = (float*)(ws + OFF_GB0);
    float* GB1 = (float*)(ws + OFF_GB1);
    float* FB1 = (float*)(ws + OFF_FB1);
    float* FB2 = (float*)(ws + OFF_FB2);
    unsigned* GMXU = (unsigned*)(ws + OFF_GMX);   // [0..1]=layer0, [2..3]=layer1
    uint2* PE0 = (uint2*)(ws + OFF_PE0);          // packed {src,p} head0 (reuses XB)
    uint2* PE1 = (uint2*)(ws + OFF_PE1);          // packed {src,p} head1 (reuses H1)
    float* denA = (float*)(ws + OFF_DENA);        // per (node,head) denominators

    // dtype detection + input normalization (+ deg/gcnt/gmx init)
    detect_dtype<<<1, 256, 0, stream>>>((const u16*)x, (const u16*)mlp_w1, (const u16*)fin_w1, flag);
    cvt_x<<<(NN * FD / 4) / 256, 256, 0, stream>>>(flag, x, XB, deg, gcnt, GMXU);
    prep_params<<<1, 512, 0, stream>>>(flag,
                                       bn1g, bn1b, bn1m, bn1v, mlp_b1,
                                       bn2g, bn2b, bn2m, bn2v, mlp_b2,
                                       bn3g, bn3b, bn3m, bn3v,
                                       g0as, g0ad, g0bias, g1as, g1ad, g1bias,
                                       fin_b1, fin_b2,
                                       S1, T1, S2, T2, S3, T3,
                                       A0S, A0D, A1S, A1D, GB0, GB1, FB1, FB2);
    transpose_all<<<1920, 256, 0, stream>>>(flag, mlp_w1, mlp_w2, g0w, g1w, w1T, w2T, g0T, g1T);

    // CSR build with PADDED segments (graph fixed across both layers) + graph offsets
    hist_k<<<HB, 256, 0, stream>>>(dst, ew, batch, deg, gcnt);
    scan_blk<<<NBLK, 256, 0, stream>>>(deg, offP, part);
    scan_small<<<1, 128, 0, stream>>>(part, ptot, gcnt, goff);
    scan_add<<<NBLK, 256, 0, stream>>>(offP, part, ptot, cur);
    csr_fill<<<HB, 256, 0, stream>>>(src, dst, ew, cur, csrcP);

    // MLP (157 row-blocks of 128 cover 20096 >= 20000)
    gemm_tile<1><<<dim3(157, 2), 256, 0, stream>>>(XB, w1T, h1, S1, T1, NN, C0, FD);
    gemm_tile<1><<<dim3(157, 2), 256, 0, stream>>>(h1, w2T, h2, S2, T2, NN, C0, C0);

    // GAT layer 0 (xw chunk-major; PE0/PE1 reuse XB/H1 -- both dead after the MLP gemms)
    gemm_tile<2><<<dim3(157, 4), 256, 0, stream>>>(h2, g0T, xwt, nullptr, nullptr, NN, C1, C0);
    gat_logits<<<LGB, 256, 0, stream>>>(xwt, A0S, A0D, ls, ld, GMXU);
    gat_prep<<<NN / 4, 256, 0, stream>>>(offP, deg, csrcP, ls, ld, GMXU, PE0, PE1, denA);
    gat_aggregate<<<dim3(NCH, NN / 8), 256, 0, stream>>>(offP, PE0, PE1, denA, xwt, GB0, h34);

    // GAT layer 1
    gemm_tile<2><<<dim3(157, 4), 256, 0, stream>>>(h34, g1T, xwt, nullptr, nullptr, NN, C1, C1);
    gat_logits<<<LGB, 256, 0, stream>>>(xwt, A1S, A1D, ls, ld, GMXU + 2);
    gat_prep<<<NN / 4, 256, 0, stream>>>(offP, deg, csrcP, ls, ld, GMXU + 2, PE0, PE1, denA);
    gat_aggregate<<<dim3(NCH, NN / 8), 256, 0, stream>>>(offP, PE0, PE1, denA, xwt, GB1, h34);  // h4

    // pool + head
    pool_bn<<<NG, 512, 0, stream>>>(h34, goff, S3, T3, z1);
    head_fc1<<<NG, 512, 0, stream>>>(flag, z1, fin_w1, FB1, z2);
    head_fc2<<<dim3(NG, NC), 64, 0, stream>>>(flag, z2, fin_w2, FB2, d_out);
}

// Round 8
// 443.253 us; speedup vs baseline: 1.0762x; 1.0762x over previous
//
#include <hip/hip_runtime.h>

typedef unsigned short u16;

// ---------------- problem constants ----------------
constexpr int NN = 20000;   // nodes
constexpr int EE = 320000;  // edges
constexpr int FD = 128;     // input features
constexpr int C0 = 256;     // hidden (mlp)
constexpr int C1 = 512;     // H*C for GAT
constexpr int NG = 128;     // graphs
constexpr int NC = 10;      // classes
constexpr int NBLK = (NN + 255) / 256;  // 79
constexpr int HB  = 320;                // hist/fill blocks
constexpr int EST = HB * 256;           // edge stride (81920); 4 chunks cover EE
constexpr int LGB = 640;                // logits blocks (persistent)

// ---------------- workspace layout (bytes) ----------------
constexpr size_t OFF_XB   = 0;                                   // NN*FD bf16 (dead after gemm1 -> reused for P0/P1)
constexpr size_t OFF_H1   = OFF_XB  + (size_t)NN * FD * 2;       // NN*C0 bf16
constexpr size_t OFF_H2   = OFF_H1  + (size_t)NN * C0 * 2;       // NN*C0 bf16
constexpr size_t OFF_XW   = OFF_H2  + (size_t)NN * C0 * 2;       // NN*C1 bf16 (ROW-major xw)
constexpr size_t OFF_H34  = OFF_XW  + (size_t)NN * C1 * 2;       // NN*C1 bf16 (h3 then h4, row-major)
constexpr size_t OFF_LS   = OFF_H34 + (size_t)NN * C1 * 2;       // NN*2 f32
constexpr size_t OFF_LD   = OFF_LS  + (size_t)NN * 2 * 4;        // NN*2 f32
constexpr size_t OFF_DEG  = OFF_LD  + (size_t)NN * 2 * 4;        // NN i32
constexpr size_t OFF_OFFS = OFF_DEG + (size_t)NN * 4;            // NN+1 i32 (pad 80016)
constexpr size_t OFF_CUR  = OFF_OFFS + 80016;                    // NN i32
constexpr size_t OFF_CSRC = OFF_CUR + (size_t)NN * 4;            // EE u16 (region sized for old i32; half used)
constexpr size_t OFF_GCNT = OFF_CSRC + (size_t)EE * 4;           // NG i32
constexpr size_t OFF_GOFF = OFF_GCNT + 512;                      // NG+1 i32 (pad 768)
constexpr size_t OFF_PART = OFF_GOFF + 768;                      // NBLK i32 (pad 512)
constexpr size_t OFF_PTOT = OFF_PART + 512;                      // 1 i32 (pad 256)
constexpr size_t OFF_Z1   = OFF_PTOT + 256;                      // NG*C1 bf16
constexpr size_t OFF_Z2   = OFF_Z1  + (size_t)NG * C1 * 2;
constexpr size_t OFF_ST   = OFF_Z2  + (size_t)NG * C1 * 2;       // S1,T1,S2,T2 (256 f32), S3,T3 (512 f32)
constexpr size_t OFF_W1T  = OFF_ST  + 8192;
constexpr size_t OFF_W2T  = OFF_W1T + (size_t)FD * C0 * 2;
constexpr size_t OFF_G0T  = OFF_W2T + (size_t)C0 * C0 * 2;
constexpr size_t OFF_G1T  = OFF_G0T + (size_t)C0 * C1 * 2;
constexpr size_t OFF_AUX  = OFF_G1T + (size_t)C1 * C1 * 2;
constexpr size_t OFF_FLAG = OFF_AUX  + 0;      // u32
constexpr size_t OFF_A0S  = OFF_AUX  + 256;    // 512 u16
constexpr size_t OFF_A0D  = OFF_AUX  + 1280;
constexpr size_t OFF_A1S  = OFF_AUX  + 2304;
constexpr size_t OFF_A1D  = OFF_AUX  + 3328;
constexpr size_t OFF_GB0  = OFF_AUX  + 4352;   // 512 f32
constexpr size_t OFF_GB1  = OFF_AUX  + 6400;
constexpr size_t OFF_FB1  = OFF_AUX  + 8448;   // 512 f32
constexpr size_t OFF_FB2  = OFF_AUX  + 10496;  // 10 f32 (pad 256)
constexpr size_t OFF_GMX  = OFF_AUX  + 10752;  // 4 u32 (encoded max: layer0 h0,h1; layer1 h0,h1)
// per-edge softmax weights alpha = p/den (f32, per head) -- reuse dead XB region
constexpr size_t OFF_P0   = OFF_XB;            // EE f32
constexpr size_t OFF_P1   = OFF_XB + (size_t)EE * 4;
// end ~= 70 MB

// ---------------- helpers ----------------
__device__ inline float bf2f(u16 u) { return __uint_as_float(((unsigned)u) << 16); }
__device__ inline u16 f2bf(float f) {
    unsigned u = __float_as_uint(f);
    unsigned r = u + 0x7fffu + ((u >> 16) & 1u);   // RNE
    return (u16)(r >> 16);
}
// flag-driven load of an external float input (flag=1 -> f32, 0 -> bf16)
__device__ inline float ldf(const void* p, long i, unsigned f) {
    return f ? ((const float*)p)[i] : bf2f(((const u16*)p)[i]);
}
__device__ inline unsigned encf(float f) {  // monotonic float->uint for atomicMax
    unsigned u = __float_as_uint(f);
    return (u & 0x80000000u) ? ~u : (u | 0x80000000u);
}
__device__ inline float decf(unsigned e) {
    return (e & 0x80000000u) ? __uint_as_float(e ^ 0x80000000u) : __uint_as_float(~e);
}
// 2 VALU ops per 32-bit word (low: shl drops high; high: mask)
__device__ inline void unpack8(uint4 r, float* v) {
    v[0] = __uint_as_float(r.x << 16); v[1] = __uint_as_float(r.x & 0xffff0000u);
    v[2] = __uint_as_float(r.y << 16); v[3] = __uint_as_float(r.y & 0xffff0000u);
    v[4] = __uint_as_float(r.z << 16); v[5] = __uint_as_float(r.z & 0xffff0000u);
    v[6] = __uint_as_float(r.w << 16); v[7] = __uint_as_float(r.w & 0xffff0000u);
}

typedef __bf16 bf16x8_t __attribute__((ext_vector_type(8)));
typedef float  f32x4_t  __attribute__((ext_vector_type(4)));

// async 16B global -> LDS (wave-uniform LDS base + lane*16 layout)
__device__ __forceinline__ void gl_lds16(const u16* g, u16* l) {
    __builtin_amdgcn_global_load_lds((const __attribute__((address_space(1))) void*)g,
                                     (__attribute__((address_space(3))) void*)l, 16, 0, 0);
}

// ---------------- dtype detector ----------------
__global__ void detect_dtype(const u16* __restrict__ x, const u16* __restrict__ w,
                             const u16* __restrict__ fw, unsigned* flag) {
    __shared__ int cnt;
    if (threadIdx.x == 0) cnt = 0;
    __syncthreads();
    int c = 0;
    for (int i = threadIdx.x; i < 4096; i += 256) {
        c += (((x[i]  >> 7) & 0xFF) == 0xFF);
        c += (((w[i]  >> 7) & 0xFF) == 0xFF);
        c += (((fw[i] >> 7) & 0xFF) == 0xFF);
    }
    atomicAdd(&cnt, c);
    __syncthreads();
    if (threadIdx.x == 0) *flag = (cnt >= 2) ? 1u : 0u;  // 1 = f32 inputs
}

// ---------------- x -> internal bf16 copy (+ zero deg/gcnt, init gmx) ----------------
__global__ void cvt_x(const unsigned* __restrict__ flag, const void* __restrict__ xin,
                      u16* __restrict__ XB, int* __restrict__ deg, int* __restrict__ gcnt,
                      unsigned* __restrict__ gmxu) {
    int i = blockIdx.x * 256 + threadIdx.x;  // grid covers NN*FD/4 (2500 blocks)
    if (i < NN) deg[i] = 0;
    if (i < NG) gcnt[i] = 0;
    if (i < 4)  gmxu[i] = encf(-1e30f);
    if (*flag) {
        float4 v = ((const float4*)xin)[i];
        ushort4 r;
        r.x = f2bf(v.x); r.y = f2bf(v.y); r.z = f2bf(v.z); r.w = f2bf(v.w);
        ((ushort4*)XB)[i] = r;
    } else {
        ((ushort4*)XB)[i] = ((const ushort4*)xin)[i];
    }
}

// ---------------- params prep ----------------
__global__ void prep_params(const unsigned* __restrict__ flag,
                            const void* g1, const void* b1, const void* m1, const void* v1, const void* lb1,
                            const void* g2, const void* b2, const void* m2, const void* v2, const void* lb2,
                            const void* g3, const void* b3, const void* m3, const void* v3,
                            const void* a0s, const void* a0d, const void* gb0in,
                            const void* a1s, const void* a1d, const void* gb1in,
                            const void* fb1in, const void* fb2in,
                            float* S1, float* T1, float* S2, float* T2, float* S3, float* T3,
                            u16* A0S, u16* A0D, u16* A1S, u16* A1D,
                            float* GB0, float* GB1, float* FB1, float* FB2) {
    unsigned f = *flag;
    int c = threadIdx.x;  // block 512
    if (c < 256) {
        float s = ldf(g1, c, f) / sqrtf(ldf(v1, c, f) + 1e-5f);
        S1[c] = s; T1[c] = s * (ldf(lb1, c, f) - ldf(m1, c, f)) + ldf(b1, c, f);
        float s2 = ldf(g2, c, f) / sqrtf(ldf(v2, c, f) + 1e-5f);
        S2[c] = s2; T2[c] = s2 * (ldf(lb2, c, f) - ldf(m2, c, f)) + ldf(b2, c, f);
    }
    float s3 = ldf(g3, c, f) / sqrtf(ldf(v3, c, f) + 1e-5f);
    S3[c] = s3; T3[c] = ldf(b3, c, f) - ldf(m3, c, f) * s3;
    A0S[c] = f2bf(ldf(a0s, c, f));
    A0D[c] = f2bf(ldf(a0d, c, f));
    A1S[c] = f2bf(ldf(a1s, c, f));
    A1D[c] = f2bf(ldf(a1d, c, f));
    GB0[c] = ldf(gb0in, c, f);
    GB1[c] = ldf(gb1in, c, f);
    FB1[c] = ldf(fb1in, c, f);
    if (c < NC) FB2[c] = ldf(fb2in, c, f);
}

// ---------------- all 4 weight transposes fused (B[K,N] -> BT[N,K] bf16) ----------------
__global__ void transpose_all(const unsigned* __restrict__ flag,
                              const void* __restrict__ w1, const void* __restrict__ w2,
                              const void* __restrict__ g0, const void* __restrict__ g1,
                              u16* __restrict__ w1T, u16* __restrict__ w2T,
                              u16* __restrict__ g0T, u16* __restrict__ g1T) {
    int b = blockIdx.x;
    const void* B; u16* BT; int K, logN, base;
    if (b < 128)      { B = w1; BT = w1T; K = FD; logN = 8; base = 0; }
    else if (b < 384) { B = w2; BT = w2T; K = C0; logN = 8; base = 128; }
    else if (b < 896) { B = g0; BT = g0T; K = C0; logN = 9; base = 384; }
    else              { B = g1; BT = g1T; K = C1; logN = 9; base = 896; }
    int idx = (b - base) * 256 + threadIdx.x;
    int N = 1 << logN;
    int k = idx >> logN, n = idx & (N - 1);
    u16 v = (*flag) ? f2bf(((const float*)B)[idx]) : ((const u16*)B)[idx];
    BT[(size_t)n * K + k] = v;
}

// ---------------- CSR build: histograms (pipelined atomics + wave-run gcnt) ----------------
__global__ __launch_bounds__(256) void hist_k(const int* __restrict__ dst, const int* __restrict__ ew,
                                              const int* __restrict__ batch,
                                              int* __restrict__ deg, int* __restrict__ gcnt) {
    int tid = blockIdx.x * 256 + threadIdx.x;
    int lane = threadIdx.x & 63;
    // edges: 4 independent atomic chains per thread (outstanding-transaction pipelining)
#pragma unroll
    for (int j = 0; j < 4; j++) {
        int e = tid + j * EST;
        if (e < EE && ew[e] == 1) atomicAdd(&deg[dst[e]], 1);
    }
    // nodes: batch is sorted -> one atomic per run per wave (kills same-address serialization)
    int n = tid;
    if (n < NN) {
        int g = batch[n];
        int pg = __shfl_up(g, 1);
        bool head = (lane == 0) || (pg != g);
        unsigned long long act = __ballot(1);
        unsigned long long hm  = __ballot(head);
        if (head) {
            unsigned long long above = (lane < 63) ? ((hm >> (lane + 1)) << (lane + 1)) : 0ull;
            int limit = 64 - __builtin_clzll(act);           // highest active lane + 1
            int nxt = above ? __builtin_ctzll(above) : limit;
            atomicAdd(&gcnt[g], nxt - lane);
        }
    }
}
// hierarchical scan: (1) per-block local exclusive scan + block totals
__global__ __launch_bounds__(256) void scan_blk(const int* __restrict__ deg, int* __restrict__ off,
                                                int* __restrict__ part) {
    __shared__ int tmp[256];
    int tid = threadIdx.x, i = blockIdx.x * 256 + tid;
    int v = (i < NN) ? deg[i] : 0;
    tmp[tid] = v;
    __syncthreads();
#pragma unroll
    for (int s = 1; s < 256; s <<= 1) {
        int a = (tid >= s) ? tmp[tid - s] : 0;
        __syncthreads();
        if (tid >= s) tmp[tid] += a;
        __syncthreads();
    }
    if (i < NN) off[i] = tmp[tid] - v;   // block-local exclusive
    if (tid == 255) part[blockIdx.x] = tmp[255];
}
// (2) scan the NBLK partials + scan gcnt -> goff (one small block does both)
__global__ __launch_bounds__(128) void scan_small(int* __restrict__ part, int* __restrict__ ptot,
                                                  const int* __restrict__ gcnt, int* __restrict__ goff) {
    __shared__ int tmp[128];
    int tid = threadIdx.x;
    int v = (tid < NBLK) ? part[tid] : 0;
    tmp[tid] = v;
    __syncthreads();
#pragma unroll
    for (int s = 1; s < 128; s <<= 1) {
        int a = (tid >= s) ? tmp[tid - s] : 0;
        __syncthreads();
        if (tid >= s) tmp[tid] += a;
        __syncthreads();
    }
    if (tid < NBLK) part[tid] = tmp[tid] - v;  // exclusive
    if (tid == 127) *ptot = tmp[127];
    __syncthreads();
    int g = gcnt[tid];
    tmp[tid] = g;
    __syncthreads();
#pragma unroll
    for (int s = 1; s < 128; s <<= 1) {
        int a = (tid >= s) ? tmp[tid - s] : 0;
        __syncthreads();
        if (tid >= s) tmp[tid] += a;
        __syncthreads();
    }
    goff[tid] = tmp[tid] - g;
    if (tid == 127) goff[128] = tmp[127];
}
// (3) add block prefix, emit cursor copy and total
__global__ __launch_bounds__(256) void scan_add(int* __restrict__ off, const int* __restrict__ part,
                                                const int* __restrict__ ptot, int* __restrict__ cursor) {
    int tid = threadIdx.x, i = blockIdx.x * 256 + tid;
    if (i < NN) {
        int o = off[i] + part[blockIdx.x];
        off[i] = o;
        cursor[i] = o;
    }
    if (i == 0) off[NN] = *ptot;
}
// fill: 4 independent atomic-return chains per thread; csrc stored u16 (NN < 65536)
__global__ __launch_bounds__(256) void csr_fill(const int* __restrict__ src, const int* __restrict__ dst,
                                                const int* __restrict__ ew,
                                                int* __restrict__ cursor, u16* __restrict__ csrc) {
    int tid = blockIdx.x * 256 + threadIdx.x;
    bool ok[4]; int sv[4]; int p[4];
#pragma unroll
    for (int j = 0; j < 4; j++) {
        int e = tid + j * EST;
        ok[j] = false; sv[j] = 0; p[j] = 0;
        if (e < EE && ew[e] == 1) {
            ok[j] = true;
            sv[j] = src[e];
            p[j] = atomicAdd(&cursor[dst[e]], 1);
        }
    }
#pragma unroll
    for (int j = 0; j < 4; j++) if (ok[j]) csrc[p[j]] = (u16)sv[j];
}

// ---------------- MFMA GEMM (m97-style LDS-staged): C[M,N] = A[M,K] @ B[K,N] ----------------
// 128x128 block, 4 waves 2x2 (64x64 per wave), BK=32, async global->LDS staging.
// EPI: 0 = store raw bf16 row-major; 1 = relu(acc*S[col]+T[col]) row-major
template <int EPI>
__global__ __launch_bounds__(256) void gemm_tile(const u16* __restrict__ A, const u16* __restrict__ BT,
                                                 u16* __restrict__ Cm,
                                                 const float* __restrict__ S, const float* __restrict__ T,
                                                 int M, int N, int K) {
    __shared__ u16 As[128 * 32];   // [row][k] row-major, unpadded (global_load_lds layout)
    __shared__ u16 Bs[128 * 32];   // [col][k]
    const int tid  = threadIdx.x;
    const int wave = tid >> 6;
    const int lane = tid & 63;
    const int quad = lane >> 4;
    const int l16  = lane & 15;
    const int wr0  = (wave >> 1) * 64;
    const int wc0  = (wave & 1) * 64;
    const int row0 = blockIdx.x * 128;
    const int col0 = blockIdx.y * 128;

    const int lr = lane >> 2;          // 0..15 row within 16-row segment
    const int lk = (lane & 3) * 8;     // 0,8,16,24 element offset in k
    int r0l = wave * 32 + lr;
    int r1l = r0l + 16;
    int gr0 = row0 + r0l; if (gr0 >= M) gr0 = M - 1;   // clamp: loads valid, stores guarded
    int gr1 = row0 + r1l; if (gr1 >= M) gr1 = M - 1;
    const u16* ga0 = A  + (size_t)gr0 * K + lk;
    const u16* ga1 = A  + (size_t)gr1 * K + lk;
    const u16* gb0 = BT + (size_t)(col0 + r0l) * K + lk;
    const u16* gb1 = BT + (size_t)(col0 + r1l) * K + lk;
    u16* la0 = As + (size_t)(wave * 32)      * 32 + lane * 8;
    u16* la1 = As + (size_t)(wave * 32 + 16) * 32 + lane * 8;
    u16* lb0 = Bs + (size_t)(wave * 32)      * 32 + lane * 8;
    u16* lb1 = Bs + (size_t)(wave * 32 + 16) * 32 + lane * 8;

    f32x4_t acc[4][4];
#pragma unroll
    for (int r = 0; r < 4; r++)
#pragma unroll
        for (int c = 0; c < 4; c++)
#pragma unroll
            for (int i = 0; i < 4; i++) acc[r][c][i] = 0.f;

    for (int k0 = 0; k0 < K; k0 += 32) {
        gl_lds16(ga0 + k0, la0);
        gl_lds16(ga1 + k0, la1);
        gl_lds16(gb0 + k0, lb0);
        gl_lds16(gb1 + k0, lb1);
        __syncthreads();   // drains vmcnt (async LDS writes) + all waves

        bf16x8_t a[4], b[4];
#pragma unroll
        for (int r = 0; r < 4; r++)
            a[r] = *(const bf16x8_t*)(As + (size_t)(wr0 + r * 16 + l16) * 32 + quad * 8);
#pragma unroll
        for (int c = 0; c < 4; c++)
            b[c] = *(const bf16x8_t*)(Bs + (size_t)(wc0 + c * 16 + l16) * 32 + quad * 8);
#pragma unroll
        for (int r = 0; r < 4; r++)
#pragma unroll
            for (int c = 0; c < 4; c++)
                acc[r][c] = __builtin_amdgcn_mfma_f32_16x16x32_bf16(a[r], b[c], acc[r][c], 0, 0, 0);
        __syncthreads();   // LDS reads done before next staging overwrites
    }

#pragma unroll
    for (int r = 0; r < 4; r++) {
        int rb = row0 + wr0 + r * 16 + quad * 4;
#pragma unroll
        for (int c = 0; c < 4; c++) {
            int col = col0 + wc0 + c * 16 + l16;
            float sc = (EPI == 1) ? S[col] : 0.f;
            float sh = (EPI == 1) ? T[col] : 0.f;
#pragma unroll
            for (int i = 0; i < 4; i++) {
                int row = rb + i;
                if (row < M) {
                    float v = acc[r][c][i];
                    if (EPI == 1) v = fmaxf(v * sc + sh, 0.f);
                    Cm[(size_t)row * N + col] = f2bf(v);
                }
            }
        }
    }
}

// ---------------- GAT: per-node attention logits (persistent, fused global max) ----------------
// row-major xw; 640 blocks x 4 waves, 1-deep prefetch; block max -> atomicMax (max is exact
// under any order -> gmx identical to a separate ls_max kernel).
__global__ __launch_bounds__(256) void gat_logits(const u16* __restrict__ xw, const u16* __restrict__ asrc,
                                                  const u16* __restrict__ adst, float* __restrict__ ls,
                                                  float* __restrict__ ld, unsigned* __restrict__ gmx) {
    __shared__ float smax[8];
    int lane = threadIdx.x & 63;
    int wv   = threadIdx.x >> 6;
    int h    = lane >> 5;
    uint4 av = ((const uint4*)asrc)[lane];
    uint4 dv = ((const uint4*)adst)[lane];
    float a[8], d[8];
    unpack8(av, a); unpack8(dv, d);
    float mm = -1e30f;
    int n = blockIdx.x * 4 + wv;
    uint4 xv;
    if (n < NN) xv = ((const uint4*)(xw + (size_t)n * C1))[lane];
    while (n < NN) {
        int n2 = n + LGB * 4;
        uint4 nx;
        if (n2 < NN) nx = ((const uint4*)(xw + (size_t)n2 * C1))[lane];
        float x[8];
        unpack8(xv, x);
        float ps = 0.f, pd = 0.f;
#pragma unroll
        for (int j = 0; j < 8; j++) { ps += x[j] * a[j]; pd += x[j] * d[j]; }
#pragma unroll
        for (int m = 16; m >= 1; m >>= 1) { ps += __shfl_xor(ps, m); pd += __shfl_xor(pd, m); }
        if ((lane & 31) == 0) {
            ls[n * 2 + h] = ps;
            ld[n * 2 + h] = pd;
        }
        mm = fmaxf(mm, ps);   // all lanes in a 32-group hold the reduced ps
        xv = nx; n = n2;
    }
    if ((lane & 31) == 0) smax[wv * 2 + h] = mm;
    __syncthreads();
    if (threadIdx.x < 2) {
        float m = fmaxf(fmaxf(smax[threadIdx.x], smax[2 + threadIdx.x]),
                        fmaxf(smax[4 + threadIdx.x], smax[6 + threadIdx.x]));
        atomicMax(&gmx[threadIdx.x], encf(m));
    }
}

// ---------------- per-edge softmax weights alpha = p / den (both heads) ----------------
// wave per node; lanes 0..31 -> head 0 over 32-edge windows, lanes 32..63 -> head 1.
// den per window via 32-lane butterfly; alpha written so the aggregation kernel is a
// pure weighted gather (no exp / den / divide in the hot kernel). R4-proven (same absmax).
__global__ __launch_bounds__(256) void gat_prep(const int* __restrict__ off, const u16* __restrict__ csrc,
                                                const float* __restrict__ ls, const float* __restrict__ ld,
                                                const unsigned* __restrict__ gmx,
                                                float* __restrict__ P0, float* __restrict__ P1) {
    int n = blockIdx.x * 4 + (threadIdx.x >> 6);
    if (n >= NN) return;
    int lane = threadIdx.x & 63;
    int h = lane >> 5;
    int el = lane & 31;
    int beg = off[n], end = off[n + 1];
    if (beg >= end) return;
    float2 ldv = ((const float2*)ld)[n];
    float ldh = h ? ldv.y : ldv.x;
    float gm = decf(gmx[h]) + ldh;
    float mhat = gm > 0.f ? gm : 0.2f * gm;   // leaky is monotone -> valid upper bound
    float* __restrict__ Ph = h ? P1 : P0;
    float den = 0.f;
    for (int base = beg; base < end; base += 32) {
        int e = base + el;
        int ec = e < end ? e : end - 1;      // clamp: loads stay valid
        int sv = csrc[ec];
        float vv = ls[sv * 2 + h] + ldh;
        vv = vv > 0.f ? vv : 0.2f * vv;
        float p = __expf(vv - mhat);
        float pm = (e < end) ? p : 0.f;
#pragma unroll
        for (int m = 16; m >= 1; m >>= 1) pm += __shfl_xor(pm, m);  // masks <32: stays in half
        den += pm;
        if (e < end) Ph[e] = p;              // raw p this pass
    }
    float inv = 1.f / fmaxf(den, 1e-30f);
    for (int base = beg; base < end; base += 32) {
        int e = base + el;
        if (e < end) Ph[e] *= inv;           // rescale to alpha (L1-hot, same thread)
    }
}

// ---------------- GAT aggregation (R8: R1 geometry + precomputed alpha) ----------------
// One wave per node (grid NN/4, dispatch-ordered -> R1/R2 L2-locality lesson); lane covers
// feats [lane*8, lane*8+8) of the full 512 (amortizes per-edge cost over all features --
// the R3-R7 slicing multiplied it x8 and never beat this geometry). Per 32-edge chunk:
// coalesced csrc u16 + per-half alpha f32 loads; ONE shfl per edge for the weight; 4-deep
// uint4 row pipeline. alpha precomputed by gat_prep -> no exp/den/divide in the hot loop.
__device__ __forceinline__ void proc_edge(uint4 c, float w, float* acc) {
    float x[8];
    unpack8(c, x);
#pragma unroll
    for (int q = 0; q < 8; q++) acc[q] = fmaf(w, x[q], acc[q]);
}

__global__ __launch_bounds__(256) void gat_aggregate(const int* __restrict__ off, const u16* __restrict__ csrc,
                                                     const float* __restrict__ P0, const float* __restrict__ P1,
                                                     const u16* __restrict__ xw,
                                                     const float* __restrict__ bias, u16* __restrict__ outh) {
    int n = blockIdx.x * 4 + (threadIdx.x >> 6);
    if (n >= NN) return;
    const int lane = threadIdx.x & 63;
    const int h    = lane >> 5;
    const int el   = lane & 31;
    const int hoff = h << 5;
    const float* __restrict__ Ph = h ? P1 : P0;
    int beg = off[n], end = off[n + 1];

    float acc[8];
#pragma unroll
    for (int q = 0; q < 8; q++) acc[q] = 0.f;

#define ROWLD(S) (((const uint4*)(xw + (size_t)(S) * C1))[lane])

    for (int base = beg; base < end; base += 32) {
        int cnt = end - base; if (cnt > 32) cnt = 32;
        int e = base + el;
        int ec = e < end ? e : end - 1;      // clamp: loads stay valid
        int sv = csrc[ec];                   // 32 edge srcs (both halves load same -> broadcast)
        float pv = Ph[ec];                   // alpha for edge (base+el), my head; tail unused

        // 4-deep row pipeline
        uint4 r0 = ROWLD(__shfl(sv, 0));
        uint4 r1 = ROWLD(__shfl(sv, 1));
        uint4 r2 = ROWLD(__shfl(sv, 2));
        uint4 r3 = ROWLD(__shfl(sv, 3));

        for (int j = 0; j < cnt; j += 4) {
            uint4 c0 = r0, c1 = r1, c2 = r2, c3 = r3;
            float w0 = __shfl(pv, j + hoff);
            float w1 = __shfl(pv, j + 1 + hoff);   // out-of-range j -> unused (guarded)
            float w2 = __shfl(pv, j + 2 + hoff);
            float w3 = __shfl(pv, j + 3 + hoff);
            if (j + 4 < cnt) {                     // prefetch next 4 rows (clamped -> valid)
                r0 = ROWLD(__shfl(sv, j + 4));
                r1 = ROWLD(__shfl(sv, j + 5));
                r2 = ROWLD(__shfl(sv, j + 6));
                r3 = ROWLD(__shfl(sv, j + 7));
            }
            proc_edge(c0, w0, acc);
            if (j + 1 < cnt) proc_edge(c1, w1, acc);
            if (j + 2 < cnt) proc_edge(c2, w2, acc);
            if (j + 3 < cnt) proc_edge(c3, w3, acc);
        }
    }
#undef ROWLD

    int cb = lane * 8;
    const float4* bp = (const float4*)(bias + cb);
    float4 b0 = bp[0], b1 = bp[1];
    uint4 st;
    st.x = (unsigned)f2bf(acc[0] + b0.x) | ((unsigned)f2bf(acc[1] + b0.y) << 16);
    st.y = (unsigned)f2bf(acc[2] + b0.z) | ((unsigned)f2bf(acc[3] + b0.w) << 16);
    st.z = (unsigned)f2bf(acc[4] + b1.x) | ((unsigned)f2bf(acc[5] + b1.y) << 16);
    st.w = (unsigned)f2bf(acc[6] + b1.z) | ((unsigned)f2bf(acc[7] + b1.w) << 16);
    ((uint4*)(outh + (size_t)n * C1 + cb))[0] = st;
}

// ---------------- fused pool + BN3 + ReLU (block per graph; batch is sorted) ----------------
__global__ __launch_bounds__(512) void pool_bn(const u16* __restrict__ h4, const int* __restrict__ goff,
                                               const float* __restrict__ S3, const float* __restrict__ T3,
                                               u16* __restrict__ z1) {
    int g = blockIdx.x, t = threadIdx.x;
    int b = goff[g], e = goff[g + 1];
    float s = 0.f;
    for (int n = b; n < e; n++) s += bf2f(h4[(size_t)n * C1 + t]);
    float mean = s / fmaxf((float)(e - b), 1.f);
    float v = mean * S3[t] + T3[t];
    z1[(size_t)g * C1 + t] = f2bf(fmaxf(v, 0.f));
}

// ---------------- head ----------------
__global__ __launch_bounds__(512) void head_fc1(const unsigned* __restrict__ flag, const u16* __restrict__ z1,
                                                const void* __restrict__ w1, const float* __restrict__ FB1,
                                                u16* __restrict__ z2) {
    __shared__ float zrow[512];
    int g = blockIdx.x, t = threadIdx.x;
    zrow[t] = bf2f(z1[(size_t)g * 512 + t]);
    __syncthreads();
    float acc = 0.f;
    if (*flag) {
        const float* w = (const float*)w1;
        for (int k = 0; k < 512; k++) acc = fmaf(zrow[k], w[(size_t)k * 512 + t], acc);
    } else {
        const u16* w = (const u16*)w1;
        for (int k = 0; k < 512; k++) acc = fmaf(zrow[k], bf2f(w[(size_t)k * 512 + t]), acc);
    }
    acc += FB1[t];
    z2[(size_t)g * 512 + t] = f2bf(fmaxf(acc, 0.f));
}
__global__ __launch_bounds__(64) void head_fc2(const unsigned* __restrict__ flag, const u16* __restrict__ z2,
                                               const void* __restrict__ w2, const float* __restrict__ FB2,
                                               void* __restrict__ out) {
    int g = blockIdx.x, o = blockIdx.y, lane = threadIdx.x;
    unsigned f = *flag;
    float acc = 0.f;
    if (f) {
        const float* w = (const float*)w2;
        for (int k = lane; k < 512; k += 64) acc += bf2f(z2[(size_t)g * 512 + k]) * w[(size_t)k * NC + o];
    } else {
        const u16* w = (const u16*)w2;
        for (int k = lane; k < 512; k += 64) acc += bf2f(z2[(size_t)g * 512 + k]) * bf2f(w[(size_t)k * NC + o]);
    }
#pragma unroll
    for (int m = 32; m >= 1; m >>= 1) acc += __shfl_xor(acc, m);
    if (lane == 0) {
        float v = acc + FB2[o];
        if (f) ((float*)out)[g * NC + o] = v;
        else   ((u16*)out)[g * NC + o] = f2bf(v);
    }
}

// ---------------- launch ----------------
extern "C" void kernel_launch(void* const* d_in, const int* in_sizes, int n_in,
                              void* d_out, int out_size, void* d_ws, size_t ws_size,
                              hipStream_t stream) {
    (void)in_sizes; (void)n_in; (void)out_size; (void)ws_size;

    const void* x      = d_in[0];
    const int* ei      = (const int*)d_in[1];
    const int* src     = ei;
    const int* dst     = ei + EE;
    const int* ew      = (const int*)d_in[2];
    const int* batch   = (const int*)d_in[3];
    const void* mlp_w1 = d_in[4];
    const void* mlp_b1 = d_in[5];
    const void *bn1g = d_in[6], *bn1b = d_in[7], *bn1m = d_in[8], *bn1v = d_in[9];
    const void* mlp_w2 = d_in[10];
    const void* mlp_b2 = d_in[11];
    const void *bn2g = d_in[12], *bn2b = d_in[13], *bn2m = d_in[14], *bn2v = d_in[15];
    const void* g0w    = d_in[16];
    const void* g0as   = d_in[17];
    const void* g0ad   = d_in[18];
    const void* g0bias = d_in[19];
    const void* g1w    = d_in[20];
    const void* g1as   = d_in[21];
    const void* g1ad   = d_in[22];
    const void* g1bias = d_in[23];
    const void *bn3g = d_in[24], *bn3b = d_in[25], *bn3m = d_in[26], *bn3v = d_in[27];
    const void* fin_w1 = d_in[28];
    const void* fin_b1 = d_in[29];
    const void* fin_w2 = d_in[30];
    const void* fin_b2 = d_in[31];

    char* ws = (char*)d_ws;
    u16*  XB   = (u16*)(ws + OFF_XB);
    u16*  h1   = (u16*)(ws + OFF_H1);
    u16*  h2   = (u16*)(ws + OFF_H2);
    u16*  xw   = (u16*)(ws + OFF_XW);    // row-major [NN][512]
    u16*  h34  = (u16*)(ws + OFF_H34);   // row-major [NN][512]
    float* ls  = (float*)(ws + OFF_LS);
    float* ld  = (float*)(ws + OFF_LD);
    int*  deg  = (int*)(ws + OFF_DEG);
    int*  off  = (int*)(ws + OFF_OFFS);
    int*  cur  = (int*)(ws + OFF_CUR);
    u16*  csrc = (u16*)(ws + OFF_CSRC);
    int*  gcnt = (int*)(ws + OFF_GCNT);
    int*  goff = (int*)(ws + OFF_GOFF);
    int*  part = (int*)(ws + OFF_PART);
    int*  ptot = (int*)(ws + OFF_PTOT);
    u16*  z1   = (u16*)(ws + OFF_Z1);
    u16*  z2   = (u16*)(ws + OFF_Z2);
    float* S1 = (float*)(ws + OFF_ST);
    float* T1 = S1 + 256;
    float* S2 = T1 + 256;
    float* T2 = S2 + 256;
    float* S3 = T2 + 256;
    float* T3 = S3 + 512;
    u16* w1T = (u16*)(ws + OFF_W1T);
    u16* w2T = (u16*)(ws + OFF_W2T);
    u16* g0T = (u16*)(ws + OFF_G0T);
    u16* g1T = (u16*)(ws + OFF_G1T);
    unsigned* flag = (unsigned*)(ws + OFF_FLAG);
    u16* A0S = (u16*)(ws + OFF_A0S);
    u16* A0D = (u16*)(ws + OFF_A0D);
    u16* A1S = (u16*)(ws + OFF_A1S);
    u16* A1D = (u16*)(ws + OFF_A1D);
    float* GB0 = (float*)(ws + OFF_GB0);
    float* GB1 = (float*)(ws + OFF_GB1);
    float* FB1 = (float*)(ws + OFF_FB1);
    float* FB2 = (float*)(ws + OFF_FB2);
    unsigned* GMXU = (unsigned*)(ws + OFF_GMX);   // [0..1]=layer0, [2..3]=layer1
    float* P0 = (float*)(ws + OFF_P0);            // per-edge alpha, head0 (reuses XB region)
    float* P1 = (float*)(ws + OFF_P1);            // per-edge alpha, head1

    // dtype detection + input normalization (+ deg/gcnt/gmx init)
    detect_dtype<<<1, 256, 0, stream>>>((const u16*)x, (const u16*)mlp_w1, (const u16*)fin_w1, flag);
    cvt_x<<<(NN * FD / 4) / 256, 256, 0, stream>>>(flag, x, XB, deg, gcnt, GMXU);
    prep_params<<<1, 512, 0, stream>>>(flag,
                                       bn1g, bn1b, bn1m, bn1v, mlp_b1,
                                       bn2g, bn2b, bn2m, bn2v, mlp_b2,
                                       bn3g, bn3b, bn3m, bn3v,
                                       g0as, g0ad, g0bias, g1as, g1ad, g1bias,
                                       fin_b1, fin_b2,
                                       S1, T1, S2, T2, S3, T3,
                                       A0S, A0D, A1S, A1D, GB0, GB1, FB1, FB2);
    transpose_all<<<1920, 256, 0, stream>>>(flag, mlp_w1, mlp_w2, g0w, g1w, w1T, w2T, g0T, g1T);

    // CSR build (graph fixed across both layers) + graph offsets
    hist_k<<<HB, 256, 0, stream>>>(dst, ew, batch, deg, gcnt);
    scan_blk<<<NBLK, 256, 0, stream>>>(deg, off, part);
    scan_small<<<1, 128, 0, stream>>>(part, ptot, gcnt, goff);
    scan_add<<<NBLK, 256, 0, stream>>>(off, part, ptot, cur);
    csr_fill<<<HB, 256, 0, stream>>>(src, dst, ew, cur, csrc);

    // MLP (157 row-blocks of 128 cover 20096 >= 20000)
    gemm_tile<1><<<dim3(157, 2), 256, 0, stream>>>(XB, w1T, h1, S1, T1, NN, C0, FD);
    gemm_tile<1><<<dim3(157, 2), 256, 0, stream>>>(h1, w2T, h2, S2, T2, NN, C0, C0);

    // GAT layer 0 (xw row-major; P0/P1 reuse XB region -- XB dead after gemm 1)
    gemm_tile<0><<<dim3(157, 4), 256, 0, stream>>>(h2, g0T, xw, nullptr, nullptr, NN, C1, C0);
    gat_logits<<<LGB, 256, 0, stream>>>(xw, A0S, A0D, ls, ld, GMXU);
    gat_prep<<<NN / 4, 256, 0, stream>>>(off, csrc, ls, ld, GMXU, P0, P1);
    gat_aggregate<<<NN / 4, 256, 0, stream>>>(off, csrc, P0, P1, xw, GB0, h34);

    // GAT layer 1
    gemm_tile<0><<<dim3(157, 4), 256, 0, stream>>>(h34, g1T, xw, nullptr, nullptr, NN, C1, C1);
    gat_logits<<<LGB, 256, 0, stream>>>(xw, A1S, A1D, ls, ld, GMXU + 2);
    gat_prep<<<NN / 4, 256, 0, stream>>>(off, csrc, ls, ld, GMXU + 2, P0, P1);
    gat_aggregate<<<NN / 4, 256, 0, stream>>>(off, csrc, P0, P1, xw, GB1, h34);  // h4

    // pool + head
    pool_bn<<<NG, 512, 0, stream>>>(h34, goff, S3, T3, z1);
    head_fc1<<<NG, 512, 0, stream>>>(flag, z1, fin_w1, FB1, z2);
    head_fc2<<<dim3(NG, NC), 64, 0, stream>>>(flag, z2, fin_w2, FB2, d_out);
}

// Round 9
// 407.149 us; speedup vs baseline: 1.1716x; 1.0887x over previous
//
#include <hip/hip_runtime.h>

typedef unsigned short u16;

// ---------------- problem constants ----------------
constexpr int NN = 20000;   // nodes
constexpr int EE = 320000;  // edges
constexpr int FD = 128;     // input features
constexpr int C0 = 256;     // hidden (mlp)
constexpr int C1 = 512;     // H*C for GAT
constexpr int NG = 128;     // graphs
constexpr int NC = 10;      // classes
constexpr int NBLK = (NN + 255) / 256;  // 79
constexpr int HB  = 320;                // hist/fill blocks
constexpr int EST = HB * 256;           // edge stride (81920); 4 chunks cover EE
constexpr int LGB = 640;                // logits blocks (persistent)
constexpr int PSPL = 16;                // pooling slices per graph

// ---------------- workspace layout (bytes) ----------------
constexpr size_t OFF_XB   = 0;                                   // NN*FD bf16 (dead after gemm1 -> reused for P0/P1)
constexpr size_t OFF_H1   = OFF_XB  + (size_t)NN * FD * 2;       // NN*C0 bf16
constexpr size_t OFF_H2   = OFF_H1  + (size_t)NN * C0 * 2;       // NN*C0 bf16
constexpr size_t OFF_XW   = OFF_H2  + (size_t)NN * C0 * 2;       // NN*C1 bf16 (ROW-major xw)
constexpr size_t OFF_H34  = OFF_XW  + (size_t)NN * C1 * 2;       // NN*C1 bf16 (h3 then h4, row-major)
constexpr size_t OFF_LS   = OFF_H34 + (size_t)NN * C1 * 2;       // NN*2 f32
constexpr size_t OFF_LD   = OFF_LS  + (size_t)NN * 2 * 4;        // NN*2 f32
constexpr size_t OFF_DEG  = OFF_LD  + (size_t)NN * 2 * 4;        // NN i32
constexpr size_t OFF_OFFS = OFF_DEG + (size_t)NN * 4;            // NN+1 i32 (pad 80016)
constexpr size_t OFF_CUR  = OFF_OFFS + 80016;                    // NN i32
constexpr size_t OFF_CSRC = OFF_CUR + (size_t)NN * 4;            // EE u16 (region sized for old i32; half used)
constexpr size_t OFF_GCNT = OFF_CSRC + (size_t)EE * 4;           // NG i32
constexpr size_t OFF_GOFF = OFF_GCNT + 512;                      // NG+1 i32 (pad 768)
constexpr size_t OFF_PART = OFF_GOFF + 768;                      // NBLK i32 (pad 512)
constexpr size_t OFF_PTOT = OFF_PART + 512;                      // 1 i32 (pad 256)
constexpr size_t OFF_Z1   = OFF_PTOT + 256;                      // NG*C1 bf16
constexpr size_t OFF_Z2   = OFF_Z1  + (size_t)NG * C1 * 2;
constexpr size_t OFF_ST   = OFF_Z2  + (size_t)NG * C1 * 2;       // S1,T1,S2,T2 (256 f32), S3,T3 (512 f32)
constexpr size_t OFF_W1T  = OFF_ST  + 8192;
constexpr size_t OFF_W2T  = OFF_W1T + (size_t)FD * C0 * 2;
constexpr size_t OFF_G0T  = OFF_W2T + (size_t)C0 * C0 * 2;
constexpr size_t OFF_G1T  = OFF_G0T + (size_t)C0 * C1 * 2;
constexpr size_t OFF_AUX  = OFF_G1T + (size_t)C1 * C1 * 2;
constexpr size_t OFF_FLAG = OFF_AUX  + 0;      // u32
constexpr size_t OFF_A0S  = OFF_AUX  + 256;    // 512 u16
constexpr size_t OFF_A0D  = OFF_AUX  + 1280;
constexpr size_t OFF_A1S  = OFF_AUX  + 2304;
constexpr size_t OFF_A1D  = OFF_AUX  + 3328;
constexpr size_t OFF_GB0  = OFF_AUX  + 4352;   // 512 f32
constexpr size_t OFF_GB1  = OFF_AUX  + 6400;
constexpr size_t OFF_FB1  = OFF_AUX  + 8448;   // 512 f32
constexpr size_t OFF_FB2  = OFF_AUX  + 10496;  // 10 f32 (pad 256)
constexpr size_t OFF_GMX  = OFF_AUX  + 10752;  // 4 u32 (pad 256)
constexpr size_t OFF_PP   = OFF_AUX  + 11008;  // f32[NG][PSPL][C1] pooling partials (4 MB)
// per-edge softmax weights alpha = p/den (f32, per head) -- reuse dead XB region
constexpr size_t OFF_P0   = OFF_XB;            // EE f32
constexpr size_t OFF_P1   = OFF_XB + (size_t)EE * 4;
// end ~= 74 MB

// ---------------- helpers ----------------
__device__ inline float bf2f(u16 u) { return __uint_as_float(((unsigned)u) << 16); }
__device__ inline u16 f2bf(float f) {
    unsigned u = __float_as_uint(f);
    unsigned r = u + 0x7fffu + ((u >> 16) & 1u);   // RNE
    return (u16)(r >> 16);
}
// flag-driven load of an external float input (flag=1 -> f32, 0 -> bf16)
__device__ inline float ldf(const void* p, long i, unsigned f) {
    return f ? ((const float*)p)[i] : bf2f(((const u16*)p)[i]);
}
__device__ inline unsigned encf(float f) {  // monotonic float->uint for atomicMax
    unsigned u = __float_as_uint(f);
    return (u & 0x80000000u) ? ~u : (u | 0x80000000u);
}
__device__ inline float decf(unsigned e) {
    return (e & 0x80000000u) ? __uint_as_float(e ^ 0x80000000u) : __uint_as_float(~e);
}
// 2 VALU ops per 32-bit word (low: shl drops high; high: mask)
__device__ inline void unpack8(uint4 r, float* v) {
    v[0] = __uint_as_float(r.x << 16); v[1] = __uint_as_float(r.x & 0xffff0000u);
    v[2] = __uint_as_float(r.y << 16); v[3] = __uint_as_float(r.y & 0xffff0000u);
    v[4] = __uint_as_float(r.z << 16); v[5] = __uint_as_float(r.z & 0xffff0000u);
    v[6] = __uint_as_float(r.w << 16); v[7] = __uint_as_float(r.w & 0xffff0000u);
}

typedef __bf16 bf16x8_t __attribute__((ext_vector_type(8)));
typedef float  f32x4_t  __attribute__((ext_vector_type(4)));

// async 16B global -> LDS (wave-uniform LDS base + lane*16 layout)
__device__ __forceinline__ void gl_lds16(const u16* g, u16* l) {
    __builtin_amdgcn_global_load_lds((const __attribute__((address_space(1))) void*)g,
                                     (__attribute__((address_space(3))) void*)l, 16, 0, 0);
}

// ---------------- dtype detector ----------------
__global__ void detect_dtype(const u16* __restrict__ x, const u16* __restrict__ w,
                             const u16* __restrict__ fw, unsigned* flag) {
    __shared__ int cnt;
    if (threadIdx.x == 0) cnt = 0;
    __syncthreads();
    int c = 0;
    for (int i = threadIdx.x; i < 4096; i += 256) {
        c += (((x[i]  >> 7) & 0xFF) == 0xFF);
        c += (((w[i]  >> 7) & 0xFF) == 0xFF);
        c += (((fw[i] >> 7) & 0xFF) == 0xFF);
    }
    atomicAdd(&cnt, c);
    __syncthreads();
    if (threadIdx.x == 0) *flag = (cnt >= 2) ? 1u : 0u;  // 1 = f32 inputs
}

// ---------------- x -> internal bf16 copy (+ zero deg/gcnt, init gmx) ----------------
__global__ void cvt_x(const unsigned* __restrict__ flag, const void* __restrict__ xin,
                      u16* __restrict__ XB, int* __restrict__ deg, int* __restrict__ gcnt,
                      unsigned* __restrict__ gmxu) {
    int i = blockIdx.x * 256 + threadIdx.x;  // grid covers NN*FD/4 (2500 blocks)
    if (i < NN) deg[i] = 0;
    if (i < NG) gcnt[i] = 0;
    if (i < 4)  gmxu[i] = encf(-1e30f);
    if (*flag) {
        float4 v = ((const float4*)xin)[i];
        ushort4 r;
        r.x = f2bf(v.x); r.y = f2bf(v.y); r.z = f2bf(v.z); r.w = f2bf(v.w);
        ((ushort4*)XB)[i] = r;
    } else {
        ((ushort4*)XB)[i] = ((const ushort4*)xin)[i];
    }
}

// ---------------- params prep ----------------
__global__ void prep_params(const unsigned* __restrict__ flag,
                            const void* g1, const void* b1, const void* m1, const void* v1, const void* lb1,
                            const void* g2, const void* b2, const void* m2, const void* v2, const void* lb2,
                            const void* g3, const void* b3, const void* m3, const void* v3,
                            const void* a0s, const void* a0d, const void* gb0in,
                            const void* a1s, const void* a1d, const void* gb1in,
                            const void* fb1in, const void* fb2in,
                            float* S1, float* T1, float* S2, float* T2, float* S3, float* T3,
                            u16* A0S, u16* A0D, u16* A1S, u16* A1D,
                            float* GB0, float* GB1, float* FB1, float* FB2) {
    unsigned f = *flag;
    int c = threadIdx.x;  // block 512
    if (c < 256) {
        float s = ldf(g1, c, f) / sqrtf(ldf(v1, c, f) + 1e-5f);
        S1[c] = s; T1[c] = s * (ldf(lb1, c, f) - ldf(m1, c, f)) + ldf(b1, c, f);
        float s2 = ldf(g2, c, f) / sqrtf(ldf(v2, c, f) + 1e-5f);
        S2[c] = s2; T2[c] = s2 * (ldf(lb2, c, f) - ldf(m2, c, f)) + ldf(b2, c, f);
    }
    float s3 = ldf(g3, c, f) / sqrtf(ldf(v3, c, f) + 1e-5f);
    S3[c] = s3; T3[c] = ldf(b3, c, f) - ldf(m3, c, f) * s3;
    A0S[c] = f2bf(ldf(a0s, c, f));
    A0D[c] = f2bf(ldf(a0d, c, f));
    A1S[c] = f2bf(ldf(a1s, c, f));
    A1D[c] = f2bf(ldf(a1d, c, f));
    GB0[c] = ldf(gb0in, c, f);
    GB1[c] = ldf(gb1in, c, f);
    FB1[c] = ldf(fb1in, c, f);
    if (c < NC) FB2[c] = ldf(fb2in, c, f);
}

// ---------------- all 4 weight transposes fused (B[K,N] -> BT[N,K] bf16) ----------------
__global__ void transpose_all(const unsigned* __restrict__ flag,
                              const void* __restrict__ w1, const void* __restrict__ w2,
                              const void* __restrict__ g0, const void* __restrict__ g1,
                              u16* __restrict__ w1T, u16* __restrict__ w2T,
                              u16* __restrict__ g0T, u16* __restrict__ g1T) {
    int b = blockIdx.x;
    const void* B; u16* BT; int K, logN, base;
    if (b < 128)      { B = w1; BT = w1T; K = FD; logN = 8; base = 0; }
    else if (b < 384) { B = w2; BT = w2T; K = C0; logN = 8; base = 128; }
    else if (b < 896) { B = g0; BT = g0T; K = C0; logN = 9; base = 384; }
    else              { B = g1; BT = g1T; K = C1; logN = 9; base = 896; }
    int idx = (b - base) * 256 + threadIdx.x;
    int N = 1 << logN;
    int k = idx >> logN, n = idx & (N - 1);
    u16 v = (*flag) ? f2bf(((const float*)B)[idx]) : ((const u16*)B)[idx];
    BT[(size_t)n * K + k] = v;
}

// ---------------- CSR build: histograms (pipelined atomics + wave-run gcnt) ----------------
__global__ __launch_bounds__(256) void hist_k(const int* __restrict__ dst, const int* __restrict__ ew,
                                              const int* __restrict__ batch,
                                              int* __restrict__ deg, int* __restrict__ gcnt) {
    int tid = blockIdx.x * 256 + threadIdx.x;
    int lane = threadIdx.x & 63;
    // edges: 4 independent atomic chains per thread (outstanding-transaction pipelining)
#pragma unroll
    for (int j = 0; j < 4; j++) {
        int e = tid + j * EST;
        if (e < EE && ew[e] == 1) atomicAdd(&deg[dst[e]], 1);
    }
    // nodes: batch is sorted -> one atomic per run per wave (kills same-address serialization)
    int n = tid;
    if (n < NN) {
        int g = batch[n];
        int pg = __shfl_up(g, 1);
        bool head = (lane == 0) || (pg != g);
        unsigned long long act = __ballot(1);
        unsigned long long hm  = __ballot(head);
        if (head) {
            unsigned long long above = (lane < 63) ? ((hm >> (lane + 1)) << (lane + 1)) : 0ull;
            int limit = 64 - __builtin_clzll(act);           // highest active lane + 1
            int nxt = above ? __builtin_ctzll(above) : limit;
            atomicAdd(&gcnt[g], nxt - lane);
        }
    }
}
// hierarchical scan: (1) per-block local exclusive scan + block totals
__global__ __launch_bounds__(256) void scan_blk(const int* __restrict__ deg, int* __restrict__ off,
                                                int* __restrict__ part) {
    __shared__ int tmp[256];
    int tid = threadIdx.x, i = blockIdx.x * 256 + tid;
    int v = (i < NN) ? deg[i] : 0;
    tmp[tid] = v;
    __syncthreads();
#pragma unroll
    for (int s = 1; s < 256; s <<= 1) {
        int a = (tid >= s) ? tmp[tid - s] : 0;
        __syncthreads();
        if (tid >= s) tmp[tid] += a;
        __syncthreads();
    }
    if (i < NN) off[i] = tmp[tid] - v;   // block-local exclusive
    if (tid == 255) part[blockIdx.x] = tmp[255];
}
// (2) scan the NBLK partials + scan gcnt -> goff (one small block does both)
__global__ __launch_bounds__(128) void scan_small(int* __restrict__ part, int* __restrict__ ptot,
                                                  const int* __restrict__ gcnt, int* __restrict__ goff) {
    __shared__ int tmp[128];
    int tid = threadIdx.x;
    int v = (tid < NBLK) ? part[tid] : 0;
    tmp[tid] = v;
    __syncthreads();
#pragma unroll
    for (int s = 1; s < 128; s <<= 1) {
        int a = (tid >= s) ? tmp[tid - s] : 0;
        __syncthreads();
        if (tid >= s) tmp[tid] += a;
        __syncthreads();
    }
    if (tid < NBLK) part[tid] = tmp[tid] - v;  // exclusive
    if (tid == 127) *ptot = tmp[127];
    __syncthreads();
    int g = gcnt[tid];
    tmp[tid] = g;
    __syncthreads();
#pragma unroll
    for (int s = 1; s < 128; s <<= 1) {
        int a = (tid >= s) ? tmp[tid - s] : 0;
        __syncthreads();
        if (tid >= s) tmp[tid] += a;
        __syncthreads();
    }
    goff[tid] = tmp[tid] - g;
    if (tid == 127) goff[128] = tmp[127];
}
// (3) add block prefix, emit cursor copy and total
__global__ __launch_bounds__(256) void scan_add(int* __restrict__ off, const int* __restrict__ part,
                                                const int* __restrict__ ptot, int* __restrict__ cursor) {
    int tid = threadIdx.x, i = blockIdx.x * 256 + tid;
    if (i < NN) {
        int o = off[i] + part[blockIdx.x];
        off[i] = o;
        cursor[i] = o;
    }
    if (i == 0) off[NN] = *ptot;
}
// fill: 4 independent atomic-return chains per thread; csrc stored u16 (NN < 65536)
__global__ __launch_bounds__(256) void csr_fill(const int* __restrict__ src, const int* __restrict__ dst,
                                                const int* __restrict__ ew,
                                                int* __restrict__ cursor, u16* __restrict__ csrc) {
    int tid = blockIdx.x * 256 + threadIdx.x;
    bool ok[4]; int sv[4]; int p[4];
#pragma unroll
    for (int j = 0; j < 4; j++) {
        int e = tid + j * EST;
        ok[j] = false; sv[j] = 0; p[j] = 0;
        if (e < EE && ew[e] == 1) {
            ok[j] = true;
            sv[j] = src[e];
            p[j] = atomicAdd(&cursor[dst[e]], 1);
        }
    }
#pragma unroll
    for (int j = 0; j < 4; j++) if (ok[j]) csrc[p[j]] = (u16)sv[j];
}

// ---------------- MFMA GEMM (m97-style LDS-staged): C[M,N] = A[M,K] @ B[K,N] ----------------
// 128x128 block, 4 waves 2x2 (64x64 per wave), BK=32, async global->LDS staging.
// EPI: 0 = store raw bf16 row-major; 1 = relu(acc*S[col]+T[col]) row-major
template <int EPI>
__global__ __launch_bounds__(256) void gemm_tile(const u16* __restrict__ A, const u16* __restrict__ BT,
                                                 u16* __restrict__ Cm,
                                                 const float* __restrict__ S, const float* __restrict__ T,
                                                 int M, int N, int K) {
    __shared__ u16 As[128 * 32];   // [row][k] row-major, unpadded (global_load_lds layout)
    __shared__ u16 Bs[128 * 32];   // [col][k]
    const int tid  = threadIdx.x;
    const int wave = tid >> 6;
    const int lane = tid & 63;
    const int quad = lane >> 4;
    const int l16  = lane & 15;
    const int wr0  = (wave >> 1) * 64;
    const int wc0  = (wave & 1) * 64;
    const int row0 = blockIdx.x * 128;
    const int col0 = blockIdx.y * 128;

    const int lr = lane >> 2;          // 0..15 row within 16-row segment
    const int lk = (lane & 3) * 8;     // 0,8,16,24 element offset in k
    int r0l = wave * 32 + lr;
    int r1l = r0l + 16;
    int gr0 = row0 + r0l; if (gr0 >= M) gr0 = M - 1;   // clamp: loads valid, stores guarded
    int gr1 = row0 + r1l; if (gr1 >= M) gr1 = M - 1;
    const u16* ga0 = A  + (size_t)gr0 * K + lk;
    const u16* ga1 = A  + (size_t)gr1 * K + lk;
    const u16* gb0 = BT + (size_t)(col0 + r0l) * K + lk;
    const u16* gb1 = BT + (size_t)(col0 + r1l) * K + lk;
    u16* la0 = As + (size_t)(wave * 32)      * 32 + lane * 8;
    u16* la1 = As + (size_t)(wave * 32 + 16) * 32 + lane * 8;
    u16* lb0 = Bs + (size_t)(wave * 32)      * 32 + lane * 8;
    u16* lb1 = Bs + (size_t)(wave * 32 + 16) * 32 + lane * 8;

    f32x4_t acc[4][4];
#pragma unroll
    for (int r = 0; r < 4; r++)
#pragma unroll
        for (int c = 0; c < 4; c++)
#pragma unroll
            for (int i = 0; i < 4; i++) acc[r][c][i] = 0.f;

    for (int k0 = 0; k0 < K; k0 += 32) {
        gl_lds16(ga0 + k0, la0);
        gl_lds16(ga1 + k0, la1);
        gl_lds16(gb0 + k0, lb0);
        gl_lds16(gb1 + k0, lb1);
        __syncthreads();   // drains vmcnt (async LDS writes) + all waves

        bf16x8_t a[4], b[4];
#pragma unroll
        for (int r = 0; r < 4; r++)
            a[r] = *(const bf16x8_t*)(As + (size_t)(wr0 + r * 16 + l16) * 32 + quad * 8);
#pragma unroll
        for (int c = 0; c < 4; c++)
            b[c] = *(const bf16x8_t*)(Bs + (size_t)(wc0 + c * 16 + l16) * 32 + quad * 8);
#pragma unroll
        for (int r = 0; r < 4; r++)
#pragma unroll
            for (int c = 0; c < 4; c++)
                acc[r][c] = __builtin_amdgcn_mfma_f32_16x16x32_bf16(a[r], b[c], acc[r][c], 0, 0, 0);
        __syncthreads();   // LDS reads done before next staging overwrites
    }

#pragma unroll
    for (int r = 0; r < 4; r++) {
        int rb = row0 + wr0 + r * 16 + quad * 4;
#pragma unroll
        for (int c = 0; c < 4; c++) {
            int col = col0 + wc0 + c * 16 + l16;
            float sc = (EPI == 1) ? S[col] : 0.f;
            float sh = (EPI == 1) ? T[col] : 0.f;
#pragma unroll
            for (int i = 0; i < 4; i++) {
                int row = rb + i;
                if (row < M) {
                    float v = acc[r][c][i];
                    if (EPI == 1) v = fmaxf(v * sc + sh, 0.f);
                    Cm[(size_t)row * N + col] = f2bf(v);
                }
            }
        }
    }
}

// ---------------- GAT: per-node attention logits (persistent, fused global max) ----------------
// row-major xw; 640 blocks x 4 waves, 1-deep prefetch; block max -> atomicMax (max is exact
// under any order -> gmx identical to a separate ls_max kernel).
__global__ __launch_bounds__(256) void gat_logits(const u16* __restrict__ xw, const u16* __restrict__ asrc,
                                                  const u16* __restrict__ adst, float* __restrict__ ls,
                                                  float* __restrict__ ld, unsigned* __restrict__ gmx) {
    __shared__ float smax[8];
    int lane = threadIdx.x & 63;
    int wv   = threadIdx.x >> 6;
    int h    = lane >> 5;
    uint4 av = ((const uint4*)asrc)[lane];
    uint4 dv = ((const uint4*)adst)[lane];
    float a[8], d[8];
    unpack8(av, a); unpack8(dv, d);
    float mm = -1e30f;
    int n = blockIdx.x * 4 + wv;
    uint4 xv;
    if (n < NN) xv = ((const uint4*)(xw + (size_t)n * C1))[lane];
    while (n < NN) {
        int n2 = n + LGB * 4;
        uint4 nx;
        if (n2 < NN) nx = ((const uint4*)(xw + (size_t)n2 * C1))[lane];
        float x[8];
        unpack8(xv, x);
        float ps = 0.f, pd = 0.f;
#pragma unroll
        for (int j = 0; j < 8; j++) { ps += x[j] * a[j]; pd += x[j] * d[j]; }
#pragma unroll
        for (int m = 16; m >= 1; m >>= 1) { ps += __shfl_xor(ps, m); pd += __shfl_xor(pd, m); }
        if ((lane & 31) == 0) {
            ls[n * 2 + h] = ps;
            ld[n * 2 + h] = pd;
        }
        mm = fmaxf(mm, ps);   // all lanes in a 32-group hold the reduced ps
        xv = nx; n = n2;
    }
    if ((lane & 31) == 0) smax[wv * 2 + h] = mm;
    __syncthreads();
    if (threadIdx.x < 2) {
        float m = fmaxf(fmaxf(smax[threadIdx.x], smax[2 + threadIdx.x]),
                        fmaxf(smax[4 + threadIdx.x], smax[6 + threadIdx.x]));
        atomicMax(&gmx[threadIdx.x], encf(m));
    }
}

// ---------------- per-edge softmax weights alpha = p / den (both heads) ----------------
// wave per node; lanes 0..31 -> head 0 over 32-edge windows, lanes 32..63 -> head 1.
// den per window via 32-lane butterfly; alpha written so the aggregation kernel is a
// pure weighted gather (no exp / den / divide in the hot kernel). R4-proven (same absmax).
__global__ __launch_bounds__(256) void gat_prep(const int* __restrict__ off, const u16* __restrict__ csrc,
                                                const float* __restrict__ ls, const float* __restrict__ ld,
                                                const unsigned* __restrict__ gmx,
                                                float* __restrict__ P0, float* __restrict__ P1) {
    int n = blockIdx.x * 4 + (threadIdx.x >> 6);
    if (n >= NN) return;
    int lane = threadIdx.x & 63;
    int h = lane >> 5;
    int el = lane & 31;
    int beg = off[n], end = off[n + 1];
    if (beg >= end) return;
    float2 ldv = ((const float2*)ld)[n];
    float ldh = h ? ldv.y : ldv.x;
    float gm = decf(gmx[h]) + ldh;
    float mhat = gm > 0.f ? gm : 0.2f * gm;   // leaky is monotone -> valid upper bound
    float* __restrict__ Ph = h ? P1 : P0;
    float den = 0.f;
    for (int base = beg; base < end; base += 32) {
        int e = base + el;
        int ec = e < end ? e : end - 1;      // clamp: loads stay valid
        int sv = csrc[ec];
        float vv = ls[sv * 2 + h] + ldh;
        vv = vv > 0.f ? vv : 0.2f * vv;
        float p = __expf(vv - mhat);
        float pm = (e < end) ? p : 0.f;
#pragma unroll
        for (int m = 16; m >= 1; m >>= 1) pm += __shfl_xor(pm, m);  // masks <32: stays in half
        den += pm;
        if (e < end) Ph[e] = p;              // raw p this pass
    }
    float inv = 1.f / fmaxf(den, 1e-30f);
    for (int base = beg; base < end; base += 32) {
        int e = base + el;
        if (e < end) Ph[e] *= inv;           // rescale to alpha (L1-hot, same thread)
    }
}

// ---------------- GAT aggregation (R8 geometry: wave/node + precomputed alpha) ----------------
__device__ __forceinline__ void proc_edge(uint4 c, float w, float* acc) {
    float x[8];
    unpack8(c, x);
#pragma unroll
    for (int q = 0; q < 8; q++) acc[q] = fmaf(w, x[q], acc[q]);
}

__global__ __launch_bounds__(256) void gat_aggregate(const int* __restrict__ off, const u16* __restrict__ csrc,
                                                     const float* __restrict__ P0, const float* __restrict__ P1,
                                                     const u16* __restrict__ xw,
                                                     const float* __restrict__ bias, u16* __restrict__ outh) {
    int n = blockIdx.x * 4 + (threadIdx.x >> 6);
    if (n >= NN) return;
    const int lane = threadIdx.x & 63;
    const int h    = lane >> 5;
    const int el   = lane & 31;
    const int hoff = h << 5;
    const float* __restrict__ Ph = h ? P1 : P0;
    int beg = off[n], end = off[n + 1];

    float acc[8];
#pragma unroll
    for (int q = 0; q < 8; q++) acc[q] = 0.f;

#define ROWLD(S) (((const uint4*)(xw + (size_t)(S) * C1))[lane])

    for (int base = beg; base < end; base += 32) {
        int cnt = end - base; if (cnt > 32) cnt = 32;
        int e = base + el;
        int ec = e < end ? e : end - 1;      // clamp: loads stay valid
        int sv = csrc[ec];                   // 32 edge srcs (both halves load same -> broadcast)
        float pv = Ph[ec];                   // alpha for edge (base+el), my head; tail unused

        // 4-deep row pipeline
        uint4 r0 = ROWLD(__shfl(sv, 0));
        uint4 r1 = ROWLD(__shfl(sv, 1));
        uint4 r2 = ROWLD(__shfl(sv, 2));
        uint4 r3 = ROWLD(__shfl(sv, 3));

        for (int j = 0; j < cnt; j += 4) {
            uint4 c0 = r0, c1 = r1, c2 = r2, c3 = r3;
            float w0 = __shfl(pv, j + hoff);
            float w1 = __shfl(pv, j + 1 + hoff);   // out-of-range j -> unused (guarded)
            float w2 = __shfl(pv, j + 2 + hoff);
            float w3 = __shfl(pv, j + 3 + hoff);
            if (j + 4 < cnt) {                     // prefetch next 4 rows (clamped -> valid)
                r0 = ROWLD(__shfl(sv, j + 4));
                r1 = ROWLD(__shfl(sv, j + 5));
                r2 = ROWLD(__shfl(sv, j + 6));
                r3 = ROWLD(__shfl(sv, j + 7));
            }
            proc_edge(c0, w0, acc);
            if (j + 1 < cnt) proc_edge(c1, w1, acc);
            if (j + 2 < cnt) proc_edge(c2, w2, acc);
            if (j + 3 < cnt) proc_edge(c3, w3, acc);
        }
    }
#undef ROWLD

    int cb = lane * 8;
    const float4* bp = (const float4*)(bias + cb);
    float4 b0 = bp[0], b1 = bp[1];
    uint4 st;
    st.x = (unsigned)f2bf(acc[0] + b0.x) | ((unsigned)f2bf(acc[1] + b0.y) << 16);
    st.y = (unsigned)f2bf(acc[2] + b0.z) | ((unsigned)f2bf(acc[3] + b0.w) << 16);
    st.z = (unsigned)f2bf(acc[4] + b1.x) | ((unsigned)f2bf(acc[5] + b1.y) << 16);
    st.w = (unsigned)f2bf(acc[6] + b1.z) | ((unsigned)f2bf(acc[7] + b1.w) << 16);
    ((uint4*)(outh + (size_t)n * C1 + cb))[0] = st;
}

// ---------------- two-stage pooling (R9: old pool_bn was 45.8us at 8% occupancy) -------------
// Stage 1: grid (NG, PSPL) x 128 threads; block (g,s) sums a CONTIGUOUS node sub-range of
// graph g; thread t covers feats [t*4, t*4+4) via ushort4 (8B coalesced loads, 1KB/row).
// Stage 2: sums the PSPL partials in slice order (same element order as the old sequential
// loop, chunk-reassociated only -> R4 precedent) + BN3 + ReLU.
__global__ __launch_bounds__(128) void pool_part(const u16* __restrict__ h4, const int* __restrict__ goff,
                                                 float* __restrict__ pp) {
    int g = blockIdx.x, s = blockIdx.y, t = threadIdx.x;
    int b = goff[g], e = goff[g + 1];
    int len = e - b;
    int chunk = (len + PSPL - 1) / PSPL;
    int n0 = b + s * chunk;
    int n1 = n0 + chunk; if (n1 > e) n1 = e;
    float s0 = 0.f, s1 = 0.f, s2 = 0.f, s3 = 0.f;
    for (int n = n0; n < n1; n++) {
        ushort4 v = *(const ushort4*)(h4 + (size_t)n * C1 + t * 4);
        s0 += bf2f(v.x); s1 += bf2f(v.y); s2 += bf2f(v.z); s3 += bf2f(v.w);
    }
    float4* dst = (float4*)(pp + ((size_t)g * PSPL + s) * C1 + t * 4);
    *dst = make_float4(s0, s1, s2, s3);
}

__global__ __launch_bounds__(512) void pool_fin(const float* __restrict__ pp, const int* __restrict__ goff,
                                                const float* __restrict__ S3, const float* __restrict__ T3,
                                                u16* __restrict__ z1) {
    int g = blockIdx.x, t = threadIdx.x;
    float s = 0.f;
#pragma unroll
    for (int k = 0; k < PSPL; k++) s += pp[((size_t)g * PSPL + k) * C1 + t];
    int b = goff[g], e = goff[g + 1];
    float mean = s / fmaxf((float)(e - b), 1.f);
    float v = mean * S3[t] + T3[t];
    z1[(size_t)g * C1 + t] = f2bf(fmaxf(v, 0.f));
}

// ---------------- head ----------------
__global__ __launch_bounds__(512) void head_fc1(const unsigned* __restrict__ flag, const u16* __restrict__ z1,
                                                const void* __restrict__ w1, const float* __restrict__ FB1,
                                                u16* __restrict__ z2) {
    __shared__ float zrow[512];
    int g = blockIdx.x, t = threadIdx.x;
    zrow[t] = bf2f(z1[(size_t)g * 512 + t]);
    __syncthreads();
    float acc = 0.f;
    if (*flag) {
        const float* w = (const float*)w1;
        for (int k = 0; k < 512; k++) acc = fmaf(zrow[k], w[(size_t)k * 512 + t], acc);
    } else {
        const u16* w = (const u16*)w1;
        for (int k = 0; k < 512; k++) acc = fmaf(zrow[k], bf2f(w[(size_t)k * 512 + t]), acc);
    }
    acc += FB1[t];
    z2[(size_t)g * 512 + t] = f2bf(fmaxf(acc, 0.f));
}
__global__ __launch_bounds__(64) void head_fc2(const unsigned* __restrict__ flag, const u16* __restrict__ z2,
                                               const void* __restrict__ w2, const float* __restrict__ FB2,
                                               void* __restrict__ out) {
    int g = blockIdx.x, o = blockIdx.y, lane = threadIdx.x;
    unsigned f = *flag;
    float acc = 0.f;
    if (f) {
        const float* w = (const float*)w2;
        for (int k = lane; k < 512; k += 64) acc += bf2f(z2[(size_t)g * 512 + k]) * w[(size_t)k * NC + o];
    } else {
        const u16* w = (const u16*)w2;
        for (int k = lane; k < 512; k += 64) acc += bf2f(z2[(size_t)g * 512 + k]) * bf2f(w[(size_t)k * NC + o]);
    }
#pragma unroll
    for (int m = 32; m >= 1; m >>= 1) acc += __shfl_xor(acc, m);
    if (lane == 0) {
        float v = acc + FB2[o];
        if (f) ((float*)out)[g * NC + o] = v;
        else   ((u16*)out)[g * NC + o] = f2bf(v);
    }
}

// ---------------- launch ----------------
extern "C" void kernel_launch(void* const* d_in, const int* in_sizes, int n_in,
                              void* d_out, int out_size, void* d_ws, size_t ws_size,
                              hipStream_t stream) {
    (void)in_sizes; (void)n_in; (void)out_size; (void)ws_size;

    const void* x      = d_in[0];
    const int* ei      = (const int*)d_in[1];
    const int* src     = ei;
    const int* dst     = ei + EE;
    const int* ew      = (const int*)d_in[2];
    const int* batch   = (const int*)d_in[3];
    const void* mlp_w1 = d_in[4];
    const void* mlp_b1 = d_in[5];
    const void *bn1g = d_in[6], *bn1b = d_in[7], *bn1m = d_in[8], *bn1v = d_in[9];
    const void* mlp_w2 = d_in[10];
    const void* mlp_b2 = d_in[11];
    const void *bn2g = d_in[12], *bn2b = d_in[13], *bn2m = d_in[14], *bn2v = d_in[15];
    const void* g0w    = d_in[16];
    const void* g0as   = d_in[17];
    const void* g0ad   = d_in[18];
    const void* g0bias = d_in[19];
    const void* g1w    = d_in[20];
    const void* g1as   = d_in[21];
    const void* g1ad   = d_in[22];
    const void* g1bias = d_in[23];
    const void *bn3g = d_in[24], *bn3b = d_in[25], *bn3m = d_in[26], *bn3v = d_in[27];
    const void* fin_w1 = d_in[28];
    const void* fin_b1 = d_in[29];
    const void* fin_w2 = d_in[30];
    const void* fin_b2 = d_in[31];

    char* ws = (char*)d_ws;
    u16*  XB   = (u16*)(ws + OFF_XB);
    u16*  h1   = (u16*)(ws + OFF_H1);
    u16*  h2   = (u16*)(ws + OFF_H2);
    u16*  xw   = (u16*)(ws + OFF_XW);    // row-major [NN][512]
    u16*  h34  = (u16*)(ws + OFF_H34);   // row-major [NN][512]
    float* ls  = (float*)(ws + OFF_LS);
    float* ld  = (float*)(ws + OFF_LD);
    int*  deg  = (int*)(ws + OFF_DEG);
    int*  off  = (int*)(ws + OFF_OFFS);
    int*  cur  = (int*)(ws + OFF_CUR);
    u16*  csrc = (u16*)(ws + OFF_CSRC);
    int*  gcnt = (int*)(ws + OFF_GCNT);
    int*  goff = (int*)(ws + OFF_GOFF);
    int*  part = (int*)(ws + OFF_PART);
    int*  ptot = (int*)(ws + OFF_PTOT);
    u16*  z1   = (u16*)(ws + OFF_Z1);
    u16*  z2   = (u16*)(ws + OFF_Z2);
    float* S1 = (float*)(ws + OFF_ST);
    float* T1 = S1 + 256;
    float* S2 = T1 + 256;
    float* T2 = S2 + 256;
    float* S3 = T2 + 256;
    float* T3 = S3 + 512;
    u16* w1T = (u16*)(ws + OFF_W1T);
    u16* w2T = (u16*)(ws + OFF_W2T);
    u16* g0T = (u16*)(ws + OFF_G0T);
    u16* g1T = (u16*)(ws + OFF_G1T);
    unsigned* flag = (unsigned*)(ws + OFF_FLAG);
    u16* A0S = (u16*)(ws + OFF_A0S);
    u16* A0D = (u16*)(ws + OFF_A0D);
    u16* A1S = (u16*)(ws + OFF_A1S);
    u16* A1D = (u16*)(ws + OFF_A1D);
    float* GB0 = (float*)(ws + OFF_GB0);
    float* GB1 = (float*)(ws + OFF_GB1);
    float* FB1 = (float*)(ws + OFF_FB1);
    float* FB2 = (float*)(ws + OFF_FB2);
    unsigned* GMXU = (unsigned*)(ws + OFF_GMX);   // [0..1]=layer0, [2..3]=layer1
    float* PP = (float*)(ws + OFF_PP);            // pooling partials [NG][PSPL][C1]
    float* P0 = (float*)(ws + OFF_P0);            // per-edge alpha, head0 (reuses XB region)
    float* P1 = (float*)(ws + OFF_P1);            // per-edge alpha, head1

    // dtype detection + input normalization (+ deg/gcnt/gmx init)
    detect_dtype<<<1, 256, 0, stream>>>((const u16*)x, (const u16*)mlp_w1, (const u16*)fin_w1, flag);
    cvt_x<<<(NN * FD / 4) / 256, 256, 0, stream>>>(flag, x, XB, deg, gcnt, GMXU);
    prep_params<<<1, 512, 0, stream>>>(flag,
                                       bn1g, bn1b, bn1m, bn1v, mlp_b1,
                                       bn2g, bn2b, bn2m, bn2v, mlp_b2,
                                       bn3g, bn3b, bn3m, bn3v,
                                       g0as, g0ad, g0bias, g1as, g1ad, g1bias,
                                       fin_b1, fin_b2,
                                       S1, T1, S2, T2, S3, T3,
                                       A0S, A0D, A1S, A1D, GB0, GB1, FB1, FB2);
    transpose_all<<<1920, 256, 0, stream>>>(flag, mlp_w1, mlp_w2, g0w, g1w, w1T, w2T, g0T, g1T);

    // CSR build (graph fixed across both layers) + graph offsets
    hist_k<<<HB, 256, 0, stream>>>(dst, ew, batch, deg, gcnt);
    scan_blk<<<NBLK, 256, 0, stream>>>(deg, off, part);
    scan_small<<<1, 128, 0, stream>>>(part, ptot, gcnt, goff);
    scan_add<<<NBLK, 256, 0, stream>>>(off, part, ptot, cur);
    csr_fill<<<HB, 256, 0, stream>>>(src, dst, ew, cur, csrc);

    // MLP (157 row-blocks of 128 cover 20096 >= 20000)
    gemm_tile<1><<<dim3(157, 2), 256, 0, stream>>>(XB, w1T, h1, S1, T1, NN, C0, FD);
    gemm_tile<1><<<dim3(157, 2), 256, 0, stream>>>(h1, w2T, h2, S2, T2, NN, C0, C0);

    // GAT layer 0 (xw row-major; P0/P1 reuse XB region -- XB dead after gemm 1)
    gemm_tile<0><<<dim3(157, 4), 256, 0, stream>>>(h2, g0T, xw, nullptr, nullptr, NN, C1, C0);
    gat_logits<<<LGB, 256, 0, stream>>>(xw, A0S, A0D, ls, ld, GMXU);
    gat_prep<<<NN / 4, 256, 0, stream>>>(off, csrc, ls, ld, GMXU, P0, P1);
    gat_aggregate<<<NN / 4, 256, 0, stream>>>(off, csrc, P0, P1, xw, GB0, h34);

    // GAT layer 1
    gemm_tile<0><<<dim3(157, 4), 256, 0, stream>>>(h34, g1T, xw, nullptr, nullptr, NN, C1, C1);
    gat_logits<<<LGB, 256, 0, stream>>>(xw, A1S, A1D, ls, ld, GMXU + 2);
    gat_prep<<<NN / 4, 256, 0, stream>>>(off, csrc, ls, ld, GMXU + 2, P0, P1);
    gat_aggregate<<<NN / 4, 256, 0, stream>>>(off, csrc, P0, P1, xw, GB1, h34);  // h4

    // pool (two-stage) + head
    pool_part<<<dim3(NG, PSPL), 128, 0, stream>>>(h34, goff, PP);
    pool_fin<<<NG, 512, 0, stream>>>(PP, goff, S3, T3, z1);
    head_fc1<<<NG, 512, 0, stream>>>(flag, z1, fin_w1, FB1, z2);
    head_fc2<<<dim3(NG, NC), 64, 0, stream>>>(flag, z2, fin_w2, FB2, d_out);
}

// Round 10
// 405.660 us; speedup vs baseline: 1.1759x; 1.0037x over previous
//
#include <hip/hip_runtime.h>

typedef unsigned short u16;

// ---------------- problem constants ----------------
constexpr int NN = 20000;   // nodes
constexpr int EE = 320000;  // edges
constexpr int FD = 128;     // input features
constexpr int C0 = 256;     // hidden (mlp)
constexpr int C1 = 512;     // H*C for GAT
constexpr int NG = 128;     // graphs
constexpr int NC = 10;      // classes
constexpr int NBLK = (NN + 255) / 256;  // 79
constexpr int HB  = 320;                // hist/fill blocks
constexpr int EST = HB * 256;           // edge stride (81920); 4 chunks cover EE
constexpr int LGB = 640;                // logits blocks (persistent)
constexpr int PSPL = 16;                // pooling slices per graph

// ---------------- workspace layout (bytes) ----------------
constexpr size_t OFF_XB   = 0;                                   // NN*FD bf16 (dead after gemm1 -> reused for P0/P1)
constexpr size_t OFF_H1   = OFF_XB  + (size_t)NN * FD * 2;       // NN*C0 bf16
constexpr size_t OFF_H2   = OFF_H1  + (size_t)NN * C0 * 2;       // NN*C0 bf16
constexpr size_t OFF_XW   = OFF_H2  + (size_t)NN * C0 * 2;       // NN*C1 bf16 (ROW-major xw)
constexpr size_t OFF_H34  = OFF_XW  + (size_t)NN * C1 * 2;       // NN*C1 bf16 (h3 then h4, row-major)
constexpr size_t OFF_LS   = OFF_H34 + (size_t)NN * C1 * 2;       // NN*2 f32
constexpr size_t OFF_LD   = OFF_LS  + (size_t)NN * 2 * 4;        // NN*2 f32
constexpr size_t OFF_DEG  = OFF_LD  + (size_t)NN * 2 * 4;        // NN i32
constexpr size_t OFF_OFFS = OFF_DEG + (size_t)NN * 4;            // NN+1 i32 (pad 80016)
constexpr size_t OFF_CUR  = OFF_OFFS + 80016;                    // NN i32
constexpr size_t OFF_CSRC = OFF_CUR + (size_t)NN * 4;            // EE u16 (region sized for old i32; half used)
constexpr size_t OFF_GCNT = OFF_CSRC + (size_t)EE * 4;           // NG i32
constexpr size_t OFF_GOFF = OFF_GCNT + 512;                      // NG+1 i32 (pad 768)
constexpr size_t OFF_PART = OFF_GOFF + 768;                      // NBLK i32 (pad 512)
constexpr size_t OFF_PTOT = OFF_PART + 512;                      // 1 i32 (pad 256)
constexpr size_t OFF_Z1   = OFF_PTOT + 256;                      // NG*C1 bf16 (legacy, unused)
constexpr size_t OFF_Z2   = OFF_Z1  + (size_t)NG * C1 * 2;
constexpr size_t OFF_ST   = OFF_Z2  + (size_t)NG * C1 * 2;       // S1,T1,S2,T2 (256 f32), S3,T3 (512 f32)
constexpr size_t OFF_W1T  = OFF_ST  + 8192;
constexpr size_t OFF_W2T  = OFF_W1T + (size_t)FD * C0 * 2;
constexpr size_t OFF_G0T  = OFF_W2T + (size_t)C0 * C0 * 2;
constexpr size_t OFF_G1T  = OFF_G0T + (size_t)C0 * C1 * 2;
constexpr size_t OFF_AUX  = OFF_G1T + (size_t)C1 * C1 * 2;
constexpr size_t OFF_FLAG = OFF_AUX  + 0;      // u32
constexpr size_t OFF_A0S  = OFF_AUX  + 256;    // 512 u16
constexpr size_t OFF_A0D  = OFF_AUX  + 1280;
constexpr size_t OFF_A1S  = OFF_AUX  + 2304;
constexpr size_t OFF_A1D  = OFF_AUX  + 3328;
constexpr size_t OFF_GB0  = OFF_AUX  + 4352;   // 512 f32
constexpr size_t OFF_GB1  = OFF_AUX  + 6400;
constexpr size_t OFF_FB1  = OFF_AUX  + 8448;   // 512 f32
constexpr size_t OFF_FB2  = OFF_AUX  + 10496;  // 10 f32 (pad 256)
constexpr size_t OFF_GMX  = OFF_AUX  + 10752;  // 4 u32 (pad 256)
constexpr size_t OFF_PP   = OFF_AUX  + 11008;  // f32[NG][PSPL][C1] pooling partials (4 MB)
constexpr size_t OFF_DENA = OFF_PP + (size_t)NG * PSPL * C1 * 4; // f32[NN*2] softmax denominators
// per-edge raw softmax numerators p (f32, per head) -- reuse dead XB region
constexpr size_t OFF_P0   = OFF_XB;            // EE f32
constexpr size_t OFF_P1   = OFF_XB + (size_t)EE * 4;
// end ~= 74.5 MB

// ---------------- helpers ----------------
__device__ inline float bf2f(u16 u) { return __uint_as_float(((unsigned)u) << 16); }
__device__ inline u16 f2bf(float f) {
    unsigned u = __float_as_uint(f);
    unsigned r = u + 0x7fffu + ((u >> 16) & 1u);   // RNE
    return (u16)(r >> 16);
}
// flag-driven load of an external float input (flag=1 -> f32, 0 -> bf16)
__device__ inline float ldf(const void* p, long i, unsigned f) {
    return f ? ((const float*)p)[i] : bf2f(((const u16*)p)[i]);
}
__device__ inline unsigned encf(float f) {  // monotonic float->uint for atomicMax
    unsigned u = __float_as_uint(f);
    return (u & 0x80000000u) ? ~u : (u | 0x80000000u);
}
__device__ inline float decf(unsigned e) {
    return (e & 0x80000000u) ? __uint_as_float(e ^ 0x80000000u) : __uint_as_float(~e);
}
// 2 VALU ops per 32-bit word (low: shl drops high; high: mask)
__device__ inline void unpack8(uint4 r, float* v) {
    v[0] = __uint_as_float(r.x << 16); v[1] = __uint_as_float(r.x & 0xffff0000u);
    v[2] = __uint_as_float(r.y << 16); v[3] = __uint_as_float(r.y & 0xffff0000u);
    v[4] = __uint_as_float(r.z << 16); v[5] = __uint_as_float(r.z & 0xffff0000u);
    v[6] = __uint_as_float(r.w << 16); v[7] = __uint_as_float(r.w & 0xffff0000u);
}

typedef __bf16 bf16x8_t __attribute__((ext_vector_type(8)));
typedef float  f32x4_t  __attribute__((ext_vector_type(4)));

// async 16B global -> LDS (wave-uniform LDS base + lane*16 layout)
__device__ __forceinline__ void gl_lds16(const u16* g, u16* l) {
    __builtin_amdgcn_global_load_lds((const __attribute__((address_space(1))) void*)g,
                                     (__attribute__((address_space(3))) void*)l, 16, 0, 0);
}

// ---------------- dtype detector ----------------
__global__ void detect_dtype(const u16* __restrict__ x, const u16* __restrict__ w,
                             const u16* __restrict__ fw, unsigned* flag) {
    __shared__ int cnt;
    if (threadIdx.x == 0) cnt = 0;
    __syncthreads();
    int c = 0;
    for (int i = threadIdx.x; i < 4096; i += 256) {
        c += (((x[i]  >> 7) & 0xFF) == 0xFF);
        c += (((w[i]  >> 7) & 0xFF) == 0xFF);
        c += (((fw[i] >> 7) & 0xFF) == 0xFF);
    }
    atomicAdd(&cnt, c);
    __syncthreads();
    if (threadIdx.x == 0) *flag = (cnt >= 2) ? 1u : 0u;  // 1 = f32 inputs
}

// ---------------- x -> internal bf16 copy (+ zero deg/gcnt, init gmx) ----------------
__global__ void cvt_x(const unsigned* __restrict__ flag, const void* __restrict__ xin,
                      u16* __restrict__ XB, int* __restrict__ deg, int* __restrict__ gcnt,
                      unsigned* __restrict__ gmxu) {
    int i = blockIdx.x * 256 + threadIdx.x;  // grid covers NN*FD/4 (2500 blocks)
    if (i < NN) deg[i] = 0;
    if (i < NG) gcnt[i] = 0;
    if (i < 4)  gmxu[i] = encf(-1e30f);
    if (*flag) {
        float4 v = ((const float4*)xin)[i];
        ushort4 r;
        r.x = f2bf(v.x); r.y = f2bf(v.y); r.z = f2bf(v.z); r.w = f2bf(v.w);
        ((ushort4*)XB)[i] = r;
    } else {
        ((ushort4*)XB)[i] = ((const ushort4*)xin)[i];
    }
}

// ---------------- fused params prep + all 4 weight transposes (R10: -1 launch) --------------
// block 0: params (512 threads). blocks 1..960: B[K,N] -> BT[N,K] bf16, 512 elems/block.
__global__ __launch_bounds__(512) void prep_trans(const unsigned* __restrict__ flag,
                            const void* g1, const void* b1, const void* m1, const void* v1, const void* lb1,
                            const void* g2, const void* b2, const void* m2, const void* v2, const void* lb2,
                            const void* g3, const void* b3, const void* m3, const void* v3,
                            const void* a0s, const void* a0d, const void* gb0in,
                            const void* a1s, const void* a1d, const void* gb1in,
                            const void* fb1in, const void* fb2in,
                            float* S1, float* T1, float* S2, float* T2, float* S3, float* T3,
                            u16* A0S, u16* A0D, u16* A1S, u16* A1D,
                            float* GB0, float* GB1, float* FB1, float* FB2,
                            const void* w1, const void* w2, const void* g0w, const void* g1w,
                            u16* w1T, u16* w2T, u16* g0T, u16* g1T) {
    unsigned f = *flag;
    if (blockIdx.x == 0) {
        int c = threadIdx.x;  // 512 threads
        if (c < 256) {
            float s = ldf(g1, c, f) / sqrtf(ldf(v1, c, f) + 1e-5f);
            S1[c] = s; T1[c] = s * (ldf(lb1, c, f) - ldf(m1, c, f)) + ldf(b1, c, f);
            float s2 = ldf(g2, c, f) / sqrtf(ldf(v2, c, f) + 1e-5f);
            S2[c] = s2; T2[c] = s2 * (ldf(lb2, c, f) - ldf(m2, c, f)) + ldf(b2, c, f);
        }
        float s3 = ldf(g3, c, f) / sqrtf(ldf(v3, c, f) + 1e-5f);
        S3[c] = s3; T3[c] = ldf(b3, c, f) - ldf(m3, c, f) * s3;
        A0S[c] = f2bf(ldf(a0s, c, f));
        A0D[c] = f2bf(ldf(a0d, c, f));
        A1S[c] = f2bf(ldf(a1s, c, f));
        A1D[c] = f2bf(ldf(a1d, c, f));
        GB0[c] = ldf(gb0in, c, f);
        GB1[c] = ldf(gb1in, c, f);
        FB1[c] = ldf(fb1in, c, f);
        if (c < NC) FB2[c] = ldf(fb2in, c, f);
        return;
    }
    int b = blockIdx.x - 1;   // 0..959
    const void* B; u16* BT; int K, logN, base;
    if (b < 64)       { B = w1;  BT = w1T; K = FD; logN = 8; base = 0; }
    else if (b < 192) { B = w2;  BT = w2T; K = C0; logN = 8; base = 64; }
    else if (b < 448) { B = g0w; BT = g0T; K = C0; logN = 9; base = 192; }
    else              { B = g1w; BT = g1T; K = C1; logN = 9; base = 448; }
    int idx = (b - base) * 512 + threadIdx.x;
    int N = 1 << logN;
    int k = idx >> logN, n = idx & (N - 1);
    u16 v = f ? f2bf(((const float*)B)[idx]) : ((const u16*)B)[idx];
    BT[(size_t)n * K + k] = v;
}

// ---------------- CSR build: histograms (pipelined atomics + wave-run gcnt) ----------------
__global__ __launch_bounds__(256) void hist_k(const int* __restrict__ dst, const int* __restrict__ ew,
                                              const int* __restrict__ batch,
                                              int* __restrict__ deg, int* __restrict__ gcnt) {
    int tid = blockIdx.x * 256 + threadIdx.x;
    int lane = threadIdx.x & 63;
    // edges: 4 independent atomic chains per thread (outstanding-transaction pipelining)
#pragma unroll
    for (int j = 0; j < 4; j++) {
        int e = tid + j * EST;
        if (e < EE && ew[e] == 1) atomicAdd(&deg[dst[e]], 1);
    }
    // nodes: batch is sorted -> one atomic per run per wave (kills same-address serialization)
    int n = tid;
    if (n < NN) {
        int g = batch[n];
        int pg = __shfl_up(g, 1);
        bool head = (lane == 0) || (pg != g);
        unsigned long long act = __ballot(1);
        unsigned long long hm  = __ballot(head);
        if (head) {
            unsigned long long above = (lane < 63) ? ((hm >> (lane + 1)) << (lane + 1)) : 0ull;
            int limit = 64 - __builtin_clzll(act);           // highest active lane + 1
            int nxt = above ? __builtin_ctzll(above) : limit;
            atomicAdd(&gcnt[g], nxt - lane);
        }
    }
}
// hierarchical scan: (1) per-block local exclusive scan + block totals
__global__ __launch_bounds__(256) void scan_blk(const int* __restrict__ deg, int* __restrict__ off,
                                                int* __restrict__ part) {
    __shared__ int tmp[256];
    int tid = threadIdx.x, i = blockIdx.x * 256 + tid;
    int v = (i < NN) ? deg[i] : 0;
    tmp[tid] = v;
    __syncthreads();
#pragma unroll
    for (int s = 1; s < 256; s <<= 1) {
        int a = (tid >= s) ? tmp[tid - s] : 0;
        __syncthreads();
        if (tid >= s) tmp[tid] += a;
        __syncthreads();
    }
    if (i < NN) off[i] = tmp[tid] - v;   // block-local exclusive
    if (tid == 255) part[blockIdx.x] = tmp[255];
}
// (2) scan the NBLK partials + scan gcnt -> goff (one small block does both)
__global__ __launch_bounds__(128) void scan_small(int* __restrict__ part, int* __restrict__ ptot,
                                                  const int* __restrict__ gcnt, int* __restrict__ goff) {
    __shared__ int tmp[128];
    int tid = threadIdx.x;
    int v = (tid < NBLK) ? part[tid] : 0;
    tmp[tid] = v;
    __syncthreads();
#pragma unroll
    for (int s = 1; s < 128; s <<= 1) {
        int a = (tid >= s) ? tmp[tid - s] : 0;
        __syncthreads();
        if (tid >= s) tmp[tid] += a;
        __syncthreads();
    }
    if (tid < NBLK) part[tid] = tmp[tid] - v;  // exclusive
    if (tid == 127) *ptot = tmp[127];
    __syncthreads();
    int g = gcnt[tid];
    tmp[tid] = g;
    __syncthreads();
#pragma unroll
    for (int s = 1; s < 128; s <<= 1) {
        int a = (tid >= s) ? tmp[tid - s] : 0;
        __syncthreads();
        if (tid >= s) tmp[tid] += a;
        __syncthreads();
    }
    goff[tid] = tmp[tid] - g;
    if (tid == 127) goff[128] = tmp[127];
}
// (3) add block prefix, emit cursor copy and total
__global__ __launch_bounds__(256) void scan_add(int* __restrict__ off, const int* __restrict__ part,
                                                const int* __restrict__ ptot, int* __restrict__ cursor) {
    int tid = threadIdx.x, i = blockIdx.x * 256 + tid;
    if (i < NN) {
        int o = off[i] + part[blockIdx.x];
        off[i] = o;
        cursor[i] = o;
    }
    if (i == 0) off[NN] = *ptot;
}
// fill: 4 independent atomic-return chains per thread; csrc stored u16 (NN < 65536)
__global__ __launch_bounds__(256) void csr_fill(const int* __restrict__ src, const int* __restrict__ dst,
                                                const int* __restrict__ ew,
                                                int* __restrict__ cursor, u16* __restrict__ csrc) {
    int tid = blockIdx.x * 256 + threadIdx.x;
    bool ok[4]; int sv[4]; int p[4];
#pragma unroll
    for (int j = 0; j < 4; j++) {
        int e = tid + j * EST;
        ok[j] = false; sv[j] = 0; p[j] = 0;
        if (e < EE && ew[e] == 1) {
            ok[j] = true;
            sv[j] = src[e];
            p[j] = atomicAdd(&cursor[dst[e]], 1);
        }
    }
#pragma unroll
    for (int j = 0; j < 4; j++) if (ok[j]) csrc[p[j]] = (u16)sv[j];
}

// ---------------- MFMA GEMM (m97-style LDS-staged): C[M,N] = A[M,K] @ B[K,N] ----------------
// 128x128 block, 4 waves 2x2 (64x64 per wave), BK=32, async global->LDS staging.
// EPI: 0 = store raw bf16 row-major; 1 = relu(acc*S[col]+T[col]) row-major
template <int EPI>
__global__ __launch_bounds__(256) void gemm_tile(const u16* __restrict__ A, const u16* __restrict__ BT,
                                                 u16* __restrict__ Cm,
                                                 const float* __restrict__ S, const float* __restrict__ T,
                                                 int M, int N, int K) {
    __shared__ u16 As[128 * 32];   // [row][k] row-major, unpadded (global_load_lds layout)
    __shared__ u16 Bs[128 * 32];   // [col][k]
    const int tid  = threadIdx.x;
    const int wave = tid >> 6;
    const int lane = tid & 63;
    const int quad = lane >> 4;
    const int l16  = lane & 15;
    const int wr0  = (wave >> 1) * 64;
    const int wc0  = (wave & 1) * 64;
    const int row0 = blockIdx.x * 128;
    const int col0 = blockIdx.y * 128;

    const int lr = lane >> 2;          // 0..15 row within 16-row segment
    const int lk = (lane & 3) * 8;     // 0,8,16,24 element offset in k
    int r0l = wave * 32 + lr;
    int r1l = r0l + 16;
    int gr0 = row0 + r0l; if (gr0 >= M) gr0 = M - 1;   // clamp: loads valid, stores guarded
    int gr1 = row0 + r1l; if (gr1 >= M) gr1 = M - 1;
    const u16* ga0 = A  + (size_t)gr0 * K + lk;
    const u16* ga1 = A  + (size_t)gr1 * K + lk;
    const u16* gb0 = BT + (size_t)(col0 + r0l) * K + lk;
    const u16* gb1 = BT + (size_t)(col0 + r1l) * K + lk;
    u16* la0 = As + (size_t)(wave * 32)      * 32 + lane * 8;
    u16* la1 = As + (size_t)(wave * 32 + 16) * 32 + lane * 8;
    u16* lb0 = Bs + (size_t)(wave * 32)      * 32 + lane * 8;
    u16* lb1 = Bs + (size_t)(wave * 32 + 16) * 32 + lane * 8;

    f32x4_t acc[4][4];
#pragma unroll
    for (int r = 0; r < 4; r++)
#pragma unroll
        for (int c = 0; c < 4; c++)
#pragma unroll
            for (int i = 0; i < 4; i++) acc[r][c][i] = 0.f;

    for (int k0 = 0; k0 < K; k0 += 32) {
        gl_lds16(ga0 + k0, la0);
        gl_lds16(ga1 + k0, la1);
        gl_lds16(gb0 + k0, lb0);
        gl_lds16(gb1 + k0, lb1);
        __syncthreads();   // drains vmcnt (async LDS writes) + all waves

        bf16x8_t a[4], b[4];
#pragma unroll
        for (int r = 0; r < 4; r++)
            a[r] = *(const bf16x8_t*)(As + (size_t)(wr0 + r * 16 + l16) * 32 + quad * 8);
#pragma unroll
        for (int c = 0; c < 4; c++)
            b[c] = *(const bf16x8_t*)(Bs + (size_t)(wc0 + c * 16 + l16) * 32 + quad * 8);
#pragma unroll
        for (int r = 0; r < 4; r++)
#pragma unroll
            for (int c = 0; c < 4; c++)
                acc[r][c] = __builtin_amdgcn_mfma_f32_16x16x32_bf16(a[r], b[c], acc[r][c], 0, 0, 0);
        __syncthreads();   // LDS reads done before next staging overwrites
    }

#pragma unroll
    for (int r = 0; r < 4; r++) {
        int rb = row0 + wr0 + r * 16 + quad * 4;
#pragma unroll
        for (int c = 0; c < 4; c++) {
            int col = col0 + wc0 + c * 16 + l16;
            float sc = (EPI == 1) ? S[col] : 0.f;
            float sh = (EPI == 1) ? T[col] : 0.f;
#pragma unroll
            for (int i = 0; i < 4; i++) {
                int row = rb + i;
                if (row < M) {
                    float v = acc[r][c][i];
                    if (EPI == 1) v = fmaxf(v * sc + sh, 0.f);
                    Cm[(size_t)row * N + col] = f2bf(v);
                }
            }
        }
    }
}

// ---------------- GAT: per-node attention logits (persistent, fused global max) ----------------
__global__ __launch_bounds__(256) void gat_logits(const u16* __restrict__ xw, const u16* __restrict__ asrc,
                                                  const u16* __restrict__ adst, float* __restrict__ ls,
                                                  float* __restrict__ ld, unsigned* __restrict__ gmx) {
    __shared__ float smax[8];
    int lane = threadIdx.x & 63;
    int wv   = threadIdx.x >> 6;
    int h    = lane >> 5;
    uint4 av = ((const uint4*)asrc)[lane];
    uint4 dv = ((const uint4*)adst)[lane];
    float a[8], d[8];
    unpack8(av, a); unpack8(dv, d);
    float mm = -1e30f;
    int n = blockIdx.x * 4 + wv;
    uint4 xv;
    if (n < NN) xv = ((const uint4*)(xw + (size_t)n * C1))[lane];
    while (n < NN) {
        int n2 = n + LGB * 4;
        uint4 nx;
        if (n2 < NN) nx = ((const uint4*)(xw + (size_t)n2 * C1))[lane];
        float x[8];
        unpack8(xv, x);
        float ps = 0.f, pd = 0.f;
#pragma unroll
        for (int j = 0; j < 8; j++) { ps += x[j] * a[j]; pd += x[j] * d[j]; }
#pragma unroll
        for (int m = 16; m >= 1; m >>= 1) { ps += __shfl_xor(ps, m); pd += __shfl_xor(pd, m); }
        if ((lane & 31) == 0) {
            ls[n * 2 + h] = ps;
            ld[n * 2 + h] = pd;
        }
        mm = fmaxf(mm, ps);   // all lanes in a 32-group hold the reduced ps
        xv = nx; n = n2;
    }
    if ((lane & 31) == 0) smax[wv * 2 + h] = mm;
    __syncthreads();
    if (threadIdx.x < 2) {
        float m = fmaxf(fmaxf(smax[threadIdx.x], smax[2 + threadIdx.x]),
                        fmaxf(smax[4 + threadIdx.x], smax[6 + threadIdx.x]));
        atomicMax(&gmx[threadIdx.x], encf(m));
    }
}

// ---------------- per-edge raw p + denominator per (node,head) (R10: single pass) ------------
// wave per node; lanes 0..31 -> head 0 over 32-edge windows, lanes 32..63 -> head 1.
// den via masked 32-lane butterfly (same order as before -> identical den); normalization
// moved to the aggregate epilogue (R7-proven: absmax unchanged). Empty nodes write den=0
// (aggregate: acc=0 -> output 0*inv + bias, exact).
__global__ __launch_bounds__(256) void gat_prep(const int* __restrict__ off, const u16* __restrict__ csrc,
                                                const float* __restrict__ ls, const float* __restrict__ ld,
                                                const unsigned* __restrict__ gmx,
                                                float* __restrict__ P0, float* __restrict__ P1,
                                                float* __restrict__ denA) {
    int n = blockIdx.x * 4 + (threadIdx.x >> 6);
    if (n >= NN) return;
    int lane = threadIdx.x & 63;
    int h = lane >> 5;
    int el = lane & 31;
    int beg = off[n], end = off[n + 1];
    float2 ldv = ((const float2*)ld)[n];
    float ldh = h ? ldv.y : ldv.x;
    float gm = decf(gmx[h]) + ldh;
    float mhat = gm > 0.f ? gm : 0.2f * gm;   // leaky is monotone -> valid upper bound
    float* __restrict__ Ph = h ? P1 : P0;
    float den = 0.f;
    for (int base = beg; base < end; base += 32) {
        int e = base + el;
        int ec = e < end ? e : end - 1;      // clamp: loads stay valid
        int sv = csrc[ec];
        float vv = ls[sv * 2 + h] + ldh;
        vv = vv > 0.f ? vv : 0.2f * vv;
        float p = __expf(vv - mhat);
        float pm = (e < end) ? p : 0.f;
#pragma unroll
        for (int m = 16; m >= 1; m >>= 1) pm += __shfl_xor(pm, m);  // masks <32: stays in half
        den += pm;
        if (e < end) Ph[e] = p;              // raw p (normalized at aggregate epilogue)
    }
    if (el == 0) denA[n * 2 + h] = den;      // lanes 0 (h=0) and 32 (h=1)
}

// ---------------- GAT aggregation (wave/node + raw p, normalize at epilogue) ----------------
__device__ __forceinline__ void proc_edge(uint4 c, float w, float* acc) {
    float x[8];
    unpack8(c, x);
#pragma unroll
    for (int q = 0; q < 8; q++) acc[q] = fmaf(w, x[q], acc[q]);
}

__global__ __launch_bounds__(256) void gat_aggregate(const int* __restrict__ off, const u16* __restrict__ csrc,
                                                     const float* __restrict__ P0, const float* __restrict__ P1,
                                                     const float* __restrict__ denA,
                                                     const u16* __restrict__ xw,
                                                     const float* __restrict__ bias, u16* __restrict__ outh) {
    int n = blockIdx.x * 4 + (threadIdx.x >> 6);
    if (n >= NN) return;
    const int lane = threadIdx.x & 63;
    const int h    = lane >> 5;
    const int el   = lane & 31;
    const int hoff = h << 5;
    const float* __restrict__ Ph = h ? P1 : P0;
    int beg = off[n], end = off[n + 1];

    float acc[8];
#pragma unroll
    for (int q = 0; q < 8; q++) acc[q] = 0.f;

#define ROWLD(S) (((const uint4*)(xw + (size_t)(S) * C1))[lane])

    for (int base = beg; base < end; base += 32) {
        int cnt = end - base; if (cnt > 32) cnt = 32;
        int e = base + el;
        int ec = e < end ? e : end - 1;      // clamp: loads stay valid
        int sv = csrc[ec];                   // 32 edge srcs (both halves load same -> broadcast)
        float pv = Ph[ec];                   // raw p for edge (base+el), my head; tail unused

        // 4-deep row pipeline
        uint4 r0 = ROWLD(__shfl(sv, 0));
        uint4 r1 = ROWLD(__shfl(sv, 1));
        uint4 r2 = ROWLD(__shfl(sv, 2));
        uint4 r3 = ROWLD(__shfl(sv, 3));

        for (int j = 0; j < cnt; j += 4) {
            uint4 c0 = r0, c1 = r1, c2 = r2, c3 = r3;
            float w0 = __shfl(pv, j + hoff);
            float w1 = __shfl(pv, j + 1 + hoff);   // out-of-range j -> unused (guarded)
            float w2 = __shfl(pv, j + 2 + hoff);
            float w3 = __shfl(pv, j + 3 + hoff);
            if (j + 4 < cnt) {                     // prefetch next 4 rows (clamped -> valid)
                r0 = ROWLD(__shfl(sv, j + 4));
                r1 = ROWLD(__shfl(sv, j + 5));
                r2 = ROWLD(__shfl(sv, j + 6));
                r3 = ROWLD(__shfl(sv, j + 7));
            }
            proc_edge(c0, w0, acc);
            if (j + 1 < cnt) proc_edge(c1, w1, acc);
            if (j + 2 < cnt) proc_edge(c2, w2, acc);
            if (j + 3 < cnt) proc_edge(c3, w3, acc);
        }
    }
#undef ROWLD

    float inv = 1.f / fmaxf(denA[n * 2 + h], 1e-30f);
    int cb = lane * 8;
    const float4* bp = (const float4*)(bias + cb);
    float4 b0 = bp[0], b1 = bp[1];
    uint4 st;
    st.x = (unsigned)f2bf(fmaf(acc[0], inv, b0.x)) | ((unsigned)f2bf(fmaf(acc[1], inv, b0.y)) << 16);
    st.y = (unsigned)f2bf(fmaf(acc[2], inv, b0.z)) | ((unsigned)f2bf(fmaf(acc[3], inv, b0.w)) << 16);
    st.z = (unsigned)f2bf(fmaf(acc[4], inv, b1.x)) | ((unsigned)f2bf(fmaf(acc[5], inv, b1.y)) << 16);
    st.w = (unsigned)f2bf(fmaf(acc[6], inv, b1.z)) | ((unsigned)f2bf(fmaf(acc[7], inv, b1.w)) << 16);
    ((uint4*)(outh + (size_t)n * C1 + cb))[0] = st;
}

// ---------------- two-stage pooling stage 1 (R9-proven: 45.8us -> ~5us) --------------------
__global__ __launch_bounds__(128) void pool_part(const u16* __restrict__ h4, const int* __restrict__ goff,
                                                 float* __restrict__ pp) {
    int g = blockIdx.x, s = blockIdx.y, t = threadIdx.x;
    int b = goff[g], e = goff[g + 1];
    int len = e - b;
    int chunk = (len + PSPL - 1) / PSPL;
    int n0 = b + s * chunk;
    int n1 = n0 + chunk; if (n1 > e) n1 = e;
    float s0 = 0.f, s1 = 0.f, s2 = 0.f, s3 = 0.f;
    for (int n = n0; n < n1; n++) {
        ushort4 v = *(const ushort4*)(h4 + (size_t)n * C1 + t * 4);
        s0 += bf2f(v.x); s1 += bf2f(v.y); s2 += bf2f(v.z); s3 += bf2f(v.w);
    }
    float4* dst = (float4*)(pp + ((size_t)g * PSPL + s) * C1 + t * 4);
    *dst = make_float4(s0, s1, s2, s3);
}

// ---------------- fused pool_fin + BN3 + ReLU + fc1 + fc2 (R10: -2 launches) ----------------
// 128 blocks x 512 threads. z1/z2 live in LDS (round-through-bf16 preserved to match the
// old z1/z2 store-load path). fc2 uses a deterministic block tree-reduce (ulp-level
// reassociation vs the old stride-64 butterfly; bf16 quantization dominates absmax).
__global__ __launch_bounds__(512) void head_all(const unsigned* __restrict__ flag,
                                                const float* __restrict__ pp, const int* __restrict__ goff,
                                                const float* __restrict__ S3, const float* __restrict__ T3,
                                                const void* __restrict__ w1, const float* __restrict__ FB1,
                                                const void* __restrict__ w2, const float* __restrict__ FB2,
                                                void* __restrict__ out) {
    __shared__ float zrow[512];
    __shared__ float z2row[512];
    __shared__ float red[512];
    int g = blockIdx.x, t = threadIdx.x;
    unsigned f = *flag;
    // pool_fin: sum 16 slice-partials in slice order + BN3 + ReLU
    float s = 0.f;
#pragma unroll
    for (int k = 0; k < PSPL; k++) s += pp[((size_t)g * PSPL + k) * C1 + t];
    int b = goff[g], e = goff[g + 1];
    float mean = s / fmaxf((float)(e - b), 1.f);
    float v = fmaxf(mean * S3[t] + T3[t], 0.f);
    zrow[t] = bf2f(f2bf(v));                  // round through bf16 (old z1 path)
    __syncthreads();
    // fc1
    float acc = 0.f;
    if (f) {
        const float* w = (const float*)w1;
        for (int k = 0; k < 512; k++) acc = fmaf(zrow[k], w[(size_t)k * 512 + t], acc);
    } else {
        const u16* w = (const u16*)w1;
        for (int k = 0; k < 512; k++) acc = fmaf(zrow[k], bf2f(w[(size_t)k * 512 + t]), acc);
    }
    acc += FB1[t];
    z2row[t] = bf2f(f2bf(fmaxf(acc, 0.f)));   // round through bf16 (old z2 path)
    __syncthreads();
    // fc2: 10 outputs, deterministic tree reduce over k=t
    float z2t = z2row[t];
    for (int o = 0; o < NC; o++) {
        float p = f ? z2t * ((const float*)w2)[(size_t)t * NC + o]
                    : z2t * bf2f(((const u16*)w2)[(size_t)t * NC + o]);
        red[t] = p;
        __syncthreads();
#pragma unroll
        for (int sd = 256; sd >= 1; sd >>= 1) {
            if (t < sd) red[t] += red[t + sd];
            __syncthreads();
        }
        if (t == 0) {
            float vv = red[0] + FB2[o];
            if (f) ((float*)out)[g * NC + o] = vv;
            else   ((u16*)out)[g * NC + o] = f2bf(vv);
        }
        __syncthreads();   // red reused next o
    }
}

// ---------------- launch ----------------
extern "C" void kernel_launch(void* const* d_in, const int* in_sizes, int n_in,
                              void* d_out, int out_size, void* d_ws, size_t ws_size,
                              hipStream_t stream) {
    (void)in_sizes; (void)n_in; (void)out_size; (void)ws_size;

    const void* x      = d_in[0];
    const int* ei      = (const int*)d_in[1];
    const int* src     = ei;
    const int* dst     = ei + EE;
    const int* ew      = (const int*)d_in[2];
    const int* batch   = (const int*)d_in[3];
    const void* mlp_w1 = d_in[4];
    const void* mlp_b1 = d_in[5];
    const void *bn1g = d_in[6], *bn1b = d_in[7], *bn1m = d_in[8], *bn1v = d_in[9];
    const void* mlp_w2 = d_in[10];
    const void* mlp_b2 = d_in[11];
    const void *bn2g = d_in[12], *bn2b = d_in[13], *bn2m = d_in[14], *bn2v = d_in[15];
    const void* g0w    = d_in[16];
    const void* g0as   = d_in[17];
    const void* g0ad   = d_in[18];
    const void* g0bias = d_in[19];
    const void* g1w    = d_in[20];
    const void* g1as   = d_in[21];
    const void* g1ad   = d_in[22];
    const void* g1bias = d_in[23];
    const void *bn3g = d_in[24], *bn3b = d_in[25], *bn3m = d_in[26], *bn3v = d_in[27];
    const void* fin_w1 = d_in[28];
    const void* fin_b1 = d_in[29];
    const void* fin_w2 = d_in[30];
    const void* fin_b2 = d_in[31];

    char* ws = (char*)d_ws;
    u16*  XB   = (u16*)(ws + OFF_XB);
    u16*  h1   = (u16*)(ws + OFF_H1);
    u16*  h2   = (u16*)(ws + OFF_H2);
    u16*  xw   = (u16*)(ws + OFF_XW);    // row-major [NN][512]
    u16*  h34  = (u16*)(ws + OFF_H34);   // row-major [NN][512]
    float* ls  = (float*)(ws + OFF_LS);
    float* ld  = (float*)(ws + OFF_LD);
    int*  deg  = (int*)(ws + OFF_DEG);
    int*  off  = (int*)(ws + OFF_OFFS);
    int*  cur  = (int*)(ws + OFF_CUR);
    u16*  csrc = (u16*)(ws + OFF_CSRC);
    int*  gcnt = (int*)(ws + OFF_GCNT);
    int*  goff = (int*)(ws + OFF_GOFF);
    int*  part = (int*)(ws + OFF_PART);
    int*  ptot = (int*)(ws + OFF_PTOT);
    float* S1 = (float*)(ws + OFF_ST);
    float* T1 = S1 + 256;
    float* S2 = T1 + 256;
    float* T2 = S2 + 256;
    float* S3 = T2 + 256;
    float* T3 = S3 + 512;
    u16* w1T = (u16*)(ws + OFF_W1T);
    u16* w2T = (u16*)(ws + OFF_W2T);
    u16* g0T = (u16*)(ws + OFF_G0T);
    u16* g1T = (u16*)(ws + OFF_G1T);
    unsigned* flag = (unsigned*)(ws + OFF_FLAG);
    u16* A0S = (u16*)(ws + OFF_A0S);
    u16* A0D = (u16*)(ws + OFF_A0D);
    u16* A1S = (u16*)(ws + OFF_A1S);
    u16* A1D = (u16*)(ws + OFF_A1D);
    float* GB0 = (float*)(ws + OFF_GB0);
    float* GB1 = (float*)(ws + OFF_GB1);
    float* FB1 = (float*)(ws + OFF_FB1);
    float* FB2 = (float*)(ws + OFF_FB2);
    unsigned* GMXU = (unsigned*)(ws + OFF_GMX);   // [0..1]=layer0, [2..3]=layer1
    float* PP = (float*)(ws + OFF_PP);            // pooling partials [NG][PSPL][C1]
    float* DENA = (float*)(ws + OFF_DENA);        // per (node,head) denominators
    float* P0 = (float*)(ws + OFF_P0);            // per-edge raw p, head0 (reuses XB region)
    float* P1 = (float*)(ws + OFF_P1);            // per-edge raw p, head1

    // dtype detection + input normalization (+ deg/gcnt/gmx init)
    detect_dtype<<<1, 256, 0, stream>>>((const u16*)x, (const u16*)mlp_w1, (const u16*)fin_w1, flag);
    cvt_x<<<(NN * FD / 4) / 256, 256, 0, stream>>>(flag, x, XB, deg, gcnt, GMXU);
    prep_trans<<<961, 512, 0, stream>>>(flag,
                                        bn1g, bn1b, bn1m, bn1v, mlp_b1,
                                        bn2g, bn2b, bn2m, bn2v, mlp_b2,
                                        bn3g, bn3b, bn3m, bn3v,
                                        g0as, g0ad, g0bias, g1as, g1ad, g1bias,
                                        fin_b1, fin_b2,
                                        S1, T1, S2, T2, S3, T3,
                                        A0S, A0D, A1S, A1D, GB0, GB1, FB1, FB2,
                                        mlp_w1, mlp_w2, g0w, g1w, w1T, w2T, g0T, g1T);

    // CSR build (graph fixed across both layers) + graph offsets
    hist_k<<<HB, 256, 0, stream>>>(dst, ew, batch, deg, gcnt);
    scan_blk<<<NBLK, 256, 0, stream>>>(deg, off, part);
    scan_small<<<1, 128, 0, stream>>>(part, ptot, gcnt, goff);
    scan_add<<<NBLK, 256, 0, stream>>>(off, part, ptot, cur);
    csr_fill<<<HB, 256, 0, stream>>>(src, dst, ew, cur, csrc);

    // MLP (157 row-blocks of 128 cover 20096 >= 20000)
    gemm_tile<1><<<dim3(157, 2), 256, 0, stream>>>(XB, w1T, h1, S1, T1, NN, C0, FD);
    gemm_tile<1><<<dim3(157, 2), 256, 0, stream>>>(h1, w2T, h2, S2, T2, NN, C0, C0);

    // GAT layer 0 (xw row-major; P0/P1 reuse XB region -- XB dead after gemm 1)
    gemm_tile<0><<<dim3(157, 4), 256, 0, stream>>>(h2, g0T, xw, nullptr, nullptr, NN, C1, C0);
    gat_logits<<<LGB, 256, 0, stream>>>(xw, A0S, A0D, ls, ld, GMXU);
    gat_prep<<<NN / 4, 256, 0, stream>>>(off, csrc, ls, ld, GMXU, P0, P1, DENA);
    gat_aggregate<<<NN / 4, 256, 0, stream>>>(off, csrc, P0, P1, DENA, xw, GB0, h34);

    // GAT layer 1
    gemm_tile<0><<<dim3(157, 4), 256, 0, stream>>>(h34, g1T, xw, nullptr, nullptr, NN, C1, C1);
    gat_logits<<<LGB, 256, 0, stream>>>(xw, A1S, A1D, ls, ld, GMXU + 2);
    gat_prep<<<NN / 4, 256, 0, stream>>>(off, csrc, ls, ld, GMXU + 2, P0, P1, DENA);
    gat_aggregate<<<NN / 4, 256, 0, stream>>>(off, csrc, P0, P1, DENA, xw, GB1, h34);  // h4

    // pool stage 1 + fused pool_fin/fc1/fc2
    pool_part<<<dim3(NG, PSPL), 128, 0, stream>>>(h34, goff, PP);
    head_all<<<NG, 512, 0, stream>>>(flag, PP, goff, S3, T3, fin_w1, FB1, fin_w2, FB2, d_out);
}

// Round 11
// 380.699 us; speedup vs baseline: 1.2530x; 1.0656x over previous
//
#include <hip/hip_runtime.h>

typedef unsigned short u16;

// ---------------- problem constants ----------------
constexpr int NN = 20000;   // nodes
constexpr int EE = 320000;  // edges
constexpr int FD = 128;     // input features
constexpr int C0 = 256;     // hidden (mlp)
constexpr int C1 = 512;     // H*C for GAT
constexpr int NG = 128;     // graphs
constexpr int NC = 10;      // classes
constexpr int NBLK = (NN + 255) / 256;  // 79
constexpr int HB  = 320;                // hist/fill blocks
constexpr int EST = HB * 256;           // edge stride (81920); 4 chunks cover EE
constexpr int PSPL = 16;                // pooling slices per graph

// ---------------- workspace layout (bytes) ----------------
constexpr size_t OFF_XB   = 0;                                   // NN*FD bf16 (dead after gemm1 -> reused for P0/P1)
constexpr size_t OFF_H1   = OFF_XB  + (size_t)NN * FD * 2;       // NN*C0 bf16
constexpr size_t OFF_H2   = OFF_H1  + (size_t)NN * C0 * 2;       // NN*C0 bf16
constexpr size_t OFF_XW   = OFF_H2  + (size_t)NN * C0 * 2;       // NN*C1 bf16 (ROW-major xw)
constexpr size_t OFF_H34  = OFF_XW  + (size_t)NN * C1 * 2;       // NN*C1 bf16 (h3 then h4, row-major)
constexpr size_t OFF_LS   = OFF_H34 + (size_t)NN * C1 * 2;       // NN*2 f32
constexpr size_t OFF_LD   = OFF_LS  + (size_t)NN * 2 * 4;        // NN*2 f32
constexpr size_t OFF_DEG  = OFF_LD  + (size_t)NN * 2 * 4;        // NN i32
constexpr size_t OFF_OFFS = OFF_DEG + (size_t)NN * 4;            // NN+1 i32 (pad 80016)
constexpr size_t OFF_CUR  = OFF_OFFS + 80016;                    // NN i32
constexpr size_t OFF_CSRC = OFF_CUR + (size_t)NN * 4;            // EE u16 (region sized for old i32; half used)
constexpr size_t OFF_GCNT = OFF_CSRC + (size_t)EE * 4;           // NG i32
constexpr size_t OFF_GOFF = OFF_GCNT + 512;                      // NG+1 i32 (pad 768)
constexpr size_t OFF_PART = OFF_GOFF + 768;                      // NBLK i32 (pad 512)
constexpr size_t OFF_PTOT = OFF_PART + 512;                      // 1 i32 (pad 256)
constexpr size_t OFF_Z1   = OFF_PTOT + 256;                      // (legacy)
constexpr size_t OFF_Z2   = OFF_Z1  + (size_t)NG * C1 * 2;
constexpr size_t OFF_ST   = OFF_Z2  + (size_t)NG * C1 * 2;       // S1,T1,S2,T2 (256 f32), S3,T3 (512 f32)
constexpr size_t OFF_W1T  = OFF_ST  + 8192;
constexpr size_t OFF_W2T  = OFF_W1T + (size_t)FD * C0 * 2;
constexpr size_t OFF_G0T  = OFF_W2T + (size_t)C0 * C0 * 2;
constexpr size_t OFF_G1T  = OFF_G0T + (size_t)C0 * C1 * 2;
constexpr size_t OFF_AUX  = OFF_G1T + (size_t)C1 * C1 * 2;
constexpr size_t OFF_FLAG = OFF_AUX  + 0;      // u32
constexpr size_t OFF_A0S  = OFF_AUX  + 256;    // 512 u16
constexpr size_t OFF_A0D  = OFF_AUX  + 1280;
constexpr size_t OFF_A1S  = OFF_AUX  + 2304;
constexpr size_t OFF_A1D  = OFF_AUX  + 3328;
constexpr size_t OFF_GB0  = OFF_AUX  + 4352;   // 512 f32
constexpr size_t OFF_GB1  = OFF_AUX  + 6400;
constexpr size_t OFF_FB1  = OFF_AUX  + 8448;   // 512 f32
constexpr size_t OFF_FB2  = OFF_AUX  + 10496;  // 10 f32 (pad 256)
constexpr size_t OFF_PP   = OFF_AUX  + 11008;  // f32[NG][PSPL][C1] pooling partials (4 MB)
constexpr size_t OFF_DENA = OFF_PP + (size_t)NG * PSPL * C1 * 4; // f32[NN*2] softmax denominators
constexpr size_t OFF_PLS  = OFF_DENA + (size_t)NN * 2 * 4;       // float2[4][NN] logits partials (640 KB)
// per-edge raw softmax numerators p (f32, per head) -- reuse dead XB region
constexpr size_t OFF_P0   = OFF_XB;            // EE f32
constexpr size_t OFF_P1   = OFF_XB + (size_t)EE * 4;
// end ~= 75.2 MB

// ---------------- helpers ----------------
__device__ inline float bf2f(u16 u) { return __uint_as_float(((unsigned)u) << 16); }
__device__ inline u16 f2bf(float f) {
    unsigned u = __float_as_uint(f);
    unsigned r = u + 0x7fffu + ((u >> 16) & 1u);   // RNE
    return (u16)(r >> 16);
}
// flag-driven load of an external float input (flag=1 -> f32, 0 -> bf16)
__device__ inline float ldf(const void* p, long i, unsigned f) {
    return f ? ((const float*)p)[i] : bf2f(((const u16*)p)[i]);
}
// 2 VALU ops per 32-bit word (low: shl drops high; high: mask)
__device__ inline void unpack8(uint4 r, float* v) {
    v[0] = __uint_as_float(r.x << 16); v[1] = __uint_as_float(r.x & 0xffff0000u);
    v[2] = __uint_as_float(r.y << 16); v[3] = __uint_as_float(r.y & 0xffff0000u);
    v[4] = __uint_as_float(r.z << 16); v[5] = __uint_as_float(r.z & 0xffff0000u);
    v[6] = __uint_as_float(r.w << 16); v[7] = __uint_as_float(r.w & 0xffff0000u);
}

typedef __bf16 bf16x8_t __attribute__((ext_vector_type(8)));
typedef float  f32x4_t  __attribute__((ext_vector_type(4)));

// async 16B global -> LDS (wave-uniform LDS base + lane*16 layout)
__device__ __forceinline__ void gl_lds16(const u16* g, u16* l) {
    __builtin_amdgcn_global_load_lds((const __attribute__((address_space(1))) void*)g,
                                     (__attribute__((address_space(3))) void*)l, 16, 0, 0);
}

// ---------------- dtype detector ----------------
__global__ void detect_dtype(const u16* __restrict__ x, const u16* __restrict__ w,
                             const u16* __restrict__ fw, unsigned* flag) {
    __shared__ int cnt;
    if (threadIdx.x == 0) cnt = 0;
    __syncthreads();
    int c = 0;
    for (int i = threadIdx.x; i < 4096; i += 256) {
        c += (((x[i]  >> 7) & 0xFF) == 0xFF);
        c += (((w[i]  >> 7) & 0xFF) == 0xFF);
        c += (((fw[i] >> 7) & 0xFF) == 0xFF);
    }
    atomicAdd(&cnt, c);
    __syncthreads();
    if (threadIdx.x == 0) *flag = (cnt >= 2) ? 1u : 0u;  // 1 = f32 inputs
}

// ---------------- x -> internal bf16 copy (+ zero deg/gcnt) ----------------
__global__ void cvt_x(const unsigned* __restrict__ flag, const void* __restrict__ xin,
                      u16* __restrict__ XB, int* __restrict__ deg, int* __restrict__ gcnt) {
    int i = blockIdx.x * 256 + threadIdx.x;  // grid covers NN*FD/4 (2500 blocks)
    if (i < NN) deg[i] = 0;
    if (i < NG) gcnt[i] = 0;
    if (*flag) {
        float4 v = ((const float4*)xin)[i];
        ushort4 r;
        r.x = f2bf(v.x); r.y = f2bf(v.y); r.z = f2bf(v.z); r.w = f2bf(v.w);
        ((ushort4*)XB)[i] = r;
    } else {
        ((ushort4*)XB)[i] = ((const ushort4*)xin)[i];
    }
}

// ---------------- fused params prep + all 4 weight transposes ----------------
// block 0: params (512 threads). blocks 1..960: B[K,N] -> BT[N,K] bf16, 512 elems/block.
__global__ __launch_bounds__(512) void prep_trans(const unsigned* __restrict__ flag,
                            const void* g1, const void* b1, const void* m1, const void* v1, const void* lb1,
                            const void* g2, const void* b2, const void* m2, const void* v2, const void* lb2,
                            const void* g3, const void* b3, const void* m3, const void* v3,
                            const void* a0s, const void* a0d, const void* gb0in,
                            const void* a1s, const void* a1d, const void* gb1in,
                            const void* fb1in, const void* fb2in,
                            float* S1, float* T1, float* S2, float* T2, float* S3, float* T3,
                            u16* A0S, u16* A0D, u16* A1S, u16* A1D,
                            float* GB0, float* GB1, float* FB1, float* FB2,
                            const void* w1, const void* w2, const void* g0w, const void* g1w,
                            u16* w1T, u16* w2T, u16* g0T, u16* g1T) {
    unsigned f = *flag;
    if (blockIdx.x == 0) {
        int c = threadIdx.x;  // 512 threads
        if (c < 256) {
            float s = ldf(g1, c, f) / sqrtf(ldf(v1, c, f) + 1e-5f);
            S1[c] = s; T1[c] = s * (ldf(lb1, c, f) - ldf(m1, c, f)) + ldf(b1, c, f);
            float s2 = ldf(g2, c, f) / sqrtf(ldf(v2, c, f) + 1e-5f);
            S2[c] = s2; T2[c] = s2 * (ldf(lb2, c, f) - ldf(m2, c, f)) + ldf(b2, c, f);
        }
        float s3 = ldf(g3, c, f) / sqrtf(ldf(v3, c, f) + 1e-5f);
        S3[c] = s3; T3[c] = ldf(b3, c, f) - ldf(m3, c, f) * s3;
        A0S[c] = f2bf(ldf(a0s, c, f));
        A0D[c] = f2bf(ldf(a0d, c, f));
        A1S[c] = f2bf(ldf(a1s, c, f));
        A1D[c] = f2bf(ldf(a1d, c, f));
        GB0[c] = ldf(gb0in, c, f);
        GB1[c] = ldf(gb1in, c, f);
        FB1[c] = ldf(fb1in, c, f);
        if (c < NC) FB2[c] = ldf(fb2in, c, f);
        return;
    }
    int b = blockIdx.x - 1;   // 0..959
    const void* B; u16* BT; int K, logN, base;
    if (b < 64)       { B = w1;  BT = w1T; K = FD; logN = 8; base = 0; }
    else if (b < 192) { B = w2;  BT = w2T; K = C0; logN = 8; base = 64; }
    else if (b < 448) { B = g0w; BT = g0T; K = C0; logN = 9; base = 192; }
    else              { B = g1w; BT = g1T; K = C1; logN = 9; base = 448; }
    int idx = (b - base) * 512 + threadIdx.x;
    int N = 1 << logN;
    int k = idx >> logN, n = idx & (N - 1);
    u16 v = f ? f2bf(((const float*)B)[idx]) : ((const u16*)B)[idx];
    BT[(size_t)n * K + k] = v;
}

// ---------------- CSR build: histograms (pipelined atomics + wave-run gcnt) ----------------
__global__ __launch_bounds__(256) void hist_k(const int* __restrict__ dst, const int* __restrict__ ew,
                                              const int* __restrict__ batch,
                                              int* __restrict__ deg, int* __restrict__ gcnt) {
    int tid = blockIdx.x * 256 + threadIdx.x;
    int lane = threadIdx.x & 63;
#pragma unroll
    for (int j = 0; j < 4; j++) {
        int e = tid + j * EST;
        if (e < EE && ew[e] == 1) atomicAdd(&deg[dst[e]], 1);
    }
    int n = tid;
    if (n < NN) {
        int g = batch[n];
        int pg = __shfl_up(g, 1);
        bool head = (lane == 0) || (pg != g);
        unsigned long long act = __ballot(1);
        unsigned long long hm  = __ballot(head);
        if (head) {
            unsigned long long above = (lane < 63) ? ((hm >> (lane + 1)) << (lane + 1)) : 0ull;
            int limit = 64 - __builtin_clzll(act);           // highest active lane + 1
            int nxt = above ? __builtin_ctzll(above) : limit;
            atomicAdd(&gcnt[g], nxt - lane);
        }
    }
}
// hierarchical scan: (1) per-block local exclusive scan + block totals
__global__ __launch_bounds__(256) void scan_blk(const int* __restrict__ deg, int* __restrict__ off,
                                                int* __restrict__ part) {
    __shared__ int tmp[256];
    int tid = threadIdx.x, i = blockIdx.x * 256 + tid;
    int v = (i < NN) ? deg[i] : 0;
    tmp[tid] = v;
    __syncthreads();
#pragma unroll
    for (int s = 1; s < 256; s <<= 1) {
        int a = (tid >= s) ? tmp[tid - s] : 0;
        __syncthreads();
        if (tid >= s) tmp[tid] += a;
        __syncthreads();
    }
    if (i < NN) off[i] = tmp[tid] - v;   // block-local exclusive
    if (tid == 255) part[blockIdx.x] = tmp[255];
}
// (2) scan the NBLK partials + scan gcnt -> goff (one small block does both)
__global__ __launch_bounds__(128) void scan_small(int* __restrict__ part, int* __restrict__ ptot,
                                                  const int* __restrict__ gcnt, int* __restrict__ goff) {
    __shared__ int tmp[128];
    int tid = threadIdx.x;
    int v = (tid < NBLK) ? part[tid] : 0;
    tmp[tid] = v;
    __syncthreads();
#pragma unroll
    for (int s = 1; s < 128; s <<= 1) {
        int a = (tid >= s) ? tmp[tid - s] : 0;
        __syncthreads();
        if (tid >= s) tmp[tid] += a;
        __syncthreads();
    }
    if (tid < NBLK) part[tid] = tmp[tid] - v;  // exclusive
    if (tid == 127) *ptot = tmp[127];
    __syncthreads();
    int g = gcnt[tid];
    tmp[tid] = g;
    __syncthreads();
#pragma unroll
    for (int s = 1; s < 128; s <<= 1) {
        int a = (tid >= s) ? tmp[tid - s] : 0;
        __syncthreads();
        if (tid >= s) tmp[tid] += a;
        __syncthreads();
    }
    goff[tid] = tmp[tid] - g;
    if (tid == 127) goff[128] = tmp[127];
}
// (3) add block prefix, emit cursor copy and total
__global__ __launch_bounds__(256) void scan_add(int* __restrict__ off, const int* __restrict__ part,
                                                const int* __restrict__ ptot, int* __restrict__ cursor) {
    int tid = threadIdx.x, i = blockIdx.x * 256 + tid;
    if (i < NN) {
        int o = off[i] + part[blockIdx.x];
        off[i] = o;
        cursor[i] = o;
    }
    if (i == 0) off[NN] = *ptot;
}
// fill: 4 independent atomic-return chains per thread; csrc stored u16 (NN < 65536)
__global__ __launch_bounds__(256) void csr_fill(const int* __restrict__ src, const int* __restrict__ dst,
                                                const int* __restrict__ ew,
                                                int* __restrict__ cursor, u16* __restrict__ csrc) {
    int tid = blockIdx.x * 256 + threadIdx.x;
    bool ok[4]; int sv[4]; int p[4];
#pragma unroll
    for (int j = 0; j < 4; j++) {
        int e = tid + j * EST;
        ok[j] = false; sv[j] = 0; p[j] = 0;
        if (e < EE && ew[e] == 1) {
            ok[j] = true;
            sv[j] = src[e];
            p[j] = atomicAdd(&cursor[dst[e]], 1);
        }
    }
#pragma unroll
    for (int j = 0; j < 4; j++) if (ok[j]) csrc[p[j]] = (u16)sv[j];
}

// ---------------- MFMA GEMM (R11): BK=64, XOR-swizzled staging (bank-conflict-free) --------
// 128x128 block, 4 waves 2x2 (64x64 per wave), BK=64, async global->LDS staging.
// LDS rows are 64 u16 = 8 chunks of 16B; chunk c of row r holds GLOBAL chunk c^(r&7)
// (achieved by pre-swizzling the per-lane GLOBAL address; LDS dest stays linear as
// global_load_lds requires). Reads XOR the chunk index back -> 2-way bank aliasing (free).
// MFMA call order per (r,c) is ascending k, identical to the old BK=32 loop -> bit-identical.
// EPI: 0 = store raw bf16; 1 = relu(acc*S[col]+T[col]); 3 = store raw + logits partials:
//      per-block partial dot products vs asrc/adst written to pls[blockIdx.y*NN + row].
template <int EPI>
__global__ __launch_bounds__(256) void gemm_tile(const u16* __restrict__ A, const u16* __restrict__ BT,
                                                 u16* __restrict__ Cm,
                                                 const float* __restrict__ S, const float* __restrict__ T,
                                                 const u16* __restrict__ asrc, const u16* __restrict__ adst,
                                                 float2* __restrict__ pls,
                                                 int M, int N, int K) {
    __shared__ u16 As[128 * 64];   // [row][k] rows of 64, chunk-swizzled as described
    __shared__ u16 Bs[128 * 64];   // [col][k]
    const int tid  = threadIdx.x;
    const int wave = tid >> 6;
    const int lane = tid & 63;
    const int quad = lane >> 4;
    const int l16  = lane & 15;
    const int wr0  = (wave >> 1) * 64;
    const int wc0  = (wave & 1) * 64;
    const int row0 = blockIdx.x * 128;
    const int col0 = blockIdx.y * 128;

    // staging geometry: 8 lanes per row (8 chunks of 8 u16), 8 rows per call, 4 calls per matrix
    const int srow = lane >> 3;              // 0..7 row within 8-row segment
    const int sk   = ((lane & 7) ^ srow) * 8; // PRE-SWIZZLED global chunk offset (u16)
    const u16* gaP[4]; const u16* gbP[4]; u16* laP[4]; u16* lbP[4];
#pragma unroll
    for (int i = 0; i < 4; i++) {
        int rl = wave * 32 + i * 8 + srow;
        int gr = row0 + rl; if (gr >= M) gr = M - 1;   // clamp: loads valid, stores guarded
        gaP[i] = A  + (size_t)gr * K + sk;
        gbP[i] = BT + (size_t)(col0 + rl) * K + sk;    // cols always < N by grid construction
        laP[i] = As + (size_t)rl * 64 + (lane & 7) * 8;  // linear LDS: base + lane*16B
        lbP[i] = Bs + (size_t)rl * 64 + (lane & 7) * 8;
    }

    f32x4_t acc[4][4];
#pragma unroll
    for (int r = 0; r < 4; r++)
#pragma unroll
        for (int c = 0; c < 4; c++)
#pragma unroll
            for (int i = 0; i < 4; i++) acc[r][c][i] = 0.f;

    for (int k0 = 0; k0 < K; k0 += 64) {
#pragma unroll
        for (int i = 0; i < 4; i++) {
            gl_lds16(gaP[i] + k0, laP[i]);
            gl_lds16(gbP[i] + k0, lbP[i]);
        }
        __syncthreads();   // drains vmcnt (async LDS writes) + all waves

#pragma unroll
        for (int kk = 0; kk < 2; kk++) {
            bf16x8_t a[4], b[4];
#pragma unroll
            for (int r = 0; r < 4; r++) {
                int rr = wr0 + r * 16 + l16;
                a[r] = *(const bf16x8_t*)(As + (size_t)rr * 64 + (((kk * 4 + quad) ^ (rr & 7)) * 8));
            }
#pragma unroll
            for (int c = 0; c < 4; c++) {
                int cc = wc0 + c * 16 + l16;
                b[c] = *(const bf16x8_t*)(Bs + (size_t)cc * 64 + (((kk * 4 + quad) ^ (cc & 7)) * 8));
            }
#pragma unroll
            for (int r = 0; r < 4; r++)
#pragma unroll
                for (int c = 0; c < 4; c++)
                    acc[r][c] = __builtin_amdgcn_mfma_f32_16x16x32_bf16(a[r], b[c], acc[r][c], 0, 0, 0);
        }
        __syncthreads();   // LDS reads done before next staging overwrites
    }

    // epilogue: store (+ logits partials for EPI==3; reuses As as a [2][128] float2 buffer)
    float2* lred = reinterpret_cast<float2*>(As);
#pragma unroll
    for (int r = 0; r < 4; r++) {
        int rb = row0 + wr0 + r * 16 + quad * 4;
        float ps[4] = {0.f, 0.f, 0.f, 0.f}, pd[4] = {0.f, 0.f, 0.f, 0.f};
#pragma unroll
        for (int c = 0; c < 4; c++) {
            int col = col0 + wc0 + c * 16 + l16;
            float sc = (EPI == 1) ? S[col] : 0.f;
            float sh = (EPI == 1) ? T[col] : 0.f;
            float av_ = 0.f, dv_ = 0.f;
            if (EPI == 3) { av_ = bf2f(asrc[col]); dv_ = bf2f(adst[col]); }
#pragma unroll
            for (int i = 0; i < 4; i++) {
                int row = rb + i;
                float v = acc[r][c][i];
                if (EPI == 1) v = fmaxf(v * sc + sh, 0.f);
                u16 bv = f2bf(v);
                if (row < M) Cm[(size_t)row * N + col] = bv;
                if (EPI == 3) {
                    float vb = bf2f(bv);           // same bf16-rounded value old logits read back
                    ps[i] = fmaf(vb, av_, ps[i]);
                    pd[i] = fmaf(vb, dv_, pd[i]);
                }
            }
        }
        if (EPI == 3) {
#pragma unroll
            for (int i = 0; i < 4; i++) {
#pragma unroll
                for (int m = 1; m <= 8; m <<= 1) {
                    ps[i] += __shfl_xor(ps[i], m);   // within the 16-lane l16 group (same rows)
                    pd[i] += __shfl_xor(pd[i], m);
                }
            }
            if (l16 == 0) {
#pragma unroll
                for (int i = 0; i < 4; i++) {
                    int rl = wr0 + r * 16 + quad * 4 + i;
                    lred[(size_t)(wave & 1) * 128 + rl] = make_float2(ps[i], pd[i]);
                }
            }
        }
    }
    if (EPI == 3) {
        __syncthreads();
        if (tid < 128) {
            int row = row0 + tid;
            if (row < M) {
                float2 a0 = lred[tid], a1 = lred[128 + tid];   // fixed order -> deterministic
                pls[(size_t)blockIdx.y * NN + row] = make_float2(a0.x + a1.x, a0.y + a1.y);
            }
        }
    }
}

// ---------------- combine per-colblock logits partials -> ls, ld (deterministic) ------------
// ls[n][h] = P[2h][n] + P[2h+1][n] (fixed order). Replaces the old gat_logits xw re-read.
__global__ __launch_bounds__(256) void ls_combine(const float2* __restrict__ pls,
                                                  float* __restrict__ ls, float* __restrict__ ld) {
    int n = blockIdx.x * 256 + threadIdx.x;
    if (n >= NN) return;
#pragma unroll
    for (int h = 0; h < 2; h++) {
        float2 a = pls[(size_t)(2 * h) * NN + n];
        float2 b = pls[(size_t)(2 * h + 1) * NN + n];
        ls[n * 2 + h] = a.x + b.x;
        ld[n * 2 + h] = a.y + b.y;
    }
}

// ---------------- per-edge raw p + denominator (R11: per-node exact max, no global max) -----
// wave per node; lanes 0..31 -> head 0 over 32-edge windows, lanes 32..63 -> head 1.
// pass 1 computes mhat = max_e leaky(ls_e + ldh) (exact upper bound; mhat choice only
// shifts p at fp-rounding level -- alpha is shift-invariant); pass 2 (L1/L2-hot) writes
// raw p and the masked-butterfly den (normalization at aggregate epilogue, R10-proven).
__global__ __launch_bounds__(256) void gat_prep(const int* __restrict__ off, const u16* __restrict__ csrc,
                                                const float* __restrict__ ls, const float* __restrict__ ld,
                                                float* __restrict__ P0, float* __restrict__ P1,
                                                float* __restrict__ denA) {
    int n = blockIdx.x * 4 + (threadIdx.x >> 6);
    if (n >= NN) return;
    int lane = threadIdx.x & 63;
    int h = lane >> 5;
    int el = lane & 31;
    int beg = off[n], end = off[n + 1];
    float2 ldv = ((const float2*)ld)[n];
    float ldh = h ? ldv.y : ldv.x;
    float* __restrict__ Ph = h ? P1 : P0;
    // pass 1: per-node max of leaky(ls+ldh)
    float vmax = -1e30f;
    for (int base = beg; base < end; base += 32) {
        int e = base + el;
        int ec = e < end ? e : end - 1;      // clamp: loads stay valid
        int sv = csrc[ec];
        float vv = ls[sv * 2 + h] + ldh;
        vv = vv > 0.f ? vv : 0.2f * vv;
        if (e < end) vmax = fmaxf(vmax, vv);
    }
#pragma unroll
    for (int m = 16; m >= 1; m >>= 1) vmax = fmaxf(vmax, __shfl_xor(vmax, m));  // stays in half
    float mhat = vmax;
    // pass 2: raw p + den (same gather, L1/L2-hot)
    float den = 0.f;
    for (int base = beg; base < end; base += 32) {
        int e = base + el;
        int ec = e < end ? e : end - 1;
        int sv = csrc[ec];
        float vv = ls[sv * 2 + h] + ldh;
        vv = vv > 0.f ? vv : 0.2f * vv;
        float p = __expf(vv - mhat);
        float pm = (e < end) ? p : 0.f;
#pragma unroll
        for (int m = 16; m >= 1; m >>= 1) pm += __shfl_xor(pm, m);
        den += pm;
        if (e < end) Ph[e] = p;
    }
    if (el == 0) denA[n * 2 + h] = den;      // lanes 0 (h=0) and 32 (h=1); den=0 for empty
}

// ---------------- GAT aggregation (wave/node + raw p, normalize at epilogue) ----------------
__device__ __forceinline__ void proc_edge(uint4 c, float w, float* acc) {
    float x[8];
    unpack8(c, x);
#pragma unroll
    for (int q = 0; q < 8; q++) acc[q] = fmaf(w, x[q], acc[q]);
}

__global__ __launch_bounds__(256) void gat_aggregate(const int* __restrict__ off, const u16* __restrict__ csrc,
                                                     const float* __restrict__ P0, const float* __restrict__ P1,
                                                     const float* __restrict__ denA,
                                                     const u16* __restrict__ xw,
                                                     const float* __restrict__ bias, u16* __restrict__ outh) {
    int n = blockIdx.x * 4 + (threadIdx.x >> 6);
    if (n >= NN) return;
    const int lane = threadIdx.x & 63;
    const int h    = lane >> 5;
    const int el   = lane & 31;
    const int hoff = h << 5;
    const float* __restrict__ Ph = h ? P1 : P0;
    int beg = off[n], end = off[n + 1];

    float acc[8];
#pragma unroll
    for (int q = 0; q < 8; q++) acc[q] = 0.f;

#define ROWLD(S) (((const uint4*)(xw + (size_t)(S) * C1))[lane])

    for (int base = beg; base < end; base += 32) {
        int cnt = end - base; if (cnt > 32) cnt = 32;
        int e = base + el;
        int ec = e < end ? e : end - 1;      // clamp: loads stay valid
        int sv = csrc[ec];                   // 32 edge srcs (both halves load same -> broadcast)
        float pv = Ph[ec];                   // raw p for edge (base+el), my head; tail unused

        // 4-deep row pipeline
        uint4 r0 = ROWLD(__shfl(sv, 0));
        uint4 r1 = ROWLD(__shfl(sv, 1));
        uint4 r2 = ROWLD(__shfl(sv, 2));
        uint4 r3 = ROWLD(__shfl(sv, 3));

        for (int j = 0; j < cnt; j += 4) {
            uint4 c0 = r0, c1 = r1, c2 = r2, c3 = r3;
            float w0 = __shfl(pv, j + hoff);
            float w1 = __shfl(pv, j + 1 + hoff);   // out-of-range j -> unused (guarded)
            float w2 = __shfl(pv, j + 2 + hoff);
            float w3 = __shfl(pv, j + 3 + hoff);
            if (j + 4 < cnt) {                     // prefetch next 4 rows (clamped -> valid)
                r0 = ROWLD(__shfl(sv, j + 4));
                r1 = ROWLD(__shfl(sv, j + 5));
                r2 = ROWLD(__shfl(sv, j + 6));
                r3 = ROWLD(__shfl(sv, j + 7));
            }
            proc_edge(c0, w0, acc);
            if (j + 1 < cnt) proc_edge(c1, w1, acc);
            if (j + 2 < cnt) proc_edge(c2, w2, acc);
            if (j + 3 < cnt) proc_edge(c3, w3, acc);
        }
    }
#undef ROWLD

    float inv = 1.f / fmaxf(denA[n * 2 + h], 1e-30f);
    int cb = lane * 8;
    const float4* bp = (const float4*)(bias + cb);
    float4 b0 = bp[0], b1 = bp[1];
    uint4 st;
    st.x = (unsigned)f2bf(fmaf(acc[0], inv, b0.x)) | ((unsigned)f2bf(fmaf(acc[1], inv, b0.y)) << 16);
    st.y = (unsigned)f2bf(fmaf(acc[2], inv, b0.z)) | ((unsigned)f2bf(fmaf(acc[3], inv, b0.w)) << 16);
    st.z = (unsigned)f2bf(fmaf(acc[4], inv, b1.x)) | ((unsigned)f2bf(fmaf(acc[5], inv, b1.y)) << 16);
    st.w = (unsigned)f2bf(fmaf(acc[6], inv, b1.z)) | ((unsigned)f2bf(fmaf(acc[7], inv, b1.w)) << 16);
    ((uint4*)(outh + (size_t)n * C1 + cb))[0] = st;
}

// ---------------- two-stage pooling stage 1 (R9-proven) ----------------
__global__ __launch_bounds__(128) void pool_part(const u16* __restrict__ h4, const int* __restrict__ goff,
                                                 float* __restrict__ pp) {
    int g = blockIdx.x, s = blockIdx.y, t = threadIdx.x;
    int b = goff[g], e = goff[g + 1];
    int len = e - b;
    int chunk = (len + PSPL - 1) / PSPL;
    int n0 = b + s * chunk;
    int n1 = n0 + chunk; if (n1 > e) n1 = e;
    float s0 = 0.f, s1 = 0.f, s2 = 0.f, s3 = 0.f;
    for (int n = n0; n < n1; n++) {
        ushort4 v = *(const ushort4*)(h4 + (size_t)n * C1 + t * 4);
        s0 += bf2f(v.x); s1 += bf2f(v.y); s2 += bf2f(v.z); s3 += bf2f(v.w);
    }
    float4* dst = (float4*)(pp + ((size_t)g * PSPL + s) * C1 + t * 4);
    *dst = make_float4(s0, s1, s2, s3);
}

// ---------------- fused pool_fin + BN3 + ReLU + fc1 + fc2 (R10-proven) ----------------
__global__ __launch_bounds__(512) void head_all(const unsigned* __restrict__ flag,
                                                const float* __restrict__ pp, const int* __restrict__ goff,
                                                const float* __restrict__ S3, const float* __restrict__ T3,
                                                const void* __restrict__ w1, const float* __restrict__ FB1,
                                                const void* __restrict__ w2, const float* __restrict__ FB2,
                                                void* __restrict__ out) {
    __shared__ float zrow[512];
    __shared__ float z2row[512];
    __shared__ float red[512];
    int g = blockIdx.x, t = threadIdx.x;
    unsigned f = *flag;
    float s = 0.f;
#pragma unroll
    for (int k = 0; k < PSPL; k++) s += pp[((size_t)g * PSPL + k) * C1 + t];
    int b = goff[g], e = goff[g + 1];
    float mean = s / fmaxf((float)(e - b), 1.f);
    float v = fmaxf(mean * S3[t] + T3[t], 0.f);
    zrow[t] = bf2f(f2bf(v));                  // round through bf16 (old z1 path)
    __syncthreads();
    float acc = 0.f;
    if (f) {
        const float* w = (const float*)w1;
        for (int k = 0; k < 512; k++) acc = fmaf(zrow[k], w[(size_t)k * 512 + t], acc);
    } else {
        const u16* w = (const u16*)w1;
        for (int k = 0; k < 512; k++) acc = fmaf(zrow[k], bf2f(w[(size_t)k * 512 + t]), acc);
    }
    acc += FB1[t];
    z2row[t] = bf2f(f2bf(fmaxf(acc, 0.f)));   // round through bf16 (old z2 path)
    __syncthreads();
    float z2t = z2row[t];
    for (int o = 0; o < NC; o++) {
        float p = f ? z2t * ((const float*)w2)[(size_t)t * NC + o]
                    : z2t * bf2f(((const u16*)w2)[(size_t)t * NC + o]);
        red[t] = p;
        __syncthreads();
#pragma unroll
        for (int sd = 256; sd >= 1; sd >>= 1) {
            if (t < sd) red[t] += red[t + sd];
            __syncthreads();
        }
        if (t == 0) {
            float vv = red[0] + FB2[o];
            if (f) ((float*)out)[g * NC + o] = vv;
            else   ((u16*)out)[g * NC + o] = f2bf(vv);
        }
        __syncthreads();   // red reused next o
    }
}

// ---------------- launch ----------------
extern "C" void kernel_launch(void* const* d_in, const int* in_sizes, int n_in,
                              void* d_out, int out_size, void* d_ws, size_t ws_size,
                              hipStream_t stream) {
    (void)in_sizes; (void)n_in; (void)out_size; (void)ws_size;

    const void* x      = d_in[0];
    const int* ei      = (const int*)d_in[1];
    const int* src     = ei;
    const int* dst     = ei + EE;
    const int* ew      = (const int*)d_in[2];
    const int* batch   = (const int*)d_in[3];
    const void* mlp_w1 = d_in[4];
    const void* mlp_b1 = d_in[5];
    const void *bn1g = d_in[6], *bn1b = d_in[7], *bn1m = d_in[8], *bn1v = d_in[9];
    const void* mlp_w2 = d_in[10];
    const void* mlp_b2 = d_in[11];
    const void *bn2g = d_in[12], *bn2b = d_in[13], *bn2m = d_in[14], *bn2v = d_in[15];
    const void* g0w    = d_in[16];
    const void* g0as   = d_in[17];
    const void* g0ad   = d_in[18];
    const void* g0bias = d_in[19];
    const void* g1w    = d_in[20];
    const void* g1as   = d_in[21];
    const void* g1ad   = d_in[22];
    const void* g1bias = d_in[23];
    const void *bn3g = d_in[24], *bn3b = d_in[25], *bn3m = d_in[26], *bn3v = d_in[27];
    const void* fin_w1 = d_in[28];
    const void* fin_b1 = d_in[29];
    const void* fin_w2 = d_in[30];
    const void* fin_b2 = d_in[31];

    char* ws = (char*)d_ws;
    u16*  XB   = (u16*)(ws + OFF_XB);
    u16*  h1   = (u16*)(ws + OFF_H1);
    u16*  h2   = (u16*)(ws + OFF_H2);
    u16*  xw   = (u16*)(ws + OFF_XW);    // row-major [NN][512]
    u16*  h34  = (u16*)(ws + OFF_H34);   // row-major [NN][512]
    float* ls  = (float*)(ws + OFF_LS);
    float* ld  = (float*)(ws + OFF_LD);
    int*  deg  = (int*)(ws + OFF_DEG);
    int*  off  = (int*)(ws + OFF_OFFS);
    int*  cur  = (int*)(ws + OFF_CUR);
    u16*  csrc = (u16*)(ws + OFF_CSRC);
    int*  gcnt = (int*)(ws + OFF_GCNT);
    int*  goff = (int*)(ws + OFF_GOFF);
    int*  part = (int*)(ws + OFF_PART);
    int*  ptot = (int*)(ws + OFF_PTOT);
    float* S1 = (float*)(ws + OFF_ST);
    float* T1 = S1 + 256;
    float* S2 = T1 + 256;
    float* T2 = S2 + 256;
    float* S3 = T2 + 256;
    float* T3 = S3 + 512;
    u16* w1T = (u16*)(ws + OFF_W1T);
    u16* w2T = (u16*)(ws + OFF_W2T);
    u16* g0T = (u16*)(ws + OFF_G0T);
    u16* g1T = (u16*)(ws + OFF_G1T);
    unsigned* flag = (unsigned*)(ws + OFF_FLAG);
    u16* A0S = (u16*)(ws + OFF_A0S);
    u16* A0D = (u16*)(ws + OFF_A0D);
    u16* A1S = (u16*)(ws + OFF_A1S);
    u16* A1D = (u16*)(ws + OFF_A1D);
    float* GB0 = (float*)(ws + OFF_GB0);
    float* GB1 = (float*)(ws + OFF_GB1);
    float* FB1 = (float*)(ws + OFF_FB1);
    float* FB2 = (float*)(ws + OFF_FB2);
    float* PP = (float*)(ws + OFF_PP);            // pooling partials [NG][PSPL][C1]
    float* DENA = (float*)(ws + OFF_DENA);        // per (node,head) denominators
    float2* PLS = (float2*)(ws + OFF_PLS);        // logits partials [4][NN]
    float* P0 = (float*)(ws + OFF_P0);            // per-edge raw p, head0 (reuses XB region)
    float* P1 = (float*)(ws + OFF_P1);            // per-edge raw p, head1

    // dtype detection + input normalization (+ deg/gcnt init)
    detect_dtype<<<1, 256, 0, stream>>>((const u16*)x, (const u16*)mlp_w1, (const u16*)fin_w1, flag);
    cvt_x<<<(NN * FD / 4) / 256, 256, 0, stream>>>(flag, x, XB, deg, gcnt);
    prep_trans<<<961, 512, 0, stream>>>(flag,
                                        bn1g, bn1b, bn1m, bn1v, mlp_b1,
                                        bn2g, bn2b, bn2m, bn2v, mlp_b2,
                                        bn3g, bn3b, bn3m, bn3v,
                                        g0as, g0ad, g0bias, g1as, g1ad, g1bias,
                                        fin_b1, fin_b2,
                                        S1, T1, S2, T2, S3, T3,
                                        A0S, A0D, A1S, A1D, GB0, GB1, FB1, FB2,
                                        mlp_w1, mlp_w2, g0w, g1w, w1T, w2T, g0T, g1T);

    // CSR build (graph fixed across both layers) + graph offsets
    hist_k<<<HB, 256, 0, stream>>>(dst, ew, batch, deg, gcnt);
    scan_blk<<<NBLK, 256, 0, stream>>>(deg, off, part);
    scan_small<<<1, 128, 0, stream>>>(part, ptot, gcnt, goff);
    scan_add<<<NBLK, 256, 0, stream>>>(off, part, ptot, cur);
    csr_fill<<<HB, 256, 0, stream>>>(src, dst, ew, cur, csrc);

    // MLP (157 row-blocks of 128 cover 20096 >= 20000)
    gemm_tile<1><<<dim3(157, 2), 256, 0, stream>>>(XB, w1T, h1, S1, T1, nullptr, nullptr, nullptr, NN, C0, FD);
    gemm_tile<1><<<dim3(157, 2), 256, 0, stream>>>(h1, w2T, h2, S2, T2, nullptr, nullptr, nullptr, NN, C0, C0);

    // GAT layer 0 (logits fused into gemm epilogue; P0/P1 reuse XB -- dead after gemm 1)
    gemm_tile<3><<<dim3(157, 4), 256, 0, stream>>>(h2, g0T, xw, nullptr, nullptr, A0S, A0D, PLS, NN, C1, C0);
    ls_combine<<<NBLK, 256, 0, stream>>>(PLS, ls, ld);
    gat_prep<<<NN / 4, 256, 0, stream>>>(off, csrc, ls, ld, P0, P1, DENA);
    gat_aggregate<<<NN / 4, 256, 0, stream>>>(off, csrc, P0, P1, DENA, xw, GB0, h34);

    // GAT layer 1
    gemm_tile<3><<<dim3(157, 4), 256, 0, stream>>>(h34, g1T, xw, nullptr, nullptr, A1S, A1D, PLS, NN, C1, C1);
    ls_combine<<<NBLK, 256, 0, stream>>>(PLS, ls, ld);
    gat_prep<<<NN / 4, 256, 0, stream>>>(off, csrc, ls, ld, P0, P1, DENA);
    gat_aggregate<<<NN / 4, 256, 0, stream>>>(off, csrc, P0, P1, DENA, xw, GB1, h34);  // h4

    // pool stage 1 + fused pool_fin/fc1/fc2
    pool_part<<<dim3(NG, PSPL), 128, 0, stream>>>(h34, goff, PP);
    head_all<<<NG, 512, 0, stream>>>(flag, PP, goff, S3, T3, fin_w1, FB1, fin_w2, FB2, d_out);
}

// Round 12
// 377.559 us; speedup vs baseline: 1.2634x; 1.0083x over previous
//
#include <hip/hip_runtime.h>

typedef unsigned short u16;

// ---------------- problem constants ----------------
constexpr int NN = 20000;   // nodes
constexpr int EE = 320000;  // edges
constexpr int FD = 128;     // input features
constexpr int C0 = 256;     // hidden (mlp)
constexpr int C1 = 512;     // H*C for GAT
constexpr int NG = 128;     // graphs
constexpr int NC = 10;      // classes
constexpr int NBLK = (NN + 255) / 256;  // 79
constexpr int HB  = 320;                // hist/fill blocks
constexpr int EST = HB * 256;           // edge stride (81920); 4 chunks cover EE
constexpr int PSPL = 16;                // pooling slices per graph

// ---------------- workspace layout (bytes) ----------------
constexpr size_t OFF_XB   = 0;                                   // NN*FD bf16 (dead after gemm1)
constexpr size_t OFF_H1   = OFF_XB  + (size_t)NN * FD * 2;       // NN*C0 bf16
constexpr size_t OFF_H2   = OFF_H1  + (size_t)NN * C0 * 2;       // NN*C0 bf16
constexpr size_t OFF_XW   = OFF_H2  + (size_t)NN * C0 * 2;       // NN*C1 bf16 (ROW-major xw)
constexpr size_t OFF_H34  = OFF_XW  + (size_t)NN * C1 * 2;       // NN*C1 bf16 (h3 then h4, row-major)
constexpr size_t OFF_LS   = OFF_H34 + (size_t)NN * C1 * 2;       // NN*2 f32
constexpr size_t OFF_LD   = OFF_LS  + (size_t)NN * 2 * 4;        // NN*2 f32
constexpr size_t OFF_DEG  = OFF_LD  + (size_t)NN * 2 * 4;        // NN i32
constexpr size_t OFF_OFFS = OFF_DEG + (size_t)NN * 4;            // NN+1 i32 (pad 80016)
constexpr size_t OFF_CUR  = OFF_OFFS + 80016;                    // NN i32
constexpr size_t OFF_CSRC = OFF_CUR + (size_t)NN * 4;            // EE u16 (region sized for old i32; half used)
constexpr size_t OFF_GCNT = OFF_CSRC + (size_t)EE * 4;           // NG i32
constexpr size_t OFF_GOFF = OFF_GCNT + 512;                      // NG+1 i32 (pad 768)
constexpr size_t OFF_PART = OFF_GOFF + 768;                      // NBLK i32 (pad 512)
constexpr size_t OFF_PTOT = OFF_PART + 512;                      // 1 i32 (pad 256)
constexpr size_t OFF_Z1   = OFF_PTOT + 256;                      // (legacy)
constexpr size_t OFF_Z2   = OFF_Z1  + (size_t)NG * C1 * 2;
constexpr size_t OFF_ST   = OFF_Z2  + (size_t)NG * C1 * 2;       // S1,T1,S2,T2 (256 f32), S3,T3 (512 f32)
constexpr size_t OFF_W1T  = OFF_ST  + 8192;
constexpr size_t OFF_W2T  = OFF_W1T + (size_t)FD * C0 * 2;
constexpr size_t OFF_G0T  = OFF_W2T + (size_t)C0 * C0 * 2;
constexpr size_t OFF_G1T  = OFF_G0T + (size_t)C0 * C1 * 2;
constexpr size_t OFF_AUX  = OFF_G1T + (size_t)C1 * C1 * 2;
constexpr size_t OFF_FLAG = OFF_AUX  + 0;      // u32
constexpr size_t OFF_A0S  = OFF_AUX  + 256;    // 512 u16
constexpr size_t OFF_A0D  = OFF_AUX  + 1280;
constexpr size_t OFF_A1S  = OFF_AUX  + 2304;
constexpr size_t OFF_A1D  = OFF_AUX  + 3328;
constexpr size_t OFF_GB0  = OFF_AUX  + 4352;   // 512 f32
constexpr size_t OFF_GB1  = OFF_AUX  + 6400;
constexpr size_t OFF_FB1  = OFF_AUX  + 8448;   // 512 f32
constexpr size_t OFF_FB2  = OFF_AUX  + 10496;  // 10 f32 (pad 256)
constexpr size_t OFF_PP   = OFF_AUX  + 11008;  // f32[NG][PSPL][C1] pooling partials (4 MB)
constexpr size_t OFF_DENA = OFF_PP + (size_t)NG * PSPL * C1 * 4; // (legacy, unused)
constexpr size_t OFF_PLS  = OFF_DENA + (size_t)NN * 2 * 4;       // float2[4][NN] logits partials (640 KB)
// end ~= 75.2 MB

// ---------------- helpers ----------------
__device__ inline float bf2f(u16 u) { return __uint_as_float(((unsigned)u) << 16); }
__device__ inline u16 f2bf(float f) {
    unsigned u = __float_as_uint(f);
    unsigned r = u + 0x7fffu + ((u >> 16) & 1u);   // RNE
    return (u16)(r >> 16);
}
// flag-driven load of an external float input (flag=1 -> f32, 0 -> bf16)
__device__ inline float ldf(const void* p, long i, unsigned f) {
    return f ? ((const float*)p)[i] : bf2f(((const u16*)p)[i]);
}
// 2 VALU ops per 32-bit word (low: shl drops high; high: mask)
__device__ inline void unpack8(uint4 r, float* v) {
    v[0] = __uint_as_float(r.x << 16); v[1] = __uint_as_float(r.x & 0xffff0000u);
    v[2] = __uint_as_float(r.y << 16); v[3] = __uint_as_float(r.y & 0xffff0000u);
    v[4] = __uint_as_float(r.z << 16); v[5] = __uint_as_float(r.z & 0xffff0000u);
    v[6] = __uint_as_float(r.w << 16); v[7] = __uint_as_float(r.w & 0xffff0000u);
}

typedef __bf16 bf16x8_t __attribute__((ext_vector_type(8)));
typedef float  f32x4_t  __attribute__((ext_vector_type(4)));

// async 16B global -> LDS (wave-uniform LDS base + lane*16 layout)
__device__ __forceinline__ void gl_lds16(const u16* g, u16* l) {
    __builtin_amdgcn_global_load_lds((const __attribute__((address_space(1))) void*)g,
                                     (__attribute__((address_space(3))) void*)l, 16, 0, 0);
}

// ---------------- dtype detector ----------------
__global__ void detect_dtype(const u16* __restrict__ x, const u16* __restrict__ w,
                             const u16* __restrict__ fw, unsigned* flag) {
    __shared__ int cnt;
    if (threadIdx.x == 0) cnt = 0;
    __syncthreads();
    int c = 0;
    for (int i = threadIdx.x; i < 4096; i += 256) {
        c += (((x[i]  >> 7) & 0xFF) == 0xFF);
        c += (((w[i]  >> 7) & 0xFF) == 0xFF);
        c += (((fw[i] >> 7) & 0xFF) == 0xFF);
    }
    atomicAdd(&cnt, c);
    __syncthreads();
    if (threadIdx.x == 0) *flag = (cnt >= 2) ? 1u : 0u;  // 1 = f32 inputs
}

// ---------------- x -> internal bf16 copy (+ zero deg/gcnt) ----------------
__global__ void cvt_x(const unsigned* __restrict__ flag, const void* __restrict__ xin,
                      u16* __restrict__ XB, int* __restrict__ deg, int* __restrict__ gcnt) {
    int i = blockIdx.x * 256 + threadIdx.x;  // grid covers NN*FD/4 (2500 blocks)
    if (i < NN) deg[i] = 0;
    if (i < NG) gcnt[i] = 0;
    if (*flag) {
        float4 v = ((const float4*)xin)[i];
        ushort4 r;
        r.x = f2bf(v.x); r.y = f2bf(v.y); r.z = f2bf(v.z); r.w = f2bf(v.w);
        ((ushort4*)XB)[i] = r;
    } else {
        ((ushort4*)XB)[i] = ((const ushort4*)xin)[i];
    }
}

// ---------------- fused params prep + all 4 weight transposes ----------------
// block 0: params (512 threads). blocks 1..960: B[K,N] -> BT[N,K] bf16, 512 elems/block.
__global__ __launch_bounds__(512) void prep_trans(const unsigned* __restrict__ flag,
                            const void* g1, const void* b1, const void* m1, const void* v1, const void* lb1,
                            const void* g2, const void* b2, const void* m2, const void* v2, const void* lb2,
                            const void* g3, const void* b3, const void* m3, const void* v3,
                            const void* a0s, const void* a0d, const void* gb0in,
                            const void* a1s, const void* a1d, const void* gb1in,
                            const void* fb1in, const void* fb2in,
                            float* S1, float* T1, float* S2, float* T2, float* S3, float* T3,
                            u16* A0S, u16* A0D, u16* A1S, u16* A1D,
                            float* GB0, float* GB1, float* FB1, float* FB2,
                            const void* w1, const void* w2, const void* g0w, const void* g1w,
                            u16* w1T, u16* w2T, u16* g0T, u16* g1T) {
    unsigned f = *flag;
    if (blockIdx.x == 0) {
        int c = threadIdx.x;  // 512 threads
        if (c < 256) {
            float s = ldf(g1, c, f) / sqrtf(ldf(v1, c, f) + 1e-5f);
            S1[c] = s; T1[c] = s * (ldf(lb1, c, f) - ldf(m1, c, f)) + ldf(b1, c, f);
            float s2 = ldf(g2, c, f) / sqrtf(ldf(v2, c, f) + 1e-5f);
            S2[c] = s2; T2[c] = s2 * (ldf(lb2, c, f) - ldf(m2, c, f)) + ldf(b2, c, f);
        }
        float s3 = ldf(g3, c, f) / sqrtf(ldf(v3, c, f) + 1e-5f);
        S3[c] = s3; T3[c] = ldf(b3, c, f) - ldf(m3, c, f) * s3;
        A0S[c] = f2bf(ldf(a0s, c, f));
        A0D[c] = f2bf(ldf(a0d, c, f));
        A1S[c] = f2bf(ldf(a1s, c, f));
        A1D[c] = f2bf(ldf(a1d, c, f));
        GB0[c] = ldf(gb0in, c, f);
        GB1[c] = ldf(gb1in, c, f);
        FB1[c] = ldf(fb1in, c, f);
        if (c < NC) FB2[c] = ldf(fb2in, c, f);
        return;
    }
    int b = blockIdx.x - 1;   // 0..959
    const void* B; u16* BT; int K, logN, base;
    if (b < 64)       { B = w1;  BT = w1T; K = FD; logN = 8; base = 0; }
    else if (b < 192) { B = w2;  BT = w2T; K = C0; logN = 8; base = 64; }
    else if (b < 448) { B = g0w; BT = g0T; K = C0; logN = 9; base = 192; }
    else              { B = g1w; BT = g1T; K = C1; logN = 9; base = 448; }
    int idx = (b - base) * 512 + threadIdx.x;
    int N = 1 << logN;
    int k = idx >> logN, n = idx & (N - 1);
    u16 v = f ? f2bf(((const float*)B)[idx]) : ((const u16*)B)[idx];
    BT[(size_t)n * K + k] = v;
}

// ---------------- CSR build: histograms (pipelined atomics + wave-run gcnt) ----------------
__global__ __launch_bounds__(256) void hist_k(const int* __restrict__ dst, const int* __restrict__ ew,
                                              const int* __restrict__ batch,
                                              int* __restrict__ deg, int* __restrict__ gcnt) {
    int tid = blockIdx.x * 256 + threadIdx.x;
    int lane = threadIdx.x & 63;
#pragma unroll
    for (int j = 0; j < 4; j++) {
        int e = tid + j * EST;
        if (e < EE && ew[e] == 1) atomicAdd(&deg[dst[e]], 1);
    }
    int n = tid;
    if (n < NN) {
        int g = batch[n];
        int pg = __shfl_up(g, 1);
        bool head = (lane == 0) || (pg != g);
        unsigned long long act = __ballot(1);
        unsigned long long hm  = __ballot(head);
        if (head) {
            unsigned long long above = (lane < 63) ? ((hm >> (lane + 1)) << (lane + 1)) : 0ull;
            int limit = 64 - __builtin_clzll(act);           // highest active lane + 1
            int nxt = above ? __builtin_ctzll(above) : limit;
            atomicAdd(&gcnt[g], nxt - lane);
        }
    }
}
// hierarchical scan: (1) per-block local exclusive scan + block totals
__global__ __launch_bounds__(256) void scan_blk(const int* __restrict__ deg, int* __restrict__ off,
                                                int* __restrict__ part) {
    __shared__ int tmp[256];
    int tid = threadIdx.x, i = blockIdx.x * 256 + tid;
    int v = (i < NN) ? deg[i] : 0;
    tmp[tid] = v;
    __syncthreads();
#pragma unroll
    for (int s = 1; s < 256; s <<= 1) {
        int a = (tid >= s) ? tmp[tid - s] : 0;
        __syncthreads();
        if (tid >= s) tmp[tid] += a;
        __syncthreads();
    }
    if (i < NN) off[i] = tmp[tid] - v;   // block-local exclusive
    if (tid == 255) part[blockIdx.x] = tmp[255];
}
// (2) scan the NBLK partials + scan gcnt -> goff (one small block does both)
__global__ __launch_bounds__(128) void scan_small(int* __restrict__ part, int* __restrict__ ptot,
                                                  const int* __restrict__ gcnt, int* __restrict__ goff) {
    __shared__ int tmp[128];
    int tid = threadIdx.x;
    int v = (tid < NBLK) ? part[tid] : 0;
    tmp[tid] = v;
    __syncthreads();
#pragma unroll
    for (int s = 1; s < 128; s <<= 1) {
        int a = (tid >= s) ? tmp[tid - s] : 0;
        __syncthreads();
        if (tid >= s) tmp[tid] += a;
        __syncthreads();
    }
    if (tid < NBLK) part[tid] = tmp[tid] - v;  // exclusive
    if (tid == 127) *ptot = tmp[127];
    __syncthreads();
    int g = gcnt[tid];
    tmp[tid] = g;
    __syncthreads();
#pragma unroll
    for (int s = 1; s < 128; s <<= 1) {
        int a = (tid >= s) ? tmp[tid - s] : 0;
        __syncthreads();
        if (tid >= s) tmp[tid] += a;
        __syncthreads();
    }
    goff[tid] = tmp[tid] - g;
    if (tid == 127) goff[128] = tmp[127];
}
// (3) add block prefix, emit cursor copy and total
__global__ __launch_bounds__(256) void scan_add(int* __restrict__ off, const int* __restrict__ part,
                                                const int* __restrict__ ptot, int* __restrict__ cursor) {
    int tid = threadIdx.x, i = blockIdx.x * 256 + tid;
    if (i < NN) {
        int o = off[i] + part[blockIdx.x];
        off[i] = o;
        cursor[i] = o;
    }
    if (i == 0) off[NN] = *ptot;
}
// fill: 4 independent atomic-return chains per thread; csrc stored u16 (NN < 65536)
__global__ __launch_bounds__(256) void csr_fill(const int* __restrict__ src, const int* __restrict__ dst,
                                                const int* __restrict__ ew,
                                                int* __restrict__ cursor, u16* __restrict__ csrc) {
    int tid = blockIdx.x * 256 + threadIdx.x;
    bool ok[4]; int sv[4]; int p[4];
#pragma unroll
    for (int j = 0; j < 4; j++) {
        int e = tid + j * EST;
        ok[j] = false; sv[j] = 0; p[j] = 0;
        if (e < EE && ew[e] == 1) {
            ok[j] = true;
            sv[j] = src[e];
            p[j] = atomicAdd(&cursor[dst[e]], 1);
        }
    }
#pragma unroll
    for (int j = 0; j < 4; j++) if (ok[j]) csrc[p[j]] = (u16)sv[j];
}

// ---------------- MFMA GEMM (R11-proven): BK=64, XOR-swizzled staging ----------------
// 128x128 block, 4 waves 2x2 (64x64 per wave), BK=64, async global->LDS staging.
// LDS rows of 64 u16 = 8 chunks of 16B; chunk c of row r holds GLOBAL chunk c^(r&7)
// (pre-swizzled GLOBAL address; LDS dest stays linear for global_load_lds). Reads XOR
// the chunk index back -> 2-way bank aliasing (free). MFMA order ascending k.
// EPI: 0 = raw bf16; 1 = relu(acc*S[col]+T[col]); 3 = raw + logits partials to pls.
template <int EPI>
__global__ __launch_bounds__(256) void gemm_tile(const u16* __restrict__ A, const u16* __restrict__ BT,
                                                 u16* __restrict__ Cm,
                                                 const float* __restrict__ S, const float* __restrict__ T,
                                                 const u16* __restrict__ asrc, const u16* __restrict__ adst,
                                                 float2* __restrict__ pls,
                                                 int M, int N, int K) {
    __shared__ u16 As[128 * 64];   // [row][k] rows of 64, chunk-swizzled as described
    __shared__ u16 Bs[128 * 64];   // [col][k]
    const int tid  = threadIdx.x;
    const int wave = tid >> 6;
    const int lane = tid & 63;
    const int quad = lane >> 4;
    const int l16  = lane & 15;
    const int wr0  = (wave >> 1) * 64;
    const int wc0  = (wave & 1) * 64;
    const int row0 = blockIdx.x * 128;
    const int col0 = blockIdx.y * 128;

    const int srow = lane >> 3;               // 0..7 row within 8-row segment
    const int sk   = ((lane & 7) ^ srow) * 8; // PRE-SWIZZLED global chunk offset (u16)
    const u16* gaP[4]; const u16* gbP[4]; u16* laP[4]; u16* lbP[4];
#pragma unroll
    for (int i = 0; i < 4; i++) {
        int rl = wave * 32 + i * 8 + srow;
        int gr = row0 + rl; if (gr >= M) gr = M - 1;   // clamp: loads valid, stores guarded
        gaP[i] = A  + (size_t)gr * K + sk;
        gbP[i] = BT + (size_t)(col0 + rl) * K + sk;    // cols always < N by grid construction
        laP[i] = As + (size_t)rl * 64 + (lane & 7) * 8;  // linear LDS: base + lane*16B
        lbP[i] = Bs + (size_t)rl * 64 + (lane & 7) * 8;
    }

    f32x4_t acc[4][4];
#pragma unroll
    for (int r = 0; r < 4; r++)
#pragma unroll
        for (int c = 0; c < 4; c++)
#pragma unroll
            for (int i = 0; i < 4; i++) acc[r][c][i] = 0.f;

    for (int k0 = 0; k0 < K; k0 += 64) {
#pragma unroll
        for (int i = 0; i < 4; i++) {
            gl_lds16(gaP[i] + k0, laP[i]);
            gl_lds16(gbP[i] + k0, lbP[i]);
        }
        __syncthreads();   // drains vmcnt (async LDS writes) + all waves

#pragma unroll
        for (int kk = 0; kk < 2; kk++) {
            bf16x8_t a[4], b[4];
#pragma unroll
            for (int r = 0; r < 4; r++) {
                int rr = wr0 + r * 16 + l16;
                a[r] = *(const bf16x8_t*)(As + (size_t)rr * 64 + (((kk * 4 + quad) ^ (rr & 7)) * 8));
            }
#pragma unroll
            for (int c = 0; c < 4; c++) {
                int cc = wc0 + c * 16 + l16;
                b[c] = *(const bf16x8_t*)(Bs + (size_t)cc * 64 + (((kk * 4 + quad) ^ (cc & 7)) * 8));
            }
#pragma unroll
            for (int r = 0; r < 4; r++)
#pragma unroll
                for (int c = 0; c < 4; c++)
                    acc[r][c] = __builtin_amdgcn_mfma_f32_16x16x32_bf16(a[r], b[c], acc[r][c], 0, 0, 0);
        }
        __syncthreads();   // LDS reads done before next staging overwrites
    }

    // epilogue: store (+ logits partials for EPI==3; reuses As as a [2][128] float2 buffer)
    float2* lred = reinterpret_cast<float2*>(As);
#pragma unroll
    for (int r = 0; r < 4; r++) {
        int rb = row0 + wr0 + r * 16 + quad * 4;
        float ps[4] = {0.f, 0.f, 0.f, 0.f}, pd[4] = {0.f, 0.f, 0.f, 0.f};
#pragma unroll
        for (int c = 0; c < 4; c++) {
            int col = col0 + wc0 + c * 16 + l16;
            float sc = (EPI == 1) ? S[col] : 0.f;
            float sh = (EPI == 1) ? T[col] : 0.f;
            float av_ = 0.f, dv_ = 0.f;
            if (EPI == 3) { av_ = bf2f(asrc[col]); dv_ = bf2f(adst[col]); }
#pragma unroll
            for (int i = 0; i < 4; i++) {
                int row = rb + i;
                float v = acc[r][c][i];
                if (EPI == 1) v = fmaxf(v * sc + sh, 0.f);
                u16 bv = f2bf(v);
                if (row < M) Cm[(size_t)row * N + col] = bv;
                if (EPI == 3) {
                    float vb = bf2f(bv);           // same bf16-rounded value old logits read back
                    ps[i] = fmaf(vb, av_, ps[i]);
                    pd[i] = fmaf(vb, dv_, pd[i]);
                }
            }
        }
        if (EPI == 3) {
#pragma unroll
            for (int i = 0; i < 4; i++) {
#pragma unroll
                for (int m = 1; m <= 8; m <<= 1) {
                    ps[i] += __shfl_xor(ps[i], m);   // within the 16-lane l16 group (same rows)
                    pd[i] += __shfl_xor(pd[i], m);
                }
            }
            if (l16 == 0) {
#pragma unroll
                for (int i = 0; i < 4; i++) {
                    int rl = wr0 + r * 16 + quad * 4 + i;
                    lred[(size_t)(wave & 1) * 128 + rl] = make_float2(ps[i], pd[i]);
                }
            }
        }
    }
    if (EPI == 3) {
        __syncthreads();
        if (tid < 128) {
            int row = row0 + tid;
            if (row < M) {
                float2 a0 = lred[tid], a1 = lred[128 + tid];   // fixed order -> deterministic
                pls[(size_t)blockIdx.y * NN + row] = make_float2(a0.x + a1.x, a0.y + a1.y);
            }
        }
    }
}

// ---------------- combine per-colblock logits partials -> ls, ld (deterministic) ------------
__global__ __launch_bounds__(256) void ls_combine(const float2* __restrict__ pls,
                                                  float* __restrict__ ls, float* __restrict__ ld) {
    int n = blockIdx.x * 256 + threadIdx.x;
    if (n >= NN) return;
#pragma unroll
    for (int h = 0; h < 2; h++) {
        float2 a = pls[(size_t)(2 * h) * NN + n];
        float2 b = pls[(size_t)(2 * h + 1) * NN + n];
        ls[n * 2 + h] = a.x + b.x;
        ld[n * 2 + h] = a.y + b.y;
    }
}

// ---------------- fused GAT softmax + aggregation (R12) ----------------
// Template HALF in {0,1}: processes nodes [HALF*10000, HALF*10000+10000), 2500 blocks each
// (split for profiler visibility: halves the dominant dispatch so hidden kernels surface).
// Per wave/node, three passes over the edge list (lanes 0..31 head0, 32..63 head1):
//   pass 1: mhat = max_e leaky(ls_e + ldh)      (identical ops to R11 gat_prep pass 1)
//   pass 2: den  = sum_e exp(v_e - mhat)        (identical masked butterfly -> identical den)
//   pass 3: row gather; lane el recomputes p inline (same formula -> bit-identical weight)
// Eliminates the P0/P1 arrays and the separate gat_prep launches.
__device__ __forceinline__ void proc_edge(uint4 c, float w, float* acc) {
    float x[8];
    unpack8(c, x);
#pragma unroll
    for (int q = 0; q < 8; q++) acc[q] = fmaf(w, x[q], acc[q]);
}

template <int HALF>
__global__ __launch_bounds__(256) void gat_agg_fused(const int* __restrict__ off, const u16* __restrict__ csrc,
                                                     const float* __restrict__ ls, const float* __restrict__ ld,
                                                     const u16* __restrict__ xw,
                                                     const float* __restrict__ bias, u16* __restrict__ outh) {
    int n = HALF * (NN / 2) + blockIdx.x * 4 + (threadIdx.x >> 6);   // grid (NN/2)/4 = 2500
    const int lane = threadIdx.x & 63;
    const int h    = lane >> 5;
    const int el   = lane & 31;
    const int hoff = h << 5;
    int beg = off[n], end = off[n + 1];
    float2 ldv = ((const float2*)ld)[n];
    float ldh = h ? ldv.y : ldv.x;

    // pass 1: per-node max of leaky(ls+ldh)
    float vmax = -1e30f;
    for (int base = beg; base < end; base += 32) {
        int e = base + el;
        int ec = e < end ? e : end - 1;      // clamp: loads stay valid
        int sv = csrc[ec];
        float vv = ls[sv * 2 + h] + ldh;
        vv = vv > 0.f ? vv : 0.2f * vv;
        if (e < end) vmax = fmaxf(vmax, vv);
    }
#pragma unroll
    for (int m = 16; m >= 1; m >>= 1) vmax = fmaxf(vmax, __shfl_xor(vmax, m));  // stays in half
    const float mhat = vmax;

    // pass 2: den (masked butterfly, L1/L2-hot gather)
    float den = 0.f;
    for (int base = beg; base < end; base += 32) {
        int e = base + el;
        int ec = e < end ? e : end - 1;
        int sv = csrc[ec];
        float vv = ls[sv * 2 + h] + ldh;
        vv = vv > 0.f ? vv : 0.2f * vv;
        float p = __expf(vv - mhat);
        float pm = (e < end) ? p : 0.f;
#pragma unroll
        for (int m = 16; m >= 1; m >>= 1) pm += __shfl_xor(pm, m);
        den += pm;
    }

    // pass 3: weighted row gather (p recomputed inline, bit-identical)
    float acc[8];
#pragma unroll
    for (int q = 0; q < 8; q++) acc[q] = 0.f;

#define ROWLD(S) (((const uint4*)(xw + (size_t)(S) * C1))[lane])

    for (int base = beg; base < end; base += 32) {
        int cnt = end - base; if (cnt > 32) cnt = 32;
        int e = base + el;
        int ec = e < end ? e : end - 1;      // clamp: loads stay valid
        int sv = csrc[ec];                   // 32 edge srcs (both halves load same -> broadcast)
        float vv = ls[sv * 2 + h] + ldh;
        vv = vv > 0.f ? vv : 0.2f * vv;
        float myp = __expf(vv - mhat);       // raw p for edge (base+el), my head

        // 4-deep row pipeline
        uint4 r0 = ROWLD(__shfl(sv, 0));
        uint4 r1 = ROWLD(__shfl(sv, 1));
        uint4 r2 = ROWLD(__shfl(sv, 2));
        uint4 r3 = ROWLD(__shfl(sv, 3));

        for (int j = 0; j < cnt; j += 4) {
            uint4 c0 = r0, c1 = r1, c2 = r2, c3 = r3;
            float w0 = __shfl(myp, j + hoff);
            float w1 = __shfl(myp, j + 1 + hoff);  // out-of-range j -> unused (guarded)
            float w2 = __shfl(myp, j + 2 + hoff);
            float w3 = __shfl(myp, j + 3 + hoff);
            if (j + 4 < cnt) {                     // prefetch next 4 rows (clamped -> valid)
                r0 = ROWLD(__shfl(sv, j + 4));
                r1 = ROWLD(__shfl(sv, j + 5));
                r2 = ROWLD(__shfl(sv, j + 6));
                r3 = ROWLD(__shfl(sv, j + 7));
            }
            proc_edge(c0, w0, acc);
            if (j + 1 < cnt) proc_edge(c1, w1, acc);
            if (j + 2 < cnt) proc_edge(c2, w2, acc);
            if (j + 3 < cnt) proc_edge(c3, w3, acc);
        }
    }
#undef ROWLD

    float inv = 1.f / fmaxf(den, 1e-30f);
    int cb = lane * 8;
    const float4* bp = (const float4*)(bias + cb);
    float4 b0 = bp[0], b1 = bp[1];
    uint4 st;
    st.x = (unsigned)f2bf(fmaf(acc[0], inv, b0.x)) | ((unsigned)f2bf(fmaf(acc[1], inv, b0.y)) << 16);
    st.y = (unsigned)f2bf(fmaf(acc[2], inv, b0.z)) | ((unsigned)f2bf(fmaf(acc[3], inv, b0.w)) << 16);
    st.z = (unsigned)f2bf(fmaf(acc[4], inv, b1.x)) | ((unsigned)f2bf(fmaf(acc[5], inv, b1.y)) << 16);
    st.w = (unsigned)f2bf(fmaf(acc[6], inv, b1.z)) | ((unsigned)f2bf(fmaf(acc[7], inv, b1.w)) << 16);
    ((uint4*)(outh + (size_t)n * C1 + cb))[0] = st;
}

// ---------------- two-stage pooling stage 1 (R9-proven) ----------------
__global__ __launch_bounds__(128) void pool_part(const u16* __restrict__ h4, const int* __restrict__ goff,
                                                 float* __restrict__ pp) {
    int g = blockIdx.x, s = blockIdx.y, t = threadIdx.x;
    int b = goff[g], e = goff[g + 1];
    int len = e - b;
    int chunk = (len + PSPL - 1) / PSPL;
    int n0 = b + s * chunk;
    int n1 = n0 + chunk; if (n1 > e) n1 = e;
    float s0 = 0.f, s1 = 0.f, s2 = 0.f, s3 = 0.f;
    for (int n = n0; n < n1; n++) {
        ushort4 v = *(const ushort4*)(h4 + (size_t)n * C1 + t * 4);
        s0 += bf2f(v.x); s1 += bf2f(v.y); s2 += bf2f(v.z); s3 += bf2f(v.w);
    }
    float4* dst = (float4*)(pp + ((size_t)g * PSPL + s) * C1 + t * 4);
    *dst = make_float4(s0, s1, s2, s3);
}

// ---------------- fused pool_fin + BN3 + ReLU + fc1 + fc2 (R10-proven) ----------------
__global__ __launch_bounds__(512) void head_all(const unsigned* __restrict__ flag,
                                                const float* __restrict__ pp, const int* __restrict__ goff,
                                                const float* __restrict__ S3, const float* __restrict__ T3,
                                                const void* __restrict__ w1, const float* __restrict__ FB1,
                                                const void* __restrict__ w2, const float* __restrict__ FB2,
                                                void* __restrict__ out) {
    __shared__ float zrow[512];
    __shared__ float z2row[512];
    __shared__ float red[512];
    int g = blockIdx.x, t = threadIdx.x;
    unsigned f = *flag;
    float s = 0.f;
#pragma unroll
    for (int k = 0; k < PSPL; k++) s += pp[((size_t)g * PSPL + k) * C1 + t];
    int b = goff[g], e = goff[g + 1];
    float mean = s / fmaxf((float)(e - b), 1.f);
    float v = fmaxf(mean * S3[t] + T3[t], 0.f);
    zrow[t] = bf2f(f2bf(v));                  // round through bf16 (old z1 path)
    __syncthreads();
    float acc = 0.f;
    if (f) {
        const float* w = (const float*)w1;
        for (int k = 0; k < 512; k++) acc = fmaf(zrow[k], w[(size_t)k * 512 + t], acc);
    } else {
        const u16* w = (const u16*)w1;
        for (int k = 0; k < 512; k++) acc = fmaf(zrow[k], bf2f(w[(size_t)k * 512 + t]), acc);
    }
    acc += FB1[t];
    z2row[t] = bf2f(f2bf(fmaxf(acc, 0.f)));   // round through bf16 (old z2 path)
    __syncthreads();
    float z2t = z2row[t];
    for (int o = 0; o < NC; o++) {
        float p = f ? z2t * ((const float*)w2)[(size_t)t * NC + o]
                    : z2t * bf2f(((const u16*)w2)[(size_t)t * NC + o]);
        red[t] = p;
        __syncthreads();
#pragma unroll
        for (int sd = 256; sd >= 1; sd >>= 1) {
            if (t < sd) red[t] += red[t + sd];
            __syncthreads();
        }
        if (t == 0) {
            float vv = red[0] + FB2[o];
            if (f) ((float*)out)[g * NC + o] = vv;
            else   ((u16*)out)[g * NC + o] = f2bf(vv);
        }
        __syncthreads();   // red reused next o
    }
}

// ---------------- launch ----------------
extern "C" void kernel_launch(void* const* d_in, const int* in_sizes, int n_in,
                              void* d_out, int out_size, void* d_ws, size_t ws_size,
                              hipStream_t stream) {
    (void)in_sizes; (void)n_in; (void)out_size; (void)ws_size;

    const void* x      = d_in[0];
    const int* ei      = (const int*)d_in[1];
    const int* src     = ei;
    const int* dst     = ei + EE;
    const int* ew      = (const int*)d_in[2];
    const int* batch   = (const int*)d_in[3];
    const void* mlp_w1 = d_in[4];
    const void* mlp_b1 = d_in[5];
    const void *bn1g = d_in[6], *bn1b = d_in[7], *bn1m = d_in[8], *bn1v = d_in[9];
    const void* mlp_w2 = d_in[10];
    const void* mlp_b2 = d_in[11];
    const void *bn2g = d_in[12], *bn2b = d_in[13], *bn2m = d_in[14], *bn2v = d_in[15];
    const void* g0w    = d_in[16];
    const void* g0as   = d_in[17];
    const void* g0ad   = d_in[18];
    const void* g0bias = d_in[19];
    const void* g1w    = d_in[20];
    const void* g1as   = d_in[21];
    const void* g1ad   = d_in[22];
    const void* g1bias = d_in[23];
    const void *bn3g = d_in[24], *bn3b = d_in[25], *bn3m = d_in[26], *bn3v = d_in[27];
    const void* fin_w1 = d_in[28];
    const void* fin_b1 = d_in[29];
    const void* fin_w2 = d_in[30];
    const void* fin_b2 = d_in[31];

    char* ws = (char*)d_ws;
    u16*  XB   = (u16*)(ws + OFF_XB);
    u16*  h1   = (u16*)(ws + OFF_H1);
    u16*  h2   = (u16*)(ws + OFF_H2);
    u16*  xw   = (u16*)(ws + OFF_XW);    // row-major [NN][512]
    u16*  h34  = (u16*)(ws + OFF_H34);   // row-major [NN][512]
    float* ls  = (float*)(ws + OFF_LS);
    float* ld  = (float*)(ws + OFF_LD);
    int*  deg  = (int*)(ws + OFF_DEG);
    int*  off  = (int*)(ws + OFF_OFFS);
    int*  cur  = (int*)(ws + OFF_CUR);
    u16*  csrc = (u16*)(ws + OFF_CSRC);
    int*  gcnt = (int*)(ws + OFF_GCNT);
    int*  goff = (int*)(ws + OFF_GOFF);
    int*  part = (int*)(ws + OFF_PART);
    int*  ptot = (int*)(ws + OFF_PTOT);
    float* S1 = (float*)(ws + OFF_ST);
    float* T1 = S1 + 256;
    float* S2 = T1 + 256;
    float* T2 = S2 + 256;
    float* S3 = T2 + 256;
    float* T3 = S3 + 512;
    u16* w1T = (u16*)(ws + OFF_W1T);
    u16* w2T = (u16*)(ws + OFF_W2T);
    u16* g0T = (u16*)(ws + OFF_G0T);
    u16* g1T = (u16*)(ws + OFF_G1T);
    unsigned* flag = (unsigned*)(ws + OFF_FLAG);
    u16* A0S = (u16*)(ws + OFF_A0S);
    u16* A0D = (u16*)(ws + OFF_A0D);
    u16* A1S = (u16*)(ws + OFF_A1S);
    u16* A1D = (u16*)(ws + OFF_A1D);
    float* GB0 = (float*)(ws + OFF_GB0);
    float* GB1 = (float*)(ws + OFF_GB1);
    float* FB1 = (float*)(ws + OFF_FB1);
    float* FB2 = (float*)(ws + OFF_FB2);
    float* PP = (float*)(ws + OFF_PP);            // pooling partials [NG][PSPL][C1]
    float2* PLS = (float2*)(ws + OFF_PLS);        // logits partials [4][NN]

    // dtype detection + input normalization (+ deg/gcnt init)
    detect_dtype<<<1, 256, 0, stream>>>((const u16*)x, (const u16*)mlp_w1, (const u16*)fin_w1, flag);
    cvt_x<<<(NN * FD / 4) / 256, 256, 0, stream>>>(flag, x, XB, deg, gcnt);
    prep_trans<<<961, 512, 0, stream>>>(flag,
                                        bn1g, bn1b, bn1m, bn1v, mlp_b1,
                                        bn2g, bn2b, bn2m, bn2v, mlp_b2,
                                        bn3g, bn3b, bn3m, bn3v,
                                        g0as, g0ad, g0bias, g1as, g1ad, g1bias,
                                        fin_b1, fin_b2,
                                        S1, T1, S2, T2, S3, T3,
                                        A0S, A0D, A1S, A1D, GB0, GB1, FB1, FB2,
                                        mlp_w1, mlp_w2, g0w, g1w, w1T, w2T, g0T, g1T);

    // CSR build (graph fixed across both layers) + graph offsets
    hist_k<<<HB, 256, 0, stream>>>(dst, ew, batch, deg, gcnt);
    scan_blk<<<NBLK, 256, 0, stream>>>(deg, off, part);
    scan_small<<<1, 128, 0, stream>>>(part, ptot, gcnt, goff);
    scan_add<<<NBLK, 256, 0, stream>>>(off, part, ptot, cur);
    csr_fill<<<HB, 256, 0, stream>>>(src, dst, ew, cur, csrc);

    // MLP (157 row-blocks of 128 cover 20096 >= 20000)
    gemm_tile<1><<<dim3(157, 2), 256, 0, stream>>>(XB, w1T, h1, S1, T1, nullptr, nullptr, nullptr, NN, C0, FD);
    gemm_tile<1><<<dim3(157, 2), 256, 0, stream>>>(h1, w2T, h2, S2, T2, nullptr, nullptr, nullptr, NN, C0, C0);

    // GAT layer 0 (logits fused into gemm epilogue; softmax fused into aggregation)
    gemm_tile<3><<<dim3(157, 4), 256, 0, stream>>>(h2, g0T, xw, nullptr, nullptr, A0S, A0D, PLS, NN, C1, C0);
    ls_combine<<<NBLK, 256, 0, stream>>>(PLS, ls, ld);
    gat_agg_fused<0><<<(NN / 2) / 4, 256, 0, stream>>>(off, csrc, ls, ld, xw, GB0, h34);
    gat_agg_fused<1><<<(NN / 2) / 4, 256, 0, stream>>>(off, csrc, ls, ld, xw, GB0, h34);

    // GAT layer 1
    gemm_tile<3><<<dim3(157, 4), 256, 0, stream>>>(h34, g1T, xw, nullptr, nullptr, A1S, A1D, PLS, NN, C1, C1);
    ls_combine<<<NBLK, 256, 0, stream>>>(PLS, ls, ld);
    gat_agg_fused<0><<<(NN / 2) / 4, 256, 0, stream>>>(off, csrc, ls, ld, xw, GB1, h34);
    gat_agg_fused<1><<<(NN / 2) / 4, 256, 0, stream>>>(off, csrc, ls, ld, xw, GB1, h34);

    // pool stage 1 + fused pool_fin/fc1/fc2
    pool_part<<<dim3(NG, PSPL), 128, 0, stream>>>(h34, goff, PP);
    head_all<<<NG, 512, 0, stream>>>(flag, PP, goff, S3, T3, fin_w1, FB1, fin_w2, FB2, d_out);
}